// Round 1
// baseline (2307.283 us; speedup 1.0000x reference)
//
#include <hip/hip_runtime.h>
#include <hip/hip_bf16.h>

#define B_ 4
#define T_ 1024
#define D_ 256
#define H_ 8
#define WIN_ 64
#define CIN_ 128
#define DH_ 32
#define DFF_ 512
#define L_ 4

// ---------------- conv1d: y[b,o,t] = bias[o] + sum_i sum_k x[b,i,t+k-1]*w[o,i,k]
__global__ __launch_bounds__(128) void conv1d_kernel(
    const float* __restrict__ x, const float* __restrict__ w,
    const float* __restrict__ bias, float* __restrict__ y, int I, int O) {
    int t = blockIdx.x * 128 + threadIdx.x;
    int o = blockIdx.y;
    int b = blockIdx.z;
    const float* xb = x + (size_t)b * I * T_;
    const float* wo = w + (size_t)o * I * 3;
    float acc = bias[o];
    for (int i = 0; i < I; ++i) {
        const float* xp = xb + i * T_;
        float xm = (t > 0) ? xp[t - 1] : 0.f;
        float x0 = xp[t];
        float xp1 = (t < T_ - 1) ? xp[t + 1] : 0.f;
        acc += xm * wo[3 * i] + x0 * wo[3 * i + 1] + xp1 * wo[3 * i + 2];
    }
    y[((size_t)b * O + o) * T_ + t] = acc;
}

// ---------------- LN2d reduce: per-batch mean/rstd over C*T elements
__global__ __launch_bounds__(256) void ln2d_reduce(
    const float* __restrict__ x, float* __restrict__ red, int CT) {
    int b = blockIdx.x;
    const float* xb = x + (size_t)b * CT;
    float s = 0.f, ss = 0.f;
    for (int i = threadIdx.x; i < CT; i += 256) {
        float v = xb[i];
        s += v; ss += v * v;
    }
    __shared__ float sh0[256], sh1[256];
    sh0[threadIdx.x] = s; sh1[threadIdx.x] = ss;
    __syncthreads();
    for (int st = 128; st > 0; st >>= 1) {
        if (threadIdx.x < st) {
            sh0[threadIdx.x] += sh0[threadIdx.x + st];
            sh1[threadIdx.x] += sh1[threadIdx.x + st];
        }
        __syncthreads();
    }
    if (threadIdx.x == 0) {
        float mu = sh0[0] / (float)CT;
        float var = sh1[0] / (float)CT - mu * mu;
        red[2 * b] = mu;
        red[2 * b + 1] = rsqrtf(var + 1e-5f);
    }
}

// ---------------- LN2d apply + ReLU
__global__ __launch_bounds__(256) void ln2d_apply(
    const float* __restrict__ x, const float* __restrict__ w,
    const float* __restrict__ bb, const float* __restrict__ red,
    float* __restrict__ y, int CT) {
    int idx = blockIdx.x * 256 + threadIdx.x;
    int b = blockIdx.y;
    float mu = red[2 * b], rstd = red[2 * b + 1];
    float v = (x[(size_t)b * CT + idx] - mu) * rstd * w[idx] + bb[idx];
    y[(size_t)b * CT + idx] = fmaxf(v, 0.f);
}

// ---------------- [B,D,T] -> [B,T,D] with pos add
__global__ __launch_bounds__(256) void to_btd(
    const float* __restrict__ src, const float* __restrict__ pos, float* __restrict__ h) {
    int d = threadIdx.x;
    int t = blockIdx.x;
    int b = blockIdx.z;
    h[((size_t)b * T_ + t) * D_ + d] = src[((size_t)b * D_ + d) * T_ + t] + pos[(size_t)t * D_ + d];
}

// ---------------- [B,T,D] -> [B,D,T]
__global__ __launch_bounds__(256) void to_bdt(
    const float* __restrict__ h, float* __restrict__ dst) {
    int d = threadIdx.x;
    int t = blockIdx.x;
    int b = blockIdx.z;
    dst[((size_t)b * D_ + d) * T_ + t] = h[((size_t)b * T_ + t) * D_ + d];
}

// ---------------- fp32 tiled GEMM: Y[M,N] = A[M,K] @ W[N,K]^T + bias, optional relu
// 64x64 tile, BK=16, 256 threads, 4x4 micro-tile. All dims multiples of 64/16.
template <int RELU>
__global__ __launch_bounds__(256) void gemm_bias(
    const float* __restrict__ A, const float* __restrict__ W,
    const float* __restrict__ bias, float* __restrict__ Y,
    int M, int N, int K) {
    __shared__ float As[16][65];
    __shared__ float Ws[16][65];
    int tid = threadIdx.x;
    int tx = tid & 15, ty = tid >> 4;
    int row0 = blockIdx.y * 64, col0 = blockIdx.x * 64;
    float acc[4][4] = {};
    for (int k0 = 0; k0 < K; k0 += 16) {
#pragma unroll
        for (int u = 0; u < 4; ++u) {
            int lin = u * 256 + tid;
            int r = lin >> 4, kk = lin & 15;
            As[kk][r] = A[(size_t)(row0 + r) * K + k0 + kk];
            Ws[kk][r] = W[(size_t)(col0 + r) * K + k0 + kk];
        }
        __syncthreads();
#pragma unroll
        for (int kk = 0; kk < 16; ++kk) {
            float a[4], w[4];
#pragma unroll
            for (int i = 0; i < 4; ++i) { a[i] = As[kk][ty * 4 + i]; w[i] = Ws[kk][tx * 4 + i]; }
#pragma unroll
            for (int i = 0; i < 4; ++i)
#pragma unroll
                for (int j = 0; j < 4; ++j) acc[i][j] += a[i] * w[j];
        }
        __syncthreads();
    }
#pragma unroll
    for (int i = 0; i < 4; ++i)
#pragma unroll
        for (int j = 0; j < 4; ++j) {
            int r = row0 + ty * 4 + i, c = col0 + tx * 4 + j;
            float v = acc[i][j] + bias[c];
            if (RELU) v = fmaxf(v, 0.f);
            Y[(size_t)r * N + c] = v;
        }
}

// ---------------- banded attention: one wave per (b,h,q) row
// qkv layout [B,T,3D]: q at +0, k at +256, v at +512 (head hh -> dims hh*32..+31)
__global__ __launch_bounds__(64) void attn_kernel(
    const float* __restrict__ qkv, float* __restrict__ out) {
    int qi = blockIdx.x, hh = blockIdx.y, b = blockIdx.z;
    int lane = threadIdx.x;
    const float* qptr = qkv + ((size_t)(b * T_ + qi)) * 768 + hh * 32;
    int jstart = qi >= WIN_ ? qi - WIN_ : 0;
    int n = (qi == 0) ? 1 : (qi - jstart);
    float s = -1e30f;
    if (lane < n) {
        int j = jstart + lane;
        const float* kptr = qkv + ((size_t)(b * T_ + j)) * 768 + 256 + hh * 32;
        float acc = 0.f;
#pragma unroll
        for (int d = 0; d < 32; d += 4) {
            acc += qptr[d] * kptr[d] + qptr[d + 1] * kptr[d + 1] +
                   qptr[d + 2] * kptr[d + 2] + qptr[d + 3] * kptr[d + 3];
        }
        s = acc * 0.17677669529663687f;  // 1/sqrt(32)
    }
    float m = s;
#pragma unroll
    for (int off = 32; off; off >>= 1) m = fmaxf(m, __shfl_xor(m, off));
    float p = (lane < n) ? __expf(s - m) : 0.f;
    float sum = p;
#pragma unroll
    for (int off = 32; off; off >>= 1) sum += __shfl_xor(sum, off);
    float a = p / sum;
    __shared__ float a_s[64];
    a_s[lane] = a;
    __syncthreads();
    if (lane < 32) {
        float o = 0.f;
        for (int jj = 0; jj < n; ++jj) {
            const float* vptr = qkv + ((size_t)(b * T_ + jstart + jj)) * 768 + 512 + hh * 32;
            o += a_s[jj] * vptr[lane];
        }
        out[((size_t)(b * T_ + qi)) * D_ + hh * 32 + lane] = o;
    }
}

// ---------------- residual add + row LayerNorm over D=256, in-place on h
__global__ __launch_bounds__(64) void ln_row(
    float* __restrict__ h, const float* __restrict__ o,
    const float* __restrict__ w, const float* __restrict__ bb) {
    int r = blockIdx.x;
    int lane = threadIdx.x;
    float x[4];
    float s = 0.f;
#pragma unroll
    for (int i = 0; i < 4; ++i) {
        int idx = i * 64 + lane;
        x[i] = h[(size_t)r * D_ + idx] + o[(size_t)r * D_ + idx];
        s += x[i];
    }
#pragma unroll
    for (int off = 32; off; off >>= 1) s += __shfl_xor(s, off);
    float mu = s * (1.f / D_);
    float ss = 0.f;
#pragma unroll
    for (int i = 0; i < 4; ++i) { float d = x[i] - mu; ss += d * d; }
#pragma unroll
    for (int off = 32; off; off >>= 1) ss += __shfl_xor(ss, off);
    float rstd = rsqrtf(ss * (1.f / D_) + 1e-5f);
#pragma unroll
    for (int i = 0; i < 4; ++i) {
        int idx = i * 64 + lane;
        h[(size_t)r * D_ + idx] = (x[i] - mu) * rstd * w[idx] + bb[idx];
    }
}

extern "C" void kernel_launch(void* const* d_in, const int* in_sizes, int n_in,
                              void* d_out, int out_size, void* d_ws, size_t ws_size,
                              hipStream_t stream) {
    const float* x        = (const float*)d_in[0];
    const float* pre_w0   = (const float*)d_in[1];
    const float* pre_b0   = (const float*)d_in[2];
    const float* pre_lnw0 = (const float*)d_in[3];
    const float* pre_lnb0 = (const float*)d_in[4];
    const float* pre_w1   = (const float*)d_in[5];
    const float* pre_b1   = (const float*)d_in[6];
    const float* pre_lnw1 = (const float*)d_in[7];
    const float* pre_lnb1 = (const float*)d_in[8];
    const float* pos_emb  = (const float*)d_in[9];
    const float* Wqkv     = (const float*)d_in[10];
    const float* bqkv     = (const float*)d_in[11];
    const float* Wo       = (const float*)d_in[12];
    const float* bo       = (const float*)d_in[13];
    const float* ln1w     = (const float*)d_in[14];
    const float* ln1b     = (const float*)d_in[15];
    const float* W1       = (const float*)d_in[16];
    const float* b1       = (const float*)d_in[17];
    const float* W2       = (const float*)d_in[18];
    const float* b2       = (const float*)d_in[19];
    const float* ln2w     = (const float*)d_in[20];
    const float* ln2b     = (const float*)d_in[21];
    const float* post_w0  = (const float*)d_in[22];
    const float* post_b0  = (const float*)d_in[23];
    const float* post_lnw0= (const float*)d_in[24];
    const float* post_lnb0= (const float*)d_in[25];
    const float* post_w1  = (const float*)d_in[26];
    const float* post_b1  = (const float*)d_in[27];
    const float* post_lnw1= (const float*)d_in[28];
    const float* post_lnb1= (const float*)d_in[29];

    float* ws = (float*)d_ws;
    const size_t M1 = 1u << 20;           // 1M floats
    float* H   = ws;                      // [B,T,D]      1M
    float* QKV = ws + 1 * M1;             // [B,T,3D]     3M (also A0/A1 conv bufs)
    float* A0  = QKV;                     // [B,D,T]      1M
    float* A1  = QKV + M1;                // [B,D,T]      1M
    float* F   = ws + 4 * M1;             // [B,T,DFF]    2M
    float* ATT = ws + 6 * M1;             // [B,T,D]      1M
    float* G   = ws + 7 * M1;             // [B,T,D]      1M
    float* red = ws + 8 * M1;             // 8 floats

    // ---- pre stage
    conv1d_kernel<<<dim3(8, D_, B_), 128, 0, stream>>>(x, pre_w0, pre_b0, A0, CIN_, D_);
    ln2d_reduce<<<B_, 256, 0, stream>>>(A0, red, D_ * T_);
    ln2d_apply<<<dim3(D_ * T_ / 256, B_), 256, 0, stream>>>(A0, pre_lnw0, pre_lnb0, red, A1, D_ * T_);
    conv1d_kernel<<<dim3(8, D_, B_), 128, 0, stream>>>(A1, pre_w1, pre_b1, A0, D_, D_);
    ln2d_reduce<<<B_, 256, 0, stream>>>(A0, red, D_ * T_);
    ln2d_apply<<<dim3(D_ * T_ / 256, B_), 256, 0, stream>>>(A0, pre_lnw1, pre_lnb1, red, A1, D_ * T_);
    to_btd<<<dim3(T_, 1, B_), 256, 0, stream>>>(A1, pos_emb, H);

    // ---- transformer layers
    const int M = B_ * T_;  // 4096
    for (int l = 0; l < L_; ++l) {
        gemm_bias<0><<<dim3(768 / 64, M / 64), 256, 0, stream>>>(
            H, Wqkv + (size_t)l * 768 * D_, bqkv + (size_t)l * 768, QKV, M, 768, D_);
        attn_kernel<<<dim3(T_, H_, B_), 64, 0, stream>>>(QKV, ATT);
        gemm_bias<0><<<dim3(D_ / 64, M / 64), 256, 0, stream>>>(
            ATT, Wo + (size_t)l * D_ * D_, bo + (size_t)l * D_, G, M, D_, D_);
        ln_row<<<M, 64, 0, stream>>>(H, G, ln1w + (size_t)l * D_, ln1b + (size_t)l * D_);
        gemm_bias<1><<<dim3(DFF_ / 64, M / 64), 256, 0, stream>>>(
            H, W1 + (size_t)l * DFF_ * D_, b1 + (size_t)l * DFF_, F, M, DFF_, D_);
        gemm_bias<0><<<dim3(D_ / 64, M / 64), 256, 0, stream>>>(
            F, W2 + (size_t)l * D_ * DFF_, b2 + (size_t)l * D_, G, M, D_, DFF_);
        ln_row<<<M, 64, 0, stream>>>(H, G, ln2w + (size_t)l * D_, ln2b + (size_t)l * D_);
    }

    // ---- post stage
    to_bdt<<<dim3(T_, 1, B_), 256, 0, stream>>>(H, A0);
    conv1d_kernel<<<dim3(8, D_, B_), 128, 0, stream>>>(A0, post_w0, post_b0, A1, D_, D_);
    ln2d_reduce<<<B_, 256, 0, stream>>>(A1, red, D_ * T_);
    ln2d_apply<<<dim3(D_ * T_ / 256, B_), 256, 0, stream>>>(A1, post_lnw0, post_lnb0, red, A0, D_ * T_);
    conv1d_kernel<<<dim3(8, CIN_, B_), 128, 0, stream>>>(A0, post_w1, post_b1, A1, D_, CIN_);
    ln2d_reduce<<<B_, 256, 0, stream>>>(A1, red, CIN_ * T_);
    ln2d_apply<<<dim3(CIN_ * T_ / 256, B_), 256, 0, stream>>>(A1, post_lnw1, post_lnb1, red,
                                                             (float*)d_out, CIN_ * T_);
}

// Round 2
// 1424.855 us; speedup vs baseline: 1.6193x; 1.6193x over previous
//
#include <hip/hip_runtime.h>
#include <hip/hip_bf16.h>

#define B_ 4
#define T_ 1024
#define D_ 256
#define H_ 8
#define WIN_ 64
#define CIN_ 128
#define DH_ 32
#define DFF_ 512
#define L_ 4
#define NC_ 32   // LN2d reduction chunks per batch

// ---------------- conv1d: y[b,o,t] = bias[o] + sum_i sum_k x[b,i,t+k-1]*w[o,i,k]
__global__ __launch_bounds__(128) void conv1d_kernel(
    const float* __restrict__ x, const float* __restrict__ w,
    const float* __restrict__ bias, float* __restrict__ y, int I, int O) {
    int t = blockIdx.x * 128 + threadIdx.x;
    int o = blockIdx.y;
    int b = blockIdx.z;
    const float* xb = x + (size_t)b * I * T_;
    const float* wo = w + (size_t)o * I * 3;
    float acc = bias[o];
    for (int i = 0; i < I; ++i) {
        const float* xp = xb + i * T_;
        float xm = (t > 0) ? xp[t - 1] : 0.f;
        float x0 = xp[t];
        float xp1 = (t < T_ - 1) ? xp[t + 1] : 0.f;
        acc += xm * wo[3 * i] + x0 * wo[3 * i + 1] + xp1 * wo[3 * i + 2];
    }
    y[((size_t)b * O + o) * T_ + t] = acc;
}

// ---------------- LN2d stage A: partial sums per (chunk, batch)
__global__ __launch_bounds__(256) void ln2d_partial(
    const float* __restrict__ x, float* __restrict__ part, int CT) {
    int b = blockIdx.y;
    int chunk = blockIdx.x;
    int n4 = CT / (4 * NC_);  // float4 elements per chunk
    const float4* xb = (const float4*)(x + (size_t)b * CT) + (size_t)chunk * n4;
    float s = 0.f, ss = 0.f;
    for (int i = threadIdx.x; i < n4; i += 256) {
        float4 v = xb[i];
        s += v.x + v.y + v.z + v.w;
        ss += v.x * v.x + v.y * v.y + v.z * v.z + v.w * v.w;
    }
#pragma unroll
    for (int off = 32; off; off >>= 1) {
        s += __shfl_xor(s, off);
        ss += __shfl_xor(ss, off);
    }
    __shared__ float sh0[4], sh1[4];
    int wave = threadIdx.x >> 6;
    if ((threadIdx.x & 63) == 0) { sh0[wave] = s; sh1[wave] = ss; }
    __syncthreads();
    if (threadIdx.x == 0) {
        float ts = sh0[0] + sh0[1] + sh0[2] + sh0[3];
        float tss = sh1[0] + sh1[1] + sh1[2] + sh1[3];
        part[(size_t)(b * NC_ + chunk) * 2] = ts;
        part[(size_t)(b * NC_ + chunk) * 2 + 1] = tss;
    }
}

// ---------------- LN2d stage B: finalize mean/rstd per batch
__global__ __launch_bounds__(64) void ln2d_final(
    const float* __restrict__ part, float* __restrict__ red, int CT) {
    int b = blockIdx.x;
    int lane = threadIdx.x;
    float s = 0.f, ss = 0.f;
    if (lane < NC_) {
        s = part[(size_t)(b * NC_ + lane) * 2];
        ss = part[(size_t)(b * NC_ + lane) * 2 + 1];
    }
#pragma unroll
    for (int off = 32; off; off >>= 1) {
        s += __shfl_xor(s, off);
        ss += __shfl_xor(ss, off);
    }
    if (lane == 0) {
        float mu = s / (float)CT;
        float var = ss / (float)CT - mu * mu;
        red[2 * b] = mu;
        red[2 * b + 1] = rsqrtf(var + 1e-5f);
    }
}

// ---------------- LN2d apply + ReLU (float4)
__global__ __launch_bounds__(256) void ln2d_apply(
    const float* __restrict__ x, const float* __restrict__ w,
    const float* __restrict__ bb, const float* __restrict__ red,
    float* __restrict__ y, int CT) {
    int idx = blockIdx.x * 256 + threadIdx.x;   // float4 index
    int b = blockIdx.y;
    float mu = red[2 * b], rstd = red[2 * b + 1];
    const float4* x4 = (const float4*)(x + (size_t)b * CT);
    const float4* w4 = (const float4*)w;
    const float4* b4 = (const float4*)bb;
    float4* y4 = (float4*)(y + (size_t)b * CT);
    float4 v = x4[idx], wv = w4[idx], bv = b4[idx];
    float4 r;
    r.x = fmaxf((v.x - mu) * rstd * wv.x + bv.x, 0.f);
    r.y = fmaxf((v.y - mu) * rstd * wv.y + bv.y, 0.f);
    r.z = fmaxf((v.z - mu) * rstd * wv.z + bv.z, 0.f);
    r.w = fmaxf((v.w - mu) * rstd * wv.w + bv.w, 0.f);
    y4[idx] = r;
}

// ---------------- [B,D,T] -> [B,T,D] with pos add
__global__ __launch_bounds__(256) void to_btd(
    const float* __restrict__ src, const float* __restrict__ pos, float* __restrict__ h) {
    int d = threadIdx.x;
    int t = blockIdx.x;
    int b = blockIdx.z;
    h[((size_t)b * T_ + t) * D_ + d] = src[((size_t)b * D_ + d) * T_ + t] + pos[(size_t)t * D_ + d];
}

// ---------------- [B,T,D] -> [B,D,T]
__global__ __launch_bounds__(256) void to_bdt(
    const float* __restrict__ h, float* __restrict__ dst) {
    int d = threadIdx.x;
    int t = blockIdx.x;
    int b = blockIdx.z;
    dst[((size_t)b * D_ + d) * T_ + t] = h[((size_t)b * T_ + t) * D_ + d];
}

// ---------------- fp32 tiled GEMM: Y[M,N] = A[M,K] @ W[N,K]^T + bias, optional relu
template <int RELU>
__global__ __launch_bounds__(256) void gemm_bias(
    const float* __restrict__ A, const float* __restrict__ W,
    const float* __restrict__ bias, float* __restrict__ Y,
    int M, int N, int K) {
    __shared__ float As[16][65];
    __shared__ float Ws[16][65];
    int tid = threadIdx.x;
    int tx = tid & 15, ty = tid >> 4;
    int row0 = blockIdx.y * 64, col0 = blockIdx.x * 64;
    float acc[4][4] = {};
    for (int k0 = 0; k0 < K; k0 += 16) {
#pragma unroll
        for (int u = 0; u < 4; ++u) {
            int lin = u * 256 + tid;
            int r = lin >> 4, kk = lin & 15;
            As[kk][r] = A[(size_t)(row0 + r) * K + k0 + kk];
            Ws[kk][r] = W[(size_t)(col0 + r) * K + k0 + kk];
        }
        __syncthreads();
#pragma unroll
        for (int kk = 0; kk < 16; ++kk) {
            float a[4], w[4];
#pragma unroll
            for (int i = 0; i < 4; ++i) { a[i] = As[kk][ty * 4 + i]; w[i] = Ws[kk][tx * 4 + i]; }
#pragma unroll
            for (int i = 0; i < 4; ++i)
#pragma unroll
                for (int j = 0; j < 4; ++j) acc[i][j] += a[i] * w[j];
        }
        __syncthreads();
    }
#pragma unroll
    for (int i = 0; i < 4; ++i)
#pragma unroll
        for (int j = 0; j < 4; ++j) {
            int r = row0 + ty * 4 + i, c = col0 + tx * 4 + j;
            float v = acc[i][j] + bias[c];
            if (RELU) v = fmaxf(v, 0.f);
            Y[(size_t)r * N + c] = v;
        }
}

// ---------------- banded attention: one wave per (b,h,q) row
__global__ __launch_bounds__(64) void attn_kernel(
    const float* __restrict__ qkv, float* __restrict__ out) {
    int qi = blockIdx.x, hh = blockIdx.y, b = blockIdx.z;
    int lane = threadIdx.x;
    const float* qptr = qkv + ((size_t)(b * T_ + qi)) * 768 + hh * 32;
    int jstart = qi >= WIN_ ? qi - WIN_ : 0;
    int n = (qi == 0) ? 1 : (qi - jstart);
    float s = -1e30f;
    if (lane < n) {
        int j = jstart + lane;
        const float* kptr = qkv + ((size_t)(b * T_ + j)) * 768 + 256 + hh * 32;
        float acc = 0.f;
#pragma unroll
        for (int d = 0; d < 32; d += 4) {
            acc += qptr[d] * kptr[d] + qptr[d + 1] * kptr[d + 1] +
                   qptr[d + 2] * kptr[d + 2] + qptr[d + 3] * kptr[d + 3];
        }
        s = acc * 0.17677669529663687f;  // 1/sqrt(32)
    }
    float m = s;
#pragma unroll
    for (int off = 32; off; off >>= 1) m = fmaxf(m, __shfl_xor(m, off));
    float p = (lane < n) ? __expf(s - m) : 0.f;
    float sum = p;
#pragma unroll
    for (int off = 32; off; off >>= 1) sum += __shfl_xor(sum, off);
    float a = p / sum;
    __shared__ float a_s[64];
    a_s[lane] = a;
    __syncthreads();
    if (lane < 32) {
        float o = 0.f;
        for (int jj = 0; jj < n; ++jj) {
            const float* vptr = qkv + ((size_t)(b * T_ + jstart + jj)) * 768 + 512 + hh * 32;
            o += a_s[jj] * vptr[lane];
        }
        out[((size_t)(b * T_ + qi)) * D_ + hh * 32 + lane] = o;
    }
}

// ---------------- residual add + row LayerNorm over D=256, in-place on h
__global__ __launch_bounds__(64) void ln_row(
    float* __restrict__ h, const float* __restrict__ o,
    const float* __restrict__ w, const float* __restrict__ bb) {
    int r = blockIdx.x;
    int lane = threadIdx.x;
    float x[4];
    float s = 0.f;
#pragma unroll
    for (int i = 0; i < 4; ++i) {
        int idx = i * 64 + lane;
        x[i] = h[(size_t)r * D_ + idx] + o[(size_t)r * D_ + idx];
        s += x[i];
    }
#pragma unroll
    for (int off = 32; off; off >>= 1) s += __shfl_xor(s, off);
    float mu = s * (1.f / D_);
    float ss = 0.f;
#pragma unroll
    for (int i = 0; i < 4; ++i) { float d = x[i] - mu; ss += d * d; }
#pragma unroll
    for (int off = 32; off; off >>= 1) ss += __shfl_xor(ss, off);
    float rstd = rsqrtf(ss * (1.f / D_) + 1e-5f);
#pragma unroll
    for (int i = 0; i < 4; ++i) {
        int idx = i * 64 + lane;
        h[(size_t)r * D_ + idx] = (x[i] - mu) * rstd * w[idx] + bb[idx];
    }
}

extern "C" void kernel_launch(void* const* d_in, const int* in_sizes, int n_in,
                              void* d_out, int out_size, void* d_ws, size_t ws_size,
                              hipStream_t stream) {
    const float* x        = (const float*)d_in[0];
    const float* pre_w0   = (const float*)d_in[1];
    const float* pre_b0   = (const float*)d_in[2];
    const float* pre_lnw0 = (const float*)d_in[3];
    const float* pre_lnb0 = (const float*)d_in[4];
    const float* pre_w1   = (const float*)d_in[5];
    const float* pre_b1   = (const float*)d_in[6];
    const float* pre_lnw1 = (const float*)d_in[7];
    const float* pre_lnb1 = (const float*)d_in[8];
    const float* pos_emb  = (const float*)d_in[9];
    const float* Wqkv     = (const float*)d_in[10];
    const float* bqkv     = (const float*)d_in[11];
    const float* Wo       = (const float*)d_in[12];
    const float* bo       = (const float*)d_in[13];
    const float* ln1w     = (const float*)d_in[14];
    const float* ln1b     = (const float*)d_in[15];
    const float* W1       = (const float*)d_in[16];
    const float* b1       = (const float*)d_in[17];
    const float* W2       = (const float*)d_in[18];
    const float* b2       = (const float*)d_in[19];
    const float* ln2w     = (const float*)d_in[20];
    const float* ln2b     = (const float*)d_in[21];
    const float* post_w0  = (const float*)d_in[22];
    const float* post_b0  = (const float*)d_in[23];
    const float* post_lnw0= (const float*)d_in[24];
    const float* post_lnb0= (const float*)d_in[25];
    const float* post_w1  = (const float*)d_in[26];
    const float* post_b1  = (const float*)d_in[27];
    const float* post_lnw1= (const float*)d_in[28];
    const float* post_lnb1= (const float*)d_in[29];

    float* ws = (float*)d_ws;
    const size_t M1 = 1u << 20;           // 1M floats
    float* H   = ws;                      // [B,T,D]      1M
    float* QKV = ws + 1 * M1;             // [B,T,3D]     3M (also A0/A1 conv bufs)
    float* A0  = QKV;                     // [B,D,T]      1M
    float* A1  = QKV + M1;                // [B,D,T]      1M
    float* F   = ws + 4 * M1;             // [B,T,DFF]    2M
    float* ATT = ws + 6 * M1;             // [B,T,D]      1M
    float* G   = ws + 7 * M1;             // [B,T,D]      1M
    float* red = ws + 8 * M1;             // 8 floats
    float* part= red + 16;                // B*NC*2 = 256 floats

    // ---- pre stage
    conv1d_kernel<<<dim3(8, D_, B_), 128, 0, stream>>>(x, pre_w0, pre_b0, A0, CIN_, D_);
    ln2d_partial<<<dim3(NC_, B_), 256, 0, stream>>>(A0, part, D_ * T_);
    ln2d_final<<<B_, 64, 0, stream>>>(part, red, D_ * T_);
    ln2d_apply<<<dim3(D_ * T_ / 1024, B_), 256, 0, stream>>>(A0, pre_lnw0, pre_lnb0, red, A1, D_ * T_);
    conv1d_kernel<<<dim3(8, D_, B_), 128, 0, stream>>>(A1, pre_w1, pre_b1, A0, D_, D_);
    ln2d_partial<<<dim3(NC_, B_), 256, 0, stream>>>(A0, part, D_ * T_);
    ln2d_final<<<B_, 64, 0, stream>>>(part, red, D_ * T_);
    ln2d_apply<<<dim3(D_ * T_ / 1024, B_), 256, 0, stream>>>(A0, pre_lnw1, pre_lnb1, red, A1, D_ * T_);
    to_btd<<<dim3(T_, 1, B_), 256, 0, stream>>>(A1, pos_emb, H);

    // ---- transformer layers
    const int M = B_ * T_;  // 4096
    for (int l = 0; l < L_; ++l) {
        gemm_bias<0><<<dim3(768 / 64, M / 64), 256, 0, stream>>>(
            H, Wqkv + (size_t)l * 768 * D_, bqkv + (size_t)l * 768, QKV, M, 768, D_);
        attn_kernel<<<dim3(T_, H_, B_), 64, 0, stream>>>(QKV, ATT);
        gemm_bias<0><<<dim3(D_ / 64, M / 64), 256, 0, stream>>>(
            ATT, Wo + (size_t)l * D_ * D_, bo + (size_t)l * D_, G, M, D_, D_);
        ln_row<<<M, 64, 0, stream>>>(H, G, ln1w + (size_t)l * D_, ln1b + (size_t)l * D_);
        gemm_bias<1><<<dim3(DFF_ / 64, M / 64), 256, 0, stream>>>(
            H, W1 + (size_t)l * DFF_ * D_, b1 + (size_t)l * DFF_, F, M, DFF_, D_);
        gemm_bias<0><<<dim3(D_ / 64, M / 64), 256, 0, stream>>>(
            F, W2 + (size_t)l * D_ * DFF_, b2 + (size_t)l * D_, G, M, D_, DFF_);
        ln_row<<<M, 64, 0, stream>>>(H, G, ln2w + (size_t)l * D_, ln2b + (size_t)l * D_);
    }

    // ---- post stage
    to_bdt<<<dim3(T_, 1, B_), 256, 0, stream>>>(H, A0);
    conv1d_kernel<<<dim3(8, D_, B_), 128, 0, stream>>>(A0, post_w0, post_b0, A1, D_, D_);
    ln2d_partial<<<dim3(NC_, B_), 256, 0, stream>>>(A1, part, D_ * T_);
    ln2d_final<<<B_, 64, 0, stream>>>(part, red, D_ * T_);
    ln2d_apply<<<dim3(D_ * T_ / 1024, B_), 256, 0, stream>>>(A1, post_lnw0, post_lnb0, red, A0, D_ * T_);
    conv1d_kernel<<<dim3(8, CIN_, B_), 128, 0, stream>>>(A0, post_w1, post_b1, A1, D_, CIN_);
    ln2d_partial<<<dim3(NC_, B_), 256, 0, stream>>>(A1, part, CIN_ * T_);
    ln2d_final<<<B_, 64, 0, stream>>>(part, red, CIN_ * T_);
    ln2d_apply<<<dim3(CIN_ * T_ / 1024, B_), 256, 0, stream>>>(A1, post_lnw1, post_lnb1, red,
                                                              (float*)d_out, CIN_ * T_);
}

// Round 3
// 705.668 us; speedup vs baseline: 3.2696x; 2.0192x over previous
//
#include <hip/hip_runtime.h>
#include <hip/hip_bf16.h>

#define B_ 4
#define T_ 1024
#define D_ 256
#define H_ 8
#define WIN_ 64
#define CIN_ 128
#define DH_ 32
#define DFF_ 512
#define L_ 4
#define NC_ 32   // LN2d reduction chunks per batch

typedef __attribute__((ext_vector_type(4))) short s16x4;
typedef __attribute__((ext_vector_type(8))) short s16x8;
typedef __attribute__((ext_vector_type(4))) float f32x4;

__device__ inline short f2bf(float f) {
    __hip_bfloat16 h = __float2bfloat16(f);
    return *reinterpret_cast<short*>(&h);
}

// ---------------- im2col (channel-major input): Acol[(b*T+t)][i*3+k] = x[b,i,t+k-1]
// TT=32 t-tile per block. K = I*3.
__global__ __launch_bounds__(256) void im2col_kernel(
    const float* __restrict__ x, float* __restrict__ Acol, int I) {
    const int K = I * 3;
    int t0 = blockIdx.x * 32;
    int b = blockIdx.y;
    extern __shared__ float xs[];   // [I][34]
    for (int idx = threadIdx.x; idx < I * 34; idx += 256) {
        int i = idx / 34, tt = idx % 34;
        int tg = t0 - 1 + tt;
        xs[idx] = (tg >= 0 && tg < T_) ? x[((size_t)b * I + i) * T_ + tg] : 0.f;
    }
    __syncthreads();
    int nf4 = K / 4;
    for (int idx = threadIdx.x; idx < 32 * nf4; idx += 256) {
        int tl = idx / nf4, c4 = idx % nf4;
        int c = c4 * 4;
        float4 v;
        {
            int cc = c;     int i = cc / 3, k = cc - 3 * i; v.x = xs[i * 34 + tl + k];
        }
        {
            int cc = c + 1; int i = cc / 3, k = cc - 3 * i; v.y = xs[i * 34 + tl + k];
        }
        {
            int cc = c + 2; int i = cc / 3, k = cc - 3 * i; v.z = xs[i * 34 + tl + k];
        }
        {
            int cc = c + 3; int i = cc / 3, k = cc - 3 * i; v.w = xs[i * 34 + tl + k];
        }
        *(float4*)&Acol[((size_t)(b * T_ + t0 + tl)) * K + c] = v;
    }
}

// ---------------- bf16 MFMA GEMM: Y = A[M,K] @ W[N,K]^T + bias
// A,W fp32 (converted to bf16 during LDS staging). 128x128 tile, BK=32, 256 threads.
// TRANSOUT=0: Y[M,N] row-major. TRANSOUT=1: Y is [B][N][1024], row r=(b*1024+t).
template <int RELU, int TRANSOUT>
__global__ __launch_bounds__(256) void gemm_mfma(
    const float* __restrict__ A, const float* __restrict__ W,
    const float* __restrict__ bias, float* __restrict__ Y,
    int M, int N, int K) {
    __shared__ short Al[128 * 40];
    __shared__ short Wl[128 * 40];
    int tid = threadIdx.x;
    int row0 = blockIdx.y * 128, col0 = blockIdx.x * 128;
    int wave = tid >> 6, lane = tid & 63;
    int wr = wave >> 1, wc = wave & 1;
    f32x4 acc[4][4] = {};

    int srow = tid >> 3;            // 0..31
    int scol = (tid & 7) * 4;       // 0,4,..,28
    for (int k0 = 0; k0 < K; k0 += 32) {
#pragma unroll
        for (int p = 0; p < 4; ++p) {
            int rr = srow + p * 32;
            float4 va = *(const float4*)&A[(size_t)(row0 + rr) * K + k0 + scol];
            float4 vw = *(const float4*)&W[(size_t)(col0 + rr) * K + k0 + scol];
            s16x4 sa, sw;
            sa[0] = f2bf(va.x); sa[1] = f2bf(va.y); sa[2] = f2bf(va.z); sa[3] = f2bf(va.w);
            sw[0] = f2bf(vw.x); sw[1] = f2bf(vw.y); sw[2] = f2bf(vw.z); sw[3] = f2bf(vw.w);
            *(s16x4*)&Al[rr * 40 + scol] = sa;
            *(s16x4*)&Wl[rr * 40 + scol] = sw;
        }
        __syncthreads();
        s16x8 af[4], wf[4];
#pragma unroll
        for (int i = 0; i < 4; ++i) {
            af[i] = *(const s16x8*)&Al[(wr * 64 + i * 16 + (lane & 15)) * 40 + (lane >> 4) * 8];
            wf[i] = *(const s16x8*)&Wl[(wc * 64 + i * 16 + (lane & 15)) * 40 + (lane >> 4) * 8];
        }
#pragma unroll
        for (int i = 0; i < 4; ++i)
#pragma unroll
            for (int j = 0; j < 4; ++j)
                acc[i][j] = __builtin_amdgcn_mfma_f32_16x16x32_bf16(af[i], wf[j], acc[i][j], 0, 0, 0);
        __syncthreads();
    }

    if (TRANSOUT) {
        // Y[((b*N + c))*1024 + t], r = b*1024 + t; tiles never cross b.
        int b = row0 >> 10;
        int t0 = row0 & 1023;
#pragma unroll
        for (int i = 0; i < 4; ++i) {
            int tg = t0 + wr * 64 + i * 16 + (lane >> 4) * 4;
#pragma unroll
            for (int j = 0; j < 4; ++j) {
                int cg = col0 + wc * 64 + j * 16 + (lane & 15);
                float bv = bias[cg];
                float4 o;
                o.x = acc[i][j][0] + bv; o.y = acc[i][j][1] + bv;
                o.z = acc[i][j][2] + bv; o.w = acc[i][j][3] + bv;
                if (RELU) {
                    o.x = fmaxf(o.x, 0.f); o.y = fmaxf(o.y, 0.f);
                    o.z = fmaxf(o.z, 0.f); o.w = fmaxf(o.w, 0.f);
                }
                *(float4*)&Y[((size_t)(b * N + cg)) * 1024 + tg] = o;
            }
        }
    } else {
#pragma unroll
        for (int i = 0; i < 4; ++i) {
            int rg = row0 + wr * 64 + i * 16 + (lane >> 4) * 4;
#pragma unroll
            for (int j = 0; j < 4; ++j) {
                int cg = col0 + wc * 64 + j * 16 + (lane & 15);
                float bv = bias[cg];
#pragma unroll
                for (int q = 0; q < 4; ++q) {
                    float v = acc[i][j][q] + bv;
                    if (RELU) v = fmaxf(v, 0.f);
                    Y[(size_t)(rg + q) * N + cg] = v;
                }
            }
        }
    }
}

// ---------------- LN2d stage A: partial sums per (chunk, batch)
__global__ __launch_bounds__(256) void ln2d_partial(
    const float* __restrict__ x, float* __restrict__ part, int CT) {
    int b = blockIdx.y;
    int chunk = blockIdx.x;
    int n4 = CT / (4 * NC_);
    const float4* xb = (const float4*)(x + (size_t)b * CT) + (size_t)chunk * n4;
    float s = 0.f, ss = 0.f;
    for (int i = threadIdx.x; i < n4; i += 256) {
        float4 v = xb[i];
        s += v.x + v.y + v.z + v.w;
        ss += v.x * v.x + v.y * v.y + v.z * v.z + v.w * v.w;
    }
#pragma unroll
    for (int off = 32; off; off >>= 1) {
        s += __shfl_xor(s, off);
        ss += __shfl_xor(ss, off);
    }
    __shared__ float sh0[4], sh1[4];
    int wave = threadIdx.x >> 6;
    if ((threadIdx.x & 63) == 0) { sh0[wave] = s; sh1[wave] = ss; }
    __syncthreads();
    if (threadIdx.x == 0) {
        part[(size_t)(b * NC_ + chunk) * 2] = sh0[0] + sh0[1] + sh0[2] + sh0[3];
        part[(size_t)(b * NC_ + chunk) * 2 + 1] = sh1[0] + sh1[1] + sh1[2] + sh1[3];
    }
}

// ---------------- LN2d stage B: finalize mean/rstd per batch
__global__ __launch_bounds__(64) void ln2d_final(
    const float* __restrict__ part, float* __restrict__ red, int CT) {
    int b = blockIdx.x;
    int lane = threadIdx.x;
    float s = 0.f, ss = 0.f;
    if (lane < NC_) {
        s = part[(size_t)(b * NC_ + lane) * 2];
        ss = part[(size_t)(b * NC_ + lane) * 2 + 1];
    }
#pragma unroll
    for (int off = 32; off; off >>= 1) {
        s += __shfl_xor(s, off);
        ss += __shfl_xor(ss, off);
    }
    if (lane == 0) {
        float mu = s / (float)CT;
        float var = ss / (float)CT - mu * mu;
        red[2 * b] = mu;
        red[2 * b + 1] = rsqrtf(var + 1e-5f);
    }
}

// ---------------- LN2d apply + ReLU (float4)
__global__ __launch_bounds__(256) void ln2d_apply(
    const float* __restrict__ x, const float* __restrict__ w,
    const float* __restrict__ bb, const float* __restrict__ red,
    float* __restrict__ y, int CT) {
    int idx = blockIdx.x * 256 + threadIdx.x;
    int b = blockIdx.y;
    float mu = red[2 * b], rstd = red[2 * b + 1];
    const float4* x4 = (const float4*)(x + (size_t)b * CT);
    const float4* w4 = (const float4*)w;
    const float4* b4 = (const float4*)bb;
    float4* y4 = (float4*)(y + (size_t)b * CT);
    float4 v = x4[idx], wv = w4[idx], bv = b4[idx];
    float4 r;
    r.x = fmaxf((v.x - mu) * rstd * wv.x + bv.x, 0.f);
    r.y = fmaxf((v.y - mu) * rstd * wv.y + bv.y, 0.f);
    r.z = fmaxf((v.z - mu) * rstd * wv.z + bv.z, 0.f);
    r.w = fmaxf((v.w - mu) * rstd * wv.w + bv.w, 0.f);
    y4[idx] = r;
}

// ---------------- [B,D,T] -> [B,T,D] with pos add
__global__ __launch_bounds__(256) void to_btd(
    const float* __restrict__ src, const float* __restrict__ pos, float* __restrict__ h) {
    int d = threadIdx.x;
    int t = blockIdx.x;
    int b = blockIdx.z;
    h[((size_t)b * T_ + t) * D_ + d] = src[((size_t)b * D_ + d) * T_ + t] + pos[(size_t)t * D_ + d];
}

// ---------------- [B,T,D] -> [B,D,T]
__global__ __launch_bounds__(256) void to_bdt(
    const float* __restrict__ h, float* __restrict__ dst) {
    int d = threadIdx.x;
    int t = blockIdx.x;
    int b = blockIdx.z;
    dst[((size_t)b * D_ + d) * T_ + t] = h[((size_t)b * T_ + t) * D_ + d];
}

// ---------------- banded attention: one wave per (b,h,q) row
__global__ __launch_bounds__(64) void attn_kernel(
    const float* __restrict__ qkv, float* __restrict__ out) {
    int qi = blockIdx.x, hh = blockIdx.y, b = blockIdx.z;
    int lane = threadIdx.x;
    const float* qptr = qkv + ((size_t)(b * T_ + qi)) * 768 + hh * 32;
    int jstart = qi >= WIN_ ? qi - WIN_ : 0;
    int n = (qi == 0) ? 1 : (qi - jstart);
    float s = -1e30f;
    if (lane < n) {
        int j = jstart + lane;
        const float* kptr = qkv + ((size_t)(b * T_ + j)) * 768 + 256 + hh * 32;
        float acc = 0.f;
#pragma unroll
        for (int d = 0; d < 32; d += 4) {
            acc += qptr[d] * kptr[d] + qptr[d + 1] * kptr[d + 1] +
                   qptr[d + 2] * kptr[d + 2] + qptr[d + 3] * kptr[d + 3];
        }
        s = acc * 0.17677669529663687f;  // 1/sqrt(32)
    }
    float m = s;
#pragma unroll
    for (int off = 32; off; off >>= 1) m = fmaxf(m, __shfl_xor(m, off));
    float p = (lane < n) ? __expf(s - m) : 0.f;
    float sum = p;
#pragma unroll
    for (int off = 32; off; off >>= 1) sum += __shfl_xor(sum, off);
    float a = p / sum;
    __shared__ float a_s[64];
    a_s[lane] = a;
    __syncthreads();
    if (lane < 32) {
        float o = 0.f;
        for (int jj = 0; jj < n; ++jj) {
            const float* vptr = qkv + ((size_t)(b * T_ + jstart + jj)) * 768 + 512 + hh * 32;
            o += a_s[jj] * vptr[lane];
        }
        out[((size_t)(b * T_ + qi)) * D_ + hh * 32 + lane] = o;
    }
}

// ---------------- residual add + row LayerNorm over D=256, in-place on h
__global__ __launch_bounds__(64) void ln_row(
    float* __restrict__ h, const float* __restrict__ o,
    const float* __restrict__ w, const float* __restrict__ bb) {
    int r = blockIdx.x;
    int lane = threadIdx.x;
    float x[4];
    float s = 0.f;
#pragma unroll
    for (int i = 0; i < 4; ++i) {
        int idx = i * 64 + lane;
        x[i] = h[(size_t)r * D_ + idx] + o[(size_t)r * D_ + idx];
        s += x[i];
    }
#pragma unroll
    for (int off = 32; off; off >>= 1) s += __shfl_xor(s, off);
    float mu = s * (1.f / D_);
    float ss = 0.f;
#pragma unroll
    for (int i = 0; i < 4; ++i) { float d = x[i] - mu; ss += d * d; }
#pragma unroll
    for (int off = 32; off; off >>= 1) ss += __shfl_xor(ss, off);
    float rstd = rsqrtf(ss * (1.f / D_) + 1e-5f);
#pragma unroll
    for (int i = 0; i < 4; ++i) {
        int idx = i * 64 + lane;
        h[(size_t)r * D_ + idx] = (x[i] - mu) * rstd * w[idx] + bb[idx];
    }
}

extern "C" void kernel_launch(void* const* d_in, const int* in_sizes, int n_in,
                              void* d_out, int out_size, void* d_ws, size_t ws_size,
                              hipStream_t stream) {
    const float* x        = (const float*)d_in[0];
    const float* pre_w0   = (const float*)d_in[1];
    const float* pre_b0   = (const float*)d_in[2];
    const float* pre_lnw0 = (const float*)d_in[3];
    const float* pre_lnb0 = (const float*)d_in[4];
    const float* pre_w1   = (const float*)d_in[5];
    const float* pre_b1   = (const float*)d_in[6];
    const float* pre_lnw1 = (const float*)d_in[7];
    const float* pre_lnb1 = (const float*)d_in[8];
    const float* pos_emb  = (const float*)d_in[9];
    const float* Wqkv     = (const float*)d_in[10];
    const float* bqkv     = (const float*)d_in[11];
    const float* Wo       = (const float*)d_in[12];
    const float* bo       = (const float*)d_in[13];
    const float* ln1w     = (const float*)d_in[14];
    const float* ln1b     = (const float*)d_in[15];
    const float* W1       = (const float*)d_in[16];
    const float* b1       = (const float*)d_in[17];
    const float* W2       = (const float*)d_in[18];
    const float* b2       = (const float*)d_in[19];
    const float* ln2w     = (const float*)d_in[20];
    const float* ln2b     = (const float*)d_in[21];
    const float* post_w0  = (const float*)d_in[22];
    const float* post_b0  = (const float*)d_in[23];
    const float* post_lnw0= (const float*)d_in[24];
    const float* post_lnb0= (const float*)d_in[25];
    const float* post_w1  = (const float*)d_in[26];
    const float* post_b1  = (const float*)d_in[27];
    const float* post_lnw1= (const float*)d_in[28];
    const float* post_lnb1= (const float*)d_in[29];

    float* ws = (float*)d_ws;
    const size_t M1 = 1u << 20;           // 1M floats
    float* H    = ws;                     // [B,T,D]      1M
    float* QKV  = ws + 1 * M1;            // [B,T,3D]     3M (also A0/A1 conv bufs)
    float* A0   = QKV;                    // [B,D,T]      1M
    float* A1   = QKV + M1;               // [B,D,T]      1M
    float* F    = ws + 4 * M1;            // [B,T,DFF]    2M
    float* ATT  = ws + 6 * M1;            // [B,T,D]      1M
    float* G    = ws + 7 * M1;            // [B,T,D]      1M
    float* Acol = F;                      // [B*T, 768]   3M (aliases F+ATT; dead in transformer)
    float* red  = ws + 8 * M1;            // 8 floats
    float* part = red + 16;               // B*NC*2 floats

    const int M = B_ * T_;  // 4096

    // ---- pre stage: conv = im2col + MFMA GEMM (transposed epilogue -> [B,O,T])
    im2col_kernel<<<dim3(T_ / 32, B_), 256, CIN_ * 34 * 4, stream>>>(x, Acol, CIN_);
    gemm_mfma<0, 1><<<dim3(D_ / 128, M / 128), 256, 0, stream>>>(
        Acol, pre_w0, pre_b0, A0, M, D_, CIN_ * 3);
    ln2d_partial<<<dim3(NC_, B_), 256, 0, stream>>>(A0, part, D_ * T_);
    ln2d_final<<<B_, 64, 0, stream>>>(part, red, D_ * T_);
    ln2d_apply<<<dim3(D_ * T_ / 1024, B_), 256, 0, stream>>>(A0, pre_lnw0, pre_lnb0, red, A1, D_ * T_);

    im2col_kernel<<<dim3(T_ / 32, B_), 256, D_ * 34 * 4, stream>>>(A1, Acol, D_);
    gemm_mfma<0, 1><<<dim3(D_ / 128, M / 128), 256, 0, stream>>>(
        Acol, pre_w1, pre_b1, A0, M, D_, D_ * 3);
    ln2d_partial<<<dim3(NC_, B_), 256, 0, stream>>>(A0, part, D_ * T_);
    ln2d_final<<<B_, 64, 0, stream>>>(part, red, D_ * T_);
    ln2d_apply<<<dim3(D_ * T_ / 1024, B_), 256, 0, stream>>>(A0, pre_lnw1, pre_lnb1, red, A1, D_ * T_);
    to_btd<<<dim3(T_, 1, B_), 256, 0, stream>>>(A1, pos_emb, H);

    // ---- transformer layers
    for (int l = 0; l < L_; ++l) {
        gemm_mfma<0, 0><<<dim3(768 / 128, M / 128), 256, 0, stream>>>(
            H, Wqkv + (size_t)l * 768 * D_, bqkv + (size_t)l * 768, QKV, M, 768, D_);
        attn_kernel<<<dim3(T_, H_, B_), 64, 0, stream>>>(QKV, ATT);
        gemm_mfma<0, 0><<<dim3(D_ / 128, M / 128), 256, 0, stream>>>(
            ATT, Wo + (size_t)l * D_ * D_, bo + (size_t)l * D_, G, M, D_, D_);
        ln_row<<<M, 64, 0, stream>>>(H, G, ln1w + (size_t)l * D_, ln1b + (size_t)l * D_);
        gemm_mfma<1, 0><<<dim3(DFF_ / 128, M / 128), 256, 0, stream>>>(
            H, W1 + (size_t)l * DFF_ * D_, b1 + (size_t)l * DFF_, F, M, DFF_, D_);
        gemm_mfma<0, 0><<<dim3(D_ / 128, M / 128), 256, 0, stream>>>(
            F, W2 + (size_t)l * D_ * DFF_, b2 + (size_t)l * D_, G, M, D_, DFF_);
        ln_row<<<M, 64, 0, stream>>>(H, G, ln2w + (size_t)l * D_, ln2b + (size_t)l * D_);
    }

    // ---- post stage
    to_bdt<<<dim3(T_, 1, B_), 256, 0, stream>>>(H, A0);
    im2col_kernel<<<dim3(T_ / 32, B_), 256, D_ * 34 * 4, stream>>>(A0, Acol, D_);
    gemm_mfma<0, 1><<<dim3(D_ / 128, M / 128), 256, 0, stream>>>(
        Acol, post_w0, post_b0, A1, M, D_, D_ * 3);
    ln2d_partial<<<dim3(NC_, B_), 256, 0, stream>>>(A1, part, D_ * T_);
    ln2d_final<<<B_, 64, 0, stream>>>(part, red, D_ * T_);
    ln2d_apply<<<dim3(D_ * T_ / 1024, B_), 256, 0, stream>>>(A1, post_lnw0, post_lnb0, red, A0, D_ * T_);

    im2col_kernel<<<dim3(T_ / 32, B_), 256, D_ * 34 * 4, stream>>>(A0, Acol, D_);
    gemm_mfma<0, 1><<<dim3(CIN_ / 128, M / 128), 256, 0, stream>>>(
        Acol, post_w1, post_b1, A1, M, CIN_, D_ * 3);
    ln2d_partial<<<dim3(NC_, B_), 256, 0, stream>>>(A1, part, CIN_ * T_);
    ln2d_final<<<B_, 64, 0, stream>>>(part, red, CIN_ * T_);
    ln2d_apply<<<dim3(CIN_ * T_ / 1024, B_), 256, 0, stream>>>(A1, post_lnw1, post_lnb1, red,
                                                              (float*)d_out, CIN_ * T_);
}

// Round 5
// 539.084 us; speedup vs baseline: 4.2800x; 1.3090x over previous
//
#include <hip/hip_runtime.h>
#include <hip/hip_bf16.h>

#define B_ 4
#define T_ 1024
#define D_ 256
#define H_ 8
#define WIN_ 64
#define CIN_ 128
#define DH_ 32
#define DFF_ 512
#define L_ 4
#define NC_ 32   // LN2d reduction chunks per batch
#define PSTR 152 // Ps/Vt LDS row stride (shorts): 304B, 16B-aligned, low-conflict

typedef __attribute__((ext_vector_type(4))) short s16x4;
typedef __attribute__((ext_vector_type(8))) short s16x8;
typedef __attribute__((ext_vector_type(4))) float f32x4;

__device__ inline short f2bf(float f) {
    __hip_bfloat16 h = __float2bfloat16(f);
    return *reinterpret_cast<short*>(&h);
}

// ---------------- im2col (channel-major input): Acol[(b*T+t)][i*3+k] = x[b,i,t+k-1]
__global__ __launch_bounds__(256) void im2col_kernel(
    const float* __restrict__ x, float* __restrict__ Acol, int I) {
    const int K = I * 3;
    int t0 = blockIdx.x * 32;
    int b = blockIdx.y;
    extern __shared__ float xs[];   // [I][34]
    for (int idx = threadIdx.x; idx < I * 34; idx += 256) {
        int i = idx / 34, tt = idx % 34;
        int tg = t0 - 1 + tt;
        xs[idx] = (tg >= 0 && tg < T_) ? x[((size_t)b * I + i) * T_ + tg] : 0.f;
    }
    __syncthreads();
    int nf4 = K / 4;
    for (int idx = threadIdx.x; idx < 32 * nf4; idx += 256) {
        int tl = idx / nf4, c4 = idx % nf4;
        int c = c4 * 4;
        float4 v;
        { int cc = c;     int i = cc / 3, k = cc - 3 * i; v.x = xs[i * 34 + tl + k]; }
        { int cc = c + 1; int i = cc / 3, k = cc - 3 * i; v.y = xs[i * 34 + tl + k]; }
        { int cc = c + 2; int i = cc / 3, k = cc - 3 * i; v.z = xs[i * 34 + tl + k]; }
        { int cc = c + 3; int i = cc / 3, k = cc - 3 * i; v.w = xs[i * 34 + tl + k]; }
        *(float4*)&Acol[((size_t)(b * T_ + t0 + tl)) * K + c] = v;
    }
}

// ---------------- bf16 MFMA GEMM: Y = A[M,K] @ W[N,K]^T + bias
template <int RELU, int TRANSOUT>
__global__ __launch_bounds__(256) void gemm_mfma(
    const float* __restrict__ A, const float* __restrict__ W,
    const float* __restrict__ bias, float* __restrict__ Y,
    int M, int N, int K) {
    __shared__ short Al[128 * 40];
    __shared__ short Wl[128 * 40];
    int tid = threadIdx.x;
    int row0 = blockIdx.y * 128, col0 = blockIdx.x * 128;
    int wave = tid >> 6, lane = tid & 63;
    int wr = wave >> 1, wc = wave & 1;
    f32x4 acc[4][4] = {};

    int srow = tid >> 3;            // 0..31
    int scol = (tid & 7) * 4;       // 0,4,..,28
    for (int k0 = 0; k0 < K; k0 += 32) {
#pragma unroll
        for (int p = 0; p < 4; ++p) {
            int rr = srow + p * 32;
            float4 va = *(const float4*)&A[(size_t)(row0 + rr) * K + k0 + scol];
            float4 vw = *(const float4*)&W[(size_t)(col0 + rr) * K + k0 + scol];
            s16x4 sa, sw;
            sa[0] = f2bf(va.x); sa[1] = f2bf(va.y); sa[2] = f2bf(va.z); sa[3] = f2bf(va.w);
            sw[0] = f2bf(vw.x); sw[1] = f2bf(vw.y); sw[2] = f2bf(vw.z); sw[3] = f2bf(vw.w);
            *(s16x4*)&Al[rr * 40 + scol] = sa;
            *(s16x4*)&Wl[rr * 40 + scol] = sw;
        }
        __syncthreads();
        s16x8 af[4], wf[4];
#pragma unroll
        for (int i = 0; i < 4; ++i) {
            af[i] = *(const s16x8*)&Al[(wr * 64 + i * 16 + (lane & 15)) * 40 + (lane >> 4) * 8];
            wf[i] = *(const s16x8*)&Wl[(wc * 64 + i * 16 + (lane & 15)) * 40 + (lane >> 4) * 8];
        }
#pragma unroll
        for (int i = 0; i < 4; ++i)
#pragma unroll
            for (int j = 0; j < 4; ++j)
                acc[i][j] = __builtin_amdgcn_mfma_f32_16x16x32_bf16(af[i], wf[j], acc[i][j], 0, 0, 0);
        __syncthreads();
    }

    if (TRANSOUT) {
        int b = row0 >> 10;
        int t0 = row0 & 1023;
#pragma unroll
        for (int i = 0; i < 4; ++i) {
            int tg = t0 + wr * 64 + i * 16 + (lane >> 4) * 4;
#pragma unroll
            for (int j = 0; j < 4; ++j) {
                int cg = col0 + wc * 64 + j * 16 + (lane & 15);
                float bv = bias[cg];
                float4 o;
                o.x = acc[i][j][0] + bv; o.y = acc[i][j][1] + bv;
                o.z = acc[i][j][2] + bv; o.w = acc[i][j][3] + bv;
                if (RELU) {
                    o.x = fmaxf(o.x, 0.f); o.y = fmaxf(o.y, 0.f);
                    o.z = fmaxf(o.z, 0.f); o.w = fmaxf(o.w, 0.f);
                }
                *(float4*)&Y[((size_t)(b * N + cg)) * 1024 + tg] = o;
            }
        }
    } else {
#pragma unroll
        for (int i = 0; i < 4; ++i) {
            int rg = row0 + wr * 64 + i * 16 + (lane >> 4) * 4;
#pragma unroll
            for (int j = 0; j < 4; ++j) {
                int cg = col0 + wc * 64 + j * 16 + (lane & 15);
                float bv = bias[cg];
#pragma unroll
                for (int q = 0; q < 4; ++q) {
                    float v = acc[i][j][q] + bv;
                    if (RELU) v = fmaxf(v, 0.f);
                    Y[(size_t)(rg + q) * N + cg] = v;
                }
            }
        }
    }
}

// ---------------- MFMA banded attention: one block per (64-q tile, head, batch)
// Window of keys [q0-64, q0+63] (128 wide) covers all rows' bands.
__global__ __launch_bounds__(256) void attn_mfma(
    const float* __restrict__ qkv, float* __restrict__ out) {
    int q0 = blockIdx.x * 64;
    int h = blockIdx.y, b = blockIdx.z;
    int tid = threadIdx.x;
    int wave = tid >> 6, lane = tid & 63;
    int lg = lane >> 4;   // 0..3
    int lr = lane & 15;   // 0..15
    const int j0 = q0 - 64;

    __shared__ short Qs[64][40];
    __shared__ short Ks[128][40];
    __shared__ short Vt[32][PSTR];
    __shared__ short Ps[64][PSTR];

    // Q: 64 rows x 32 dims
#pragma unroll
    for (int u = 0; u < 2; ++u) {
        int task = tid + 256 * u;         // 512 tasks
        int r = task >> 3, c = (task & 7) * 4;
        float4 v = *(const float4*)&qkv[((size_t)(b * T_ + q0 + r)) * 768 + h * 32 + c];
        s16x4 sa;
        sa[0] = f2bf(v.x); sa[1] = f2bf(v.y); sa[2] = f2bf(v.z); sa[3] = f2bf(v.w);
        *(s16x4*)&Qs[r][c] = sa;
    }
    // K: 128 rows (j0..j0+127), zero for j<0
#pragma unroll
    for (int u = 0; u < 4; ++u) {
        int task = tid + 256 * u;         // 1024 tasks
        int r = task >> 3, c = (task & 7) * 4;
        int jg = j0 + r;
        s16x4 sa = {0, 0, 0, 0};
        if (jg >= 0) {
            float4 v = *(const float4*)&qkv[((size_t)(b * T_ + jg)) * 768 + 256 + h * 32 + c];
            sa[0] = f2bf(v.x); sa[1] = f2bf(v.y); sa[2] = f2bf(v.z); sa[3] = f2bf(v.w);
        }
        *(s16x4*)&Ks[r][c] = sa;
    }
    // V transposed: Vt[d][jl]
#pragma unroll
    for (int u = 0; u < 4; ++u) {
        int task = tid + 256 * u;
        int r = task >> 3, c = (task & 7) * 4;
        int jg = j0 + r;
        float4 v = {0.f, 0.f, 0.f, 0.f};
        if (jg >= 0)
            v = *(const float4*)&qkv[((size_t)(b * T_ + jg)) * 768 + 512 + h * 32 + c];
        Vt[c + 0][r] = f2bf(v.x);
        Vt[c + 1][r] = f2bf(v.y);
        Vt[c + 2][r] = f2bf(v.z);
        Vt[c + 3][r] = f2bf(v.w);
    }
    __syncthreads();

    // S = Q @ K^T for this wave's 16 q-rows
    s16x8 aq = *(const s16x8*)&Qs[16 * wave + lr][lg * 8];
    f32x4 sacc[8];
#pragma unroll
    for (int j = 0; j < 8; ++j) {
        s16x8 bk = *(const s16x8*)&Ks[16 * j + lr][lg * 8];
        f32x4 z = {0.f, 0.f, 0.f, 0.f};
        sacc[j] = __builtin_amdgcn_mfma_f32_16x16x32_bf16(aq, bk, z, 0, 0, 0);
    }

    const float scale = 0.17677669529663687f;  // 1/sqrt(32)
    // mask + scale (C layout: row = lg*4 + q, col = 16j + lr)
#pragma unroll
    for (int j = 0; j < 8; ++j) {
        int jg = j0 + 16 * j + lr;
#pragma unroll
        for (int q = 0; q < 4; ++q) {
            int qi = q0 + 16 * wave + lg * 4 + q;
            bool ok = ((jg >= qi - WIN_) && (jg < qi) && (jg >= 0)) || (qi == 0 && jg == 0);
            sacc[j][q] = ok ? sacc[j][q] * scale : -1e30f;
        }
    }
    // row softmax (reduce across the 16 lanes of the column group)
#pragma unroll
    for (int q = 0; q < 4; ++q) {
        float m = sacc[0][q];
#pragma unroll
        for (int j = 1; j < 8; ++j) m = fmaxf(m, sacc[j][q]);
#pragma unroll
        for (int off = 1; off < 16; off <<= 1) m = fmaxf(m, __shfl_xor(m, off));
        float e[8], sum = 0.f;
#pragma unroll
        for (int j = 0; j < 8; ++j) { e[j] = __expf(sacc[j][q] - m); sum += e[j]; }
#pragma unroll
        for (int off = 1; off < 16; off <<= 1) sum += __shfl_xor(sum, off);
        float inv = 1.f / sum;
        int row = 16 * wave + lg * 4 + q;
#pragma unroll
        for (int j = 0; j < 8; ++j) Ps[row][16 * j + lr] = f2bf(e[j] * inv);
    }

    // O = P @ V  (wave reads only its own 16-row P stripe)
    f32x4 oacc[2] = {};
#pragma unroll
    for (int kk = 0; kk < 4; ++kk) {
        s16x8 ap = *(const s16x8*)&Ps[16 * wave + lr][kk * 32 + lg * 8];
#pragma unroll
        for (int n = 0; n < 2; ++n) {
            s16x8 bv = *(const s16x8*)&Vt[16 * n + lr][kk * 32 + lg * 8];
            oacc[n] = __builtin_amdgcn_mfma_f32_16x16x32_bf16(ap, bv, oacc[n], 0, 0, 0);
        }
    }
#pragma unroll
    for (int n = 0; n < 2; ++n)
#pragma unroll
        for (int q = 0; q < 4; ++q) {
            int qi = q0 + 16 * wave + lg * 4 + q;
            out[((size_t)(b * T_ + qi)) * D_ + h * 32 + 16 * n + lr] = oacc[n][q];
        }
}

// ---------------- LN2d stage A
__global__ __launch_bounds__(256) void ln2d_partial(
    const float* __restrict__ x, float* __restrict__ part, int CT) {
    int b = blockIdx.y;
    int chunk = blockIdx.x;
    int n4 = CT / (4 * NC_);
    const float4* xb = (const float4*)(x + (size_t)b * CT) + (size_t)chunk * n4;
    float s = 0.f, ss = 0.f;
    for (int i = threadIdx.x; i < n4; i += 256) {
        float4 v = xb[i];
        s += v.x + v.y + v.z + v.w;
        ss += v.x * v.x + v.y * v.y + v.z * v.z + v.w * v.w;
    }
#pragma unroll
    for (int off = 32; off; off >>= 1) {
        s += __shfl_xor(s, off);
        ss += __shfl_xor(ss, off);
    }
    __shared__ float sh0[4], sh1[4];
    int wave = threadIdx.x >> 6;
    if ((threadIdx.x & 63) == 0) { sh0[wave] = s; sh1[wave] = ss; }
    __syncthreads();
    if (threadIdx.x == 0) {
        part[(size_t)(b * NC_ + chunk) * 2] = sh0[0] + sh0[1] + sh0[2] + sh0[3];
        part[(size_t)(b * NC_ + chunk) * 2 + 1] = sh1[0] + sh1[1] + sh1[2] + sh1[3];
    }
}

// ---------------- LN2d stage B
__global__ __launch_bounds__(64) void ln2d_final(
    const float* __restrict__ part, float* __restrict__ red, int CT) {
    int b = blockIdx.x;
    int lane = threadIdx.x;
    float s = 0.f, ss = 0.f;
    if (lane < NC_) {
        s = part[(size_t)(b * NC_ + lane) * 2];
        ss = part[(size_t)(b * NC_ + lane) * 2 + 1];
    }
#pragma unroll
    for (int off = 32; off; off >>= 1) {
        s += __shfl_xor(s, off);
        ss += __shfl_xor(ss, off);
    }
    if (lane == 0) {
        float mu = s / (float)CT;
        float var = ss / (float)CT - mu * mu;
        red[2 * b] = mu;
        red[2 * b + 1] = rsqrtf(var + 1e-5f);
    }
}

// ---------------- LN2d apply + ReLU (float4)
__global__ __launch_bounds__(256) void ln2d_apply(
    const float* __restrict__ x, const float* __restrict__ w,
    const float* __restrict__ bb, const float* __restrict__ red,
    float* __restrict__ y, int CT) {
    int idx = blockIdx.x * 256 + threadIdx.x;
    int b = blockIdx.y;
    float mu = red[2 * b], rstd = red[2 * b + 1];
    const float4* x4 = (const float4*)(x + (size_t)b * CT);
    const float4* w4 = (const float4*)w;
    const float4* b4 = (const float4*)bb;
    float4* y4 = (float4*)(y + (size_t)b * CT);
    float4 v = x4[idx], wv = w4[idx], bv = b4[idx];
    float4 r;
    r.x = fmaxf((v.x - mu) * rstd * wv.x + bv.x, 0.f);
    r.y = fmaxf((v.y - mu) * rstd * wv.y + bv.y, 0.f);
    r.z = fmaxf((v.z - mu) * rstd * wv.z + bv.z, 0.f);
    r.w = fmaxf((v.w - mu) * rstd * wv.w + bv.w, 0.f);
    y4[idx] = r;
}

// ---------------- [B,D,T] -> [B,T,D] with pos add
__global__ __launch_bounds__(256) void to_btd(
    const float* __restrict__ src, const float* __restrict__ pos, float* __restrict__ h) {
    int d = threadIdx.x;
    int t = blockIdx.x;
    int b = blockIdx.z;
    h[((size_t)b * T_ + t) * D_ + d] = src[((size_t)b * D_ + d) * T_ + t] + pos[(size_t)t * D_ + d];
}

// ---------------- [B,T,D] -> [B,D,T]
__global__ __launch_bounds__(256) void to_bdt(
    const float* __restrict__ h, float* __restrict__ dst) {
    int d = threadIdx.x;
    int t = blockIdx.x;
    int b = blockIdx.z;
    dst[((size_t)b * D_ + d) * T_ + t] = h[((size_t)b * T_ + t) * D_ + d];
}

// ---------------- residual add + row LayerNorm over D=256, in-place on h
__global__ __launch_bounds__(64) void ln_row(
    float* __restrict__ h, const float* __restrict__ o,
    const float* __restrict__ w, const float* __restrict__ bb) {
    int r = blockIdx.x;
    int lane = threadIdx.x;
    float x[4];
    float s = 0.f;
#pragma unroll
    for (int i = 0; i < 4; ++i) {
        int idx = i * 64 + lane;
        x[i] = h[(size_t)r * D_ + idx] + o[(size_t)r * D_ + idx];
        s += x[i];
    }
#pragma unroll
    for (int off = 32; off; off >>= 1) s += __shfl_xor(s, off);
    float mu = s * (1.f / D_);
    float ss = 0.f;
#pragma unroll
    for (int i = 0; i < 4; ++i) { float d = x[i] - mu; ss += d * d; }
#pragma unroll
    for (int off = 32; off; off >>= 1) ss += __shfl_xor(ss, off);
    float rstd = rsqrtf(ss * (1.f / D_) + 1e-5f);
#pragma unroll
    for (int i = 0; i < 4; ++i) {
        int idx = i * 64 + lane;
        h[(size_t)r * D_ + idx] = (x[i] - mu) * rstd * w[idx] + bb[idx];
    }
}

extern "C" void kernel_launch(void* const* d_in, const int* in_sizes, int n_in,
                              void* d_out, int out_size, void* d_ws, size_t ws_size,
                              hipStream_t stream) {
    const float* x        = (const float*)d_in[0];
    const float* pre_w0   = (const float*)d_in[1];
    const float* pre_b0   = (const float*)d_in[2];
    const float* pre_lnw0 = (const float*)d_in[3];
    const float* pre_lnb0 = (const float*)d_in[4];
    const float* pre_w1   = (const float*)d_in[5];
    const float* pre_b1   = (const float*)d_in[6];
    const float* pre_lnw1 = (const float*)d_in[7];
    const float* pre_lnb1 = (const float*)d_in[8];
    const float* pos_emb  = (const float*)d_in[9];
    const float* Wqkv     = (const float*)d_in[10];
    const float* bqkv     = (const float*)d_in[11];
    const float* Wo       = (const float*)d_in[12];
    const float* bo       = (const float*)d_in[13];
    const float* ln1w     = (const float*)d_in[14];
    const float* ln1b     = (const float*)d_in[15];
    const float* W1       = (const float*)d_in[16];
    const float* b1       = (const float*)d_in[17];
    const float* W2       = (const float*)d_in[18];
    const float* b2       = (const float*)d_in[19];
    const float* ln2w     = (const float*)d_in[20];
    const float* ln2b     = (const float*)d_in[21];
    const float* post_w0  = (const float*)d_in[22];
    const float* post_b0  = (const float*)d_in[23];
    const float* post_lnw0= (const float*)d_in[24];
    const float* post_lnb0= (const float*)d_in[25];
    const float* post_w1  = (const float*)d_in[26];
    const float* post_b1  = (const float*)d_in[27];
    const float* post_lnw1= (const float*)d_in[28];
    const float* post_lnb1= (const float*)d_in[29];

    float* ws = (float*)d_ws;
    const size_t M1 = 1u << 20;           // 1M floats
    float* H    = ws;                     // [B,T,D]      1M
    float* QKV  = ws + 1 * M1;            // [B,T,3D]     3M (also A0/A1 conv bufs)
    float* A0   = QKV;                    // [B,D,T]      1M
    float* A1   = QKV + M1;               // [B,D,T]      1M
    float* F    = ws + 4 * M1;            // [B,T,DFF]    2M
    float* ATT  = ws + 6 * M1;            // [B,T,D]      1M
    float* G    = ws + 7 * M1;            // [B,T,D]      1M
    float* Acol = F;                      // [B*T, 768]   3M (aliases F+ATT; dead in transformer)
    float* red  = ws + 8 * M1;            // 8 floats
    float* part = red + 16;               // B*NC*2 floats

    const int M = B_ * T_;  // 4096

    // ---- pre stage: conv = im2col + MFMA GEMM (transposed epilogue -> [B,O,T])
    im2col_kernel<<<dim3(T_ / 32, B_), 256, CIN_ * 34 * 4, stream>>>(x, Acol, CIN_);
    gemm_mfma<0, 1><<<dim3(D_ / 128, M / 128), 256, 0, stream>>>(
        Acol, pre_w0, pre_b0, A0, M, D_, CIN_ * 3);
    ln2d_partial<<<dim3(NC_, B_), 256, 0, stream>>>(A0, part, D_ * T_);
    ln2d_final<<<B_, 64, 0, stream>>>(part, red, D_ * T_);
    ln2d_apply<<<dim3(D_ * T_ / 1024, B_), 256, 0, stream>>>(A0, pre_lnw0, pre_lnb0, red, A1, D_ * T_);

    im2col_kernel<<<dim3(T_ / 32, B_), 256, D_ * 34 * 4, stream>>>(A1, Acol, D_);
    gemm_mfma<0, 1><<<dim3(D_ / 128, M / 128), 256, 0, stream>>>(
        Acol, pre_w1, pre_b1, A0, M, D_, D_ * 3);
    ln2d_partial<<<dim3(NC_, B_), 256, 0, stream>>>(A0, part, D_ * T_);
    ln2d_final<<<B_, 64, 0, stream>>>(part, red, D_ * T_);
    ln2d_apply<<<dim3(D_ * T_ / 1024, B_), 256, 0, stream>>>(A0, pre_lnw1, pre_lnb1, red, A1, D_ * T_);
    to_btd<<<dim3(T_, 1, B_), 256, 0, stream>>>(A1, pos_emb, H);

    // ---- transformer layers
    for (int l = 0; l < L_; ++l) {
        gemm_mfma<0, 0><<<dim3(768 / 128, M / 128), 256, 0, stream>>>(
            H, Wqkv + (size_t)l * 768 * D_, bqkv + (size_t)l * 768, QKV, M, 768, D_);
        attn_mfma<<<dim3(T_ / 64, H_, B_), 256, 0, stream>>>(QKV, ATT);
        gemm_mfma<0, 0><<<dim3(D_ / 128, M / 128), 256, 0, stream>>>(
            ATT, Wo + (size_t)l * D_ * D_, bo + (size_t)l * D_, G, M, D_, D_);
        ln_row<<<M, 64, 0, stream>>>(H, G, ln1w + (size_t)l * D_, ln1b + (size_t)l * D_);
        gemm_mfma<1, 0><<<dim3(DFF_ / 128, M / 128), 256, 0, stream>>>(
            H, W1 + (size_t)l * DFF_ * D_, b1 + (size_t)l * DFF_, F, M, DFF_, D_);
        gemm_mfma<0, 0><<<dim3(D_ / 128, M / 128), 256, 0, stream>>>(
            F, W2 + (size_t)l * D_ * DFF_, b2 + (size_t)l * D_, G, M, D_, DFF_);
        ln_row<<<M, 64, 0, stream>>>(H, G, ln2w + (size_t)l * D_, ln2b + (size_t)l * D_);
    }

    // ---- post stage
    to_bdt<<<dim3(T_, 1, B_), 256, 0, stream>>>(H, A0);
    im2col_kernel<<<dim3(T_ / 32, B_), 256, D_ * 34 * 4, stream>>>(A0, Acol, D_);
    gemm_mfma<0, 1><<<dim3(D_ / 128, M / 128), 256, 0, stream>>>(
        Acol, post_w0, post_b0, A1, M, D_, D_ * 3);
    ln2d_partial<<<dim3(NC_, B_), 256, 0, stream>>>(A1, part, D_ * T_);
    ln2d_final<<<B_, 64, 0, stream>>>(part, red, D_ * T_);
    ln2d_apply<<<dim3(D_ * T_ / 1024, B_), 256, 0, stream>>>(A1, post_lnw0, post_lnb0, red, A0, D_ * T_);

    im2col_kernel<<<dim3(T_ / 32, B_), 256, D_ * 34 * 4, stream>>>(A0, Acol, D_);
    gemm_mfma<0, 1><<<dim3(CIN_ / 128, M / 128), 256, 0, stream>>>(
        Acol, post_w1, post_b1, A1, M, CIN_, D_ * 3);
    ln2d_partial<<<dim3(NC_, B_), 256, 0, stream>>>(A1, part, CIN_ * T_);
    ln2d_final<<<B_, 64, 0, stream>>>(part, red, CIN_ * T_);
    ln2d_apply<<<dim3(CIN_ * T_ / 1024, B_), 256, 0, stream>>>(A1, post_lnw1, post_lnb1, red,
                                                              (float*)d_out, CIN_ * T_);
}

// Round 8
// 440.344 us; speedup vs baseline: 5.2397x; 1.2242x over previous
//
#include <hip/hip_runtime.h>
#include <hip/hip_bf16.h>

#define B_ 4
#define T_ 1024
#define D_ 256
#define H_ 8
#define WIN_ 64
#define CIN_ 128
#define DH_ 32
#define DFF_ 512
#define L_ 4
#define NC_ 32   // LN2d reduction chunks per batch
#define PSTR 152 // Ps/Vt LDS row stride (shorts)

typedef __attribute__((ext_vector_type(4))) short s16x4;
typedef __attribute__((ext_vector_type(8))) short s16x8;
typedef __attribute__((ext_vector_type(4))) float f32x4;

__device__ inline short f2bf(float f) {
    __hip_bfloat16 h = __float2bfloat16(f);
    return *reinterpret_cast<short*>(&h);
}

// ---------------- im2col from [B,I,T]: Acol[(b*T+t)][i*3+k] = x[b,i,t+k-1]
__global__ __launch_bounds__(256) void im2col_kernel(
    const float* __restrict__ x, float* __restrict__ Acol, int I) {
    const int K = I * 3;
    int t0 = blockIdx.x * 32;
    int b = blockIdx.y;
    extern __shared__ float xs[];   // [I][34]
    for (int idx = threadIdx.x; idx < I * 34; idx += 256) {
        int i = idx / 34, tt = idx % 34;
        int tg = t0 - 1 + tt;
        xs[idx] = (tg >= 0 && tg < T_) ? x[((size_t)b * I + i) * T_ + tg] : 0.f;
    }
    __syncthreads();
    int nf4 = K / 4;
    for (int idx = threadIdx.x; idx < 32 * nf4; idx += 256) {
        int tl = idx / nf4, c4 = idx % nf4;
        int c = c4 * 4;
        float4 v;
        { int cc = c;     int i = cc / 3, k = cc - 3 * i; v.x = xs[i * 34 + tl + k]; }
        { int cc = c + 1; int i = cc / 3, k = cc - 3 * i; v.y = xs[i * 34 + tl + k]; }
        { int cc = c + 2; int i = cc / 3, k = cc - 3 * i; v.z = xs[i * 34 + tl + k]; }
        { int cc = c + 3; int i = cc / 3, k = cc - 3 * i; v.w = xs[i * 34 + tl + k]; }
        *(float4*)&Acol[((size_t)(b * T_ + t0 + tl)) * K + c] = v;
    }
}

// ---------------- im2col from [B,T,D]: Acol[(b*T+t)][i*3+k] = h[b,t+k-1,i]  (I=D_)
__global__ __launch_bounds__(256) void im2col_btd(
    const float* __restrict__ h, float* __restrict__ Acol) {
    int t0 = blockIdx.x * 32;
    int b = blockIdx.y;
    __shared__ float xs[D_ * 35];   // [i][tt], stride 35
    for (int idx = threadIdx.x; idx < 34 * (D_ / 4); idx += 256) {
        int tt = idx >> 6, i4 = (idx & 63) * 4;
        int tg = t0 - 1 + tt;
        float4 v = {0.f, 0.f, 0.f, 0.f};
        if (tg >= 0 && tg < T_) v = *(const float4*)&h[((size_t)(b * T_ + tg)) * D_ + i4];
        xs[(i4 + 0) * 35 + tt] = v.x;
        xs[(i4 + 1) * 35 + tt] = v.y;
        xs[(i4 + 2) * 35 + tt] = v.z;
        xs[(i4 + 3) * 35 + tt] = v.w;
    }
    __syncthreads();
    const int K = D_ * 3;
    const int nf4 = K / 4;
    for (int idx = threadIdx.x; idx < 32 * nf4; idx += 256) {
        int tl = idx / nf4, c4 = idx % nf4;
        int c = c4 * 4;
        float4 v;
        { int cc = c;     int i = cc / 3, k = cc - 3 * i; v.x = xs[i * 35 + tl + k]; }
        { int cc = c + 1; int i = cc / 3, k = cc - 3 * i; v.y = xs[i * 35 + tl + k]; }
        { int cc = c + 2; int i = cc / 3, k = cc - 3 * i; v.z = xs[i * 35 + tl + k]; }
        { int cc = c + 3; int i = cc / 3, k = cc - 3 * i; v.w = xs[i * 35 + tl + k]; }
        *(float4*)&Acol[((size_t)(b * T_ + t0 + tl)) * K + c] = v;
    }
}

// ---------------- bf16 MFMA GEMM, 64x64 tile, BK=32: Y = A[M,K] @ W[N,K]^T + bias
// TRANSOUT=0: Y[M,N]. TRANSOUT=1: Y[B][N][1024], row r = b*1024+t.
template <int RELU, int TRANSOUT>
__global__ __launch_bounds__(256) void gemm64(
    const float* __restrict__ A, const float* __restrict__ W,
    const float* __restrict__ bias, float* __restrict__ Y,
    int M, int N, int K) {
    __shared__ short Al[64 * 40];
    __shared__ short Wl[64 * 40];
    int tid = threadIdx.x;
    int row0 = blockIdx.y * 64, col0 = blockIdx.x * 64;
    int wave = tid >> 6, lane = tid & 63;
    int wr = wave >> 1, wc = wave & 1;
    int lg = lane >> 4, lr = lane & 15;
    f32x4 acc[2][2] = {};

    int srow = tid >> 3;            // 0..31
    int scol = (tid & 7) * 4;       // 0,4,..,28
    for (int k0 = 0; k0 < K; k0 += 32) {
#pragma unroll
        for (int p = 0; p < 2; ++p) {
            int rr = srow + p * 32;
            float4 va = *(const float4*)&A[(size_t)(row0 + rr) * K + k0 + scol];
            float4 vw = *(const float4*)&W[(size_t)(col0 + rr) * K + k0 + scol];
            s16x4 sa, sw;
            sa[0] = f2bf(va.x); sa[1] = f2bf(va.y); sa[2] = f2bf(va.z); sa[3] = f2bf(va.w);
            sw[0] = f2bf(vw.x); sw[1] = f2bf(vw.y); sw[2] = f2bf(vw.z); sw[3] = f2bf(vw.w);
            *(s16x4*)&Al[rr * 40 + scol] = sa;
            *(s16x4*)&Wl[rr * 40 + scol] = sw;
        }
        __syncthreads();
        s16x8 af[2], wf[2];
#pragma unroll
        for (int i = 0; i < 2; ++i) {
            af[i] = *(const s16x8*)&Al[(wr * 32 + i * 16 + lr) * 40 + lg * 8];
            wf[i] = *(const s16x8*)&Wl[(wc * 32 + i * 16 + lr) * 40 + lg * 8];
        }
#pragma unroll
        for (int i = 0; i < 2; ++i)
#pragma unroll
            for (int j = 0; j < 2; ++j)
                acc[i][j] = __builtin_amdgcn_mfma_f32_16x16x32_bf16(af[i], wf[j], acc[i][j], 0, 0, 0);
        __syncthreads();
    }

    if (TRANSOUT) {
        int b = row0 >> 10;
        int t0 = row0 & 1023;
#pragma unroll
        for (int i = 0; i < 2; ++i) {
            int tg = t0 + wr * 32 + i * 16 + lg * 4;
#pragma unroll
            for (int j = 0; j < 2; ++j) {
                int cg = col0 + wc * 32 + j * 16 + lr;
                float bv = bias[cg];
                float4 o;
                o.x = acc[i][j][0] + bv; o.y = acc[i][j][1] + bv;
                o.z = acc[i][j][2] + bv; o.w = acc[i][j][3] + bv;
                if (RELU) {
                    o.x = fmaxf(o.x, 0.f); o.y = fmaxf(o.y, 0.f);
                    o.z = fmaxf(o.z, 0.f); o.w = fmaxf(o.w, 0.f);
                }
                *(float4*)&Y[((size_t)(b * N + cg)) * 1024 + tg] = o;
            }
        }
    } else {
#pragma unroll
        for (int i = 0; i < 2; ++i) {
            int rg = row0 + wr * 32 + i * 16 + lg * 4;
#pragma unroll
            for (int j = 0; j < 2; ++j) {
                int cg = col0 + wc * 32 + j * 16 + lr;
                float bv = bias[cg];
#pragma unroll
                for (int q = 0; q < 4; ++q) {
                    float v = acc[i][j][q] + bv;
                    if (RELU) v = fmaxf(v, 0.f);
                    Y[(size_t)(rg + q) * N + cg] = v;
                }
            }
        }
    }
}

// ---------------- MFMA banded attention: one block per (64-q tile, head, batch)
__global__ __launch_bounds__(256) void attn_mfma(
    const float* __restrict__ qkv, float* __restrict__ out) {
    int q0 = blockIdx.x * 64;
    int h = blockIdx.y, b = blockIdx.z;
    int tid = threadIdx.x;
    int wave = tid >> 6, lane = tid & 63;
    int lg = lane >> 4;
    int lr = lane & 15;
    const int j0 = q0 - 64;

    __shared__ short Qs[64][40];
    __shared__ short Ks[128][40];
    __shared__ short Vt[32][PSTR];
    __shared__ short Ps[64][PSTR];

#pragma unroll
    for (int u = 0; u < 2; ++u) {
        int task = tid + 256 * u;
        int r = task >> 3, c = (task & 7) * 4;
        float4 v = *(const float4*)&qkv[((size_t)(b * T_ + q0 + r)) * 768 + h * 32 + c];
        s16x4 sa;
        sa[0] = f2bf(v.x); sa[1] = f2bf(v.y); sa[2] = f2bf(v.z); sa[3] = f2bf(v.w);
        *(s16x4*)&Qs[r][c] = sa;
    }
#pragma unroll
    for (int u = 0; u < 4; ++u) {
        int task = tid + 256 * u;
        int r = task >> 3, c = (task & 7) * 4;
        int jg = j0 + r;
        s16x4 sa = {0, 0, 0, 0};
        if (jg >= 0) {
            float4 v = *(const float4*)&qkv[((size_t)(b * T_ + jg)) * 768 + 256 + h * 32 + c];
            sa[0] = f2bf(v.x); sa[1] = f2bf(v.y); sa[2] = f2bf(v.z); sa[3] = f2bf(v.w);
        }
        *(s16x4*)&Ks[r][c] = sa;
    }
#pragma unroll
    for (int u = 0; u < 4; ++u) {
        int task = tid + 256 * u;
        int r = task >> 3, c = (task & 7) * 4;
        int jg = j0 + r;
        float4 v = {0.f, 0.f, 0.f, 0.f};
        if (jg >= 0)
            v = *(const float4*)&qkv[((size_t)(b * T_ + jg)) * 768 + 512 + h * 32 + c];
        Vt[c + 0][r] = f2bf(v.x);
        Vt[c + 1][r] = f2bf(v.y);
        Vt[c + 2][r] = f2bf(v.z);
        Vt[c + 3][r] = f2bf(v.w);
    }
    __syncthreads();

    s16x8 aq = *(const s16x8*)&Qs[16 * wave + lr][lg * 8];
    f32x4 sacc[8];
#pragma unroll
    for (int j = 0; j < 8; ++j) {
        s16x8 bk = *(const s16x8*)&Ks[16 * j + lr][lg * 8];
        f32x4 z = {0.f, 0.f, 0.f, 0.f};
        sacc[j] = __builtin_amdgcn_mfma_f32_16x16x32_bf16(aq, bk, z, 0, 0, 0);
    }

    const float scale = 0.17677669529663687f;
#pragma unroll
    for (int j = 0; j < 8; ++j) {
        int jg = j0 + 16 * j + lr;
#pragma unroll
        for (int q = 0; q < 4; ++q) {
            int qi = q0 + 16 * wave + lg * 4 + q;
            bool ok = ((jg >= qi - WIN_) && (jg < qi) && (jg >= 0)) || (qi == 0 && jg == 0);
            sacc[j][q] = ok ? sacc[j][q] * scale : -1e30f;
        }
    }
#pragma unroll
    for (int q = 0; q < 4; ++q) {
        float m = sacc[0][q];
#pragma unroll
        for (int j = 1; j < 8; ++j) m = fmaxf(m, sacc[j][q]);
#pragma unroll
        for (int off = 1; off < 16; off <<= 1) m = fmaxf(m, __shfl_xor(m, off));
        float e[8], sum = 0.f;
#pragma unroll
        for (int j = 0; j < 8; ++j) { e[j] = __expf(sacc[j][q] - m); sum += e[j]; }
#pragma unroll
        for (int off = 1; off < 16; off <<= 1) sum += __shfl_xor(sum, off);
        float inv = 1.f / sum;
        int row = 16 * wave + lg * 4 + q;
#pragma unroll
        for (int j = 0; j < 8; ++j) Ps[row][16 * j + lr] = f2bf(e[j] * inv);
    }

    f32x4 oacc[2] = {};
#pragma unroll
    for (int kk = 0; kk < 4; ++kk) {
        s16x8 ap = *(const s16x8*)&Ps[16 * wave + lr][kk * 32 + lg * 8];
#pragma unroll
        for (int n = 0; n < 2; ++n) {
            s16x8 bv = *(const s16x8*)&Vt[16 * n + lr][kk * 32 + lg * 8];
            oacc[n] = __builtin_amdgcn_mfma_f32_16x16x32_bf16(ap, bv, oacc[n], 0, 0, 0);
        }
    }
#pragma unroll
    for (int n = 0; n < 2; ++n)
#pragma unroll
        for (int q = 0; q < 4; ++q) {
            int qi = q0 + 16 * wave + lg * 4 + q;
            out[((size_t)(b * T_ + qi)) * D_ + h * 32 + 16 * n + lr] = oacc[n][q];
        }
}

// ---------------- LN2d stage A: partial sums per (chunk, batch)
__global__ __launch_bounds__(256) void ln2d_partial(
    const float* __restrict__ x, float* __restrict__ part, int CT) {
    int b = blockIdx.y;
    int chunk = blockIdx.x;
    int n4 = CT / (4 * NC_);
    const float4* xb = (const float4*)(x + (size_t)b * CT) + (size_t)chunk * n4;
    float s = 0.f, ss = 0.f;
    for (int i = threadIdx.x; i < n4; i += 256) {
        float4 v = xb[i];
        s += v.x + v.y + v.z + v.w;
        ss += v.x * v.x + v.y * v.y + v.z * v.z + v.w * v.w;
    }
#pragma unroll
    for (int off = 32; off; off >>= 1) {
        s += __shfl_xor(s, off);
        ss += __shfl_xor(ss, off);
    }
    __shared__ float sh0[4], sh1[4];
    int wave = threadIdx.x >> 6;
    if ((threadIdx.x & 63) == 0) { sh0[wave] = s; sh1[wave] = ss; }
    __syncthreads();
    if (threadIdx.x == 0) {
        part[(size_t)(b * NC_ + chunk) * 2] = sh0[0] + sh0[1] + sh0[2] + sh0[3];
        part[(size_t)(b * NC_ + chunk) * 2 + 1] = sh1[0] + sh1[1] + sh1[2] + sh1[3];
    }
}

__device__ inline void ln2d_stats(const float* __restrict__ part, int b, int CT,
                                  float& mu, float& rstd) {
    float s = 0.f, ss = 0.f;
    const float2* p2 = (const float2*)(part + (size_t)b * NC_ * 2);
#pragma unroll
    for (int i = 0; i < NC_; ++i) { float2 v = p2[i]; s += v.x; ss += v.y; }
    mu = s / (float)CT;
    rstd = rsqrtf(ss / (float)CT - mu * mu + 1e-5f);
}

// ---------------- LN2d apply + ReLU (float4), final-reduce fused
__global__ __launch_bounds__(256) void ln2d_apply(
    const float* __restrict__ x, const float* __restrict__ w,
    const float* __restrict__ bb, const float* __restrict__ part,
    float* __restrict__ y, int CT) {
    int idx = blockIdx.x * 256 + threadIdx.x;
    int b = blockIdx.y;
    float mu, rstd;
    ln2d_stats(part, b, CT, mu, rstd);
    const float4* x4 = (const float4*)(x + (size_t)b * CT);
    const float4* w4 = (const float4*)w;
    const float4* b4 = (const float4*)bb;
    float4* y4 = (float4*)(y + (size_t)b * CT);
    float4 v = x4[idx], wv = w4[idx], bv = b4[idx];
    float4 r;
    r.x = fmaxf((v.x - mu) * rstd * wv.x + bv.x, 0.f);
    r.y = fmaxf((v.y - mu) * rstd * wv.y + bv.y, 0.f);
    r.z = fmaxf((v.z - mu) * rstd * wv.z + bv.z, 0.f);
    r.w = fmaxf((v.w - mu) * rstd * wv.w + bv.w, 0.f);
    y4[idx] = r;
}

// ---------------- LN2d apply + ReLU + transpose + pos add: [B,D,T] -> [B,T,D]
__global__ __launch_bounds__(256) void ln2d_apply_t(
    const float* __restrict__ x, const float* __restrict__ w,
    const float* __restrict__ bb, const float* __restrict__ part,
    const float* __restrict__ pos, float* __restrict__ h) {
    int t0 = blockIdx.x * 32;
    int d0 = blockIdx.y * 32;
    int b = blockIdx.z;
    float mu, rstd;
    ln2d_stats(part, b, D_ * T_, mu, rstd);
    __shared__ float xs[32][33];
    int tt = threadIdx.x & 31, dd = threadIdx.x >> 5;   // 8 d-rows per pass
#pragma unroll
    for (int p = 0; p < 4; ++p) {
        int d = d0 + dd + p * 8;
        size_t off = ((size_t)b * D_ + d) * T_ + t0 + tt;
        size_t woff = (size_t)d * T_ + t0 + tt;
        float v = (x[off] - mu) * rstd * w[woff] + bb[woff];
        xs[dd + p * 8][tt] = fmaxf(v, 0.f);
    }
    __syncthreads();
    int dd2 = threadIdx.x & 31, tt2 = threadIdx.x >> 5;
#pragma unroll
    for (int p = 0; p < 4; ++p) {
        int t = t0 + tt2 + p * 8;
        h[((size_t)(b * T_ + t)) * D_ + d0 + dd2] =
            xs[dd2][tt2 + p * 8] + pos[(size_t)t * D_ + d0 + dd2];
    }
}

// ---------------- residual add + row LayerNorm over D=256, 4 rows/block
__global__ __launch_bounds__(256) void ln_row(
    float* __restrict__ h, const float* __restrict__ o,
    const float* __restrict__ w, const float* __restrict__ bb) {
    int r = blockIdx.x * 4 + (threadIdx.x >> 6);
    int lane = threadIdx.x & 63;
    float x[4];
    float s = 0.f;
#pragma unroll
    for (int i = 0; i < 4; ++i) {
        int idx = i * 64 + lane;
        x[i] = h[(size_t)r * D_ + idx] + o[(size_t)r * D_ + idx];
        s += x[i];
    }
#pragma unroll
    for (int off = 32; off; off >>= 1) s += __shfl_xor(s, off);
    float mu = s * (1.f / D_);
    float ss = 0.f;
#pragma unroll
    for (int i = 0; i < 4; ++i) { float d = x[i] - mu; ss += d * d; }
#pragma unroll
    for (int off = 32; off; off >>= 1) ss += __shfl_xor(ss, off);
    float rstd = rsqrtf(ss * (1.f / D_) + 1e-5f);
#pragma unroll
    for (int i = 0; i < 4; ++i) {
        int idx = i * 64 + lane;
        h[(size_t)r * D_ + idx] = (x[i] - mu) * rstd * w[idx] + bb[idx];
    }
}

extern "C" void kernel_launch(void* const* d_in, const int* in_sizes, int n_in,
                              void* d_out, int out_size, void* d_ws, size_t ws_size,
                              hipStream_t stream) {
    const float* x        = (const float*)d_in[0];
    const float* pre_w0   = (const float*)d_in[1];
    const float* pre_b0   = (const float*)d_in[2];
    const float* pre_lnw0 = (const float*)d_in[3];
    const float* pre_lnb0 = (const float*)d_in[4];
    const float* pre_w1   = (const float*)d_in[5];
    const float* pre_b1   = (const float*)d_in[6];
    const float* pre_lnw1 = (const float*)d_in[7];
    const float* pre_lnb1 = (const float*)d_in[8];
    const float* pos_emb  = (const float*)d_in[9];
    const float* Wqkv     = (const float*)d_in[10];
    const float* bqkv     = (const float*)d_in[11];
    const float* Wo       = (const float*)d_in[12];
    const float* bo       = (const float*)d_in[13];
    const float* ln1w     = (const float*)d_in[14];
    const float* ln1b     = (const float*)d_in[15];
    const float* W1       = (const float*)d_in[16];
    const float* b1       = (const float*)d_in[17];
    const float* W2       = (const float*)d_in[18];
    const float* b2       = (const float*)d_in[19];
    const float* ln2w     = (const float*)d_in[20];
    const float* ln2b     = (const float*)d_in[21];
    const float* post_w0  = (const float*)d_in[22];
    const float* post_b0  = (const float*)d_in[23];
    const float* post_lnw0= (const float*)d_in[24];
    const float* post_lnb0= (const float*)d_in[25];
    const float* post_w1  = (const float*)d_in[26];
    const float* post_b1  = (const float*)d_in[27];
    const float* post_lnw1= (const float*)d_in[28];
    const float* post_lnb1= (const float*)d_in[29];

    float* ws = (float*)d_ws;
    const size_t M1 = 1u << 20;           // 1M floats
    float* H    = ws;                     // [B,T,D]      1M
    float* QKV  = ws + 1 * M1;            // [B,T,3D]     3M (also A0/A1 conv bufs)
    float* A0   = QKV;                    // [B,D,T]      1M
    float* A1   = QKV + M1;               // [B,D,T]      1M
    float* F    = ws + 4 * M1;            // [B,T,DFF]    2M
    float* ATT  = ws + 6 * M1;            // [B,T,D]      1M
    float* G    = ws + 7 * M1;            // [B,T,D]      1M
    float* Acol = F;                      // [B*T, 768]   3M (aliases F+ATT; dead there)
    float* part = ws + 8 * M1;            // B*NC*2 floats

    const int M = B_ * T_;  // 4096

    // ---- pre stage
    im2col_kernel<<<dim3(T_ / 32, B_), 256, CIN_ * 34 * 4, stream>>>(x, Acol, CIN_);
    gemm64<0, 1><<<dim3(D_ / 64, M / 64), 256, 0, stream>>>(
        Acol, pre_w0, pre_b0, A0, M, D_, CIN_ * 3);
    ln2d_partial<<<dim3(NC_, B_), 256, 0, stream>>>(A0, part, D_ * T_);
    ln2d_apply<<<dim3(D_ * T_ / 1024, B_), 256, 0, stream>>>(A0, pre_lnw0, pre_lnb0, part, A1, D_ * T_);

    im2col_kernel<<<dim3(T_ / 32, B_), 256, D_ * 34 * 4, stream>>>(A1, Acol, D_);
    gemm64<0, 1><<<dim3(D_ / 64, M / 64), 256, 0, stream>>>(
        Acol, pre_w1, pre_b1, A0, M, D_, D_ * 3);
    ln2d_partial<<<dim3(NC_, B_), 256, 0, stream>>>(A0, part, D_ * T_);
    ln2d_apply_t<<<dim3(T_ / 32, D_ / 32, B_), 256, 0, stream>>>(
        A0, pre_lnw1, pre_lnb1, part, pos_emb, H);

    // ---- transformer layers
    for (int l = 0; l < L_; ++l) {
        gemm64<0, 0><<<dim3(768 / 64, M / 64), 256, 0, stream>>>(
            H, Wqkv + (size_t)l * 768 * D_, bqkv + (size_t)l * 768, QKV, M, 768, D_);
        attn_mfma<<<dim3(T_ / 64, H_, B_), 256, 0, stream>>>(QKV, ATT);
        gemm64<0, 0><<<dim3(D_ / 64, M / 64), 256, 0, stream>>>(
            ATT, Wo + (size_t)l * D_ * D_, bo + (size_t)l * D_, G, M, D_, D_);
        ln_row<<<M / 4, 256, 0, stream>>>(H, G, ln1w + (size_t)l * D_, ln1b + (size_t)l * D_);
        gemm64<1, 0><<<dim3(DFF_ / 64, M / 64), 256, 0, stream>>>(
            H, W1 + (size_t)l * DFF_ * D_, b1 + (size_t)l * DFF_, F, M, DFF_, D_);
        gemm64<0, 0><<<dim3(D_ / 64, M / 64), 256, 0, stream>>>(
            F, W2 + (size_t)l * D_ * DFF_, b2 + (size_t)l * D_, G, M, D_, DFF_);
        ln_row<<<M / 4, 256, 0, stream>>>(H, G, ln2w + (size_t)l * D_, ln2b + (size_t)l * D_);
    }

    // ---- post stage
    im2col_btd<<<dim3(T_ / 32, B_), 256, 0, stream>>>(H, Acol);
    gemm64<0, 1><<<dim3(D_ / 64, M / 64), 256, 0, stream>>>(
        Acol, post_w0, post_b0, A1, M, D_, D_ * 3);
    ln2d_partial<<<dim3(NC_, B_), 256, 0, stream>>>(A1, part, D_ * T_);
    ln2d_apply<<<dim3(D_ * T_ / 1024, B_), 256, 0, stream>>>(A1, post_lnw0, post_lnb0, part, A0, D_ * T_);

    im2col_kernel<<<dim3(T_ / 32, B_), 256, D_ * 34 * 4, stream>>>(A0, Acol, D_);
    gemm64<0, 1><<<dim3(CIN_ / 64, M / 64), 256, 0, stream>>>(
        Acol, post_w1, post_b1, A1, M, CIN_, D_ * 3);
    ln2d_partial<<<dim3(NC_, B_), 256, 0, stream>>>(A1, part, CIN_ * T_);
    ln2d_apply<<<dim3(CIN_ * T_ / 1024, B_), 256, 0, stream>>>(A1, post_lnw1, post_lnb1, part,
                                                               (float*)d_out, CIN_ * T_);
}

// Round 9
// 400.261 us; speedup vs baseline: 5.7645x; 1.1001x over previous
//
#include <hip/hip_runtime.h>
#include <hip/hip_bf16.h>

#define B_ 4
#define T_ 1024
#define D_ 256
#define H_ 8
#define WIN_ 64
#define CIN_ 128
#define DH_ 32
#define DFF_ 512
#define L_ 4
#define NC_ 32   // LN2d reduction chunks per batch
#define PSTR 152 // Ps/Vt LDS row stride (shorts)

typedef __attribute__((ext_vector_type(4))) short s16x4;
typedef __attribute__((ext_vector_type(8))) short s16x8;
typedef __attribute__((ext_vector_type(4))) float f32x4;

__device__ inline short f2bf(float f) {
    __hip_bfloat16 h = __float2bfloat16(f);
    return *reinterpret_cast<short*>(&h);
}

// ---------------- one-time fp32->bf16 weight conversion (Wqkv|Wo|W1|W2)
__global__ __launch_bounds__(256) void prep_w(
    const float* __restrict__ wqkv, const float* __restrict__ wo,
    const float* __restrict__ w1, const float* __restrict__ w2,
    short* __restrict__ dst) {
    const int N0 = 786432, N1 = 1048576, N2 = 1572864, NT = 2097152;
    for (int i = blockIdx.x * 256 + threadIdx.x; i < NT; i += gridDim.x * 256) {
        float v;
        if (i < N0) v = wqkv[i];
        else if (i < N1) v = wo[i - N0];
        else if (i < N2) v = w1[i - N1];
        else v = w2[i - N2];
        dst[i] = f2bf(v);
    }
}

// ---------------- im2col from [B,I,T]: Acol[(b*T+t)][i*3+k] = x[b,i,t+k-1]
__global__ __launch_bounds__(256) void im2col_kernel(
    const float* __restrict__ x, float* __restrict__ Acol, int I) {
    const int K = I * 3;
    int t0 = blockIdx.x * 32;
    int b = blockIdx.y;
    extern __shared__ float xs[];   // [I][34]
    for (int idx = threadIdx.x; idx < I * 34; idx += 256) {
        int i = idx / 34, tt = idx % 34;
        int tg = t0 - 1 + tt;
        xs[idx] = (tg >= 0 && tg < T_) ? x[((size_t)b * I + i) * T_ + tg] : 0.f;
    }
    __syncthreads();
    int nf4 = K / 4;
    for (int idx = threadIdx.x; idx < 32 * nf4; idx += 256) {
        int tl = idx / nf4, c4 = idx % nf4;
        int c = c4 * 4;
        float4 v;
        { int cc = c;     int i = cc / 3, k = cc - 3 * i; v.x = xs[i * 34 + tl + k]; }
        { int cc = c + 1; int i = cc / 3, k = cc - 3 * i; v.y = xs[i * 34 + tl + k]; }
        { int cc = c + 2; int i = cc / 3, k = cc - 3 * i; v.z = xs[i * 34 + tl + k]; }
        { int cc = c + 3; int i = cc / 3, k = cc - 3 * i; v.w = xs[i * 34 + tl + k]; }
        *(float4*)&Acol[((size_t)(b * T_ + t0 + tl)) * K + c] = v;
    }
}

// ---------------- im2col from [B,T,D]: Acol[(b*T+t)][i*3+k] = h[b,t+k-1,i]  (I=D_)
__global__ __launch_bounds__(256) void im2col_btd(
    const float* __restrict__ h, float* __restrict__ Acol) {
    int t0 = blockIdx.x * 32;
    int b = blockIdx.y;
    __shared__ float xs[D_ * 35];   // [i][tt], stride 35
    for (int idx = threadIdx.x; idx < 34 * (D_ / 4); idx += 256) {
        int tt = idx >> 6, i4 = (idx & 63) * 4;
        int tg = t0 - 1 + tt;
        float4 v = {0.f, 0.f, 0.f, 0.f};
        if (tg >= 0 && tg < T_) v = *(const float4*)&h[((size_t)(b * T_ + tg)) * D_ + i4];
        xs[(i4 + 0) * 35 + tt] = v.x;
        xs[(i4 + 1) * 35 + tt] = v.y;
        xs[(i4 + 2) * 35 + tt] = v.z;
        xs[(i4 + 3) * 35 + tt] = v.w;
    }
    __syncthreads();
    const int K = D_ * 3;
    const int nf4 = K / 4;
    for (int idx = threadIdx.x; idx < 32 * nf4; idx += 256) {
        int tl = idx / nf4, c4 = idx % nf4;
        int c = c4 * 4;
        float4 v;
        { int cc = c;     int i = cc / 3, k = cc - 3 * i; v.x = xs[i * 35 + tl + k]; }
        { int cc = c + 1; int i = cc / 3, k = cc - 3 * i; v.y = xs[i * 35 + tl + k]; }
        { int cc = c + 2; int i = cc / 3, k = cc - 3 * i; v.z = xs[i * 35 + tl + k]; }
        { int cc = c + 3; int i = cc / 3, k = cc - 3 * i; v.w = xs[i * 35 + tl + k]; }
        *(float4*)&Acol[((size_t)(b * T_ + t0 + tl)) * K + c] = v;
    }
}

// ---------------- bf16 MFMA GEMM, 64x64 tile, BK=32, fp32 weights (convs)
// TRANSOUT=1: Y[B][N][1024], row r = b*1024+t.
template <int RELU, int TRANSOUT>
__global__ __launch_bounds__(256) void gemm64(
    const float* __restrict__ A, const float* __restrict__ W,
    const float* __restrict__ bias, float* __restrict__ Y,
    int M, int N, int K) {
    __shared__ short Al[64 * 40];
    __shared__ short Wl[64 * 40];
    int tid = threadIdx.x;
    int row0 = blockIdx.y * 64, col0 = blockIdx.x * 64;
    int wave = tid >> 6, lane = tid & 63;
    int wr = wave >> 1, wc = wave & 1;
    int lg = lane >> 4, lr = lane & 15;
    f32x4 acc[2][2] = {};

    int srow = tid >> 3;            // 0..31
    int scol = (tid & 7) * 4;       // 0,4,..,28
    for (int k0 = 0; k0 < K; k0 += 32) {
#pragma unroll
        for (int p = 0; p < 2; ++p) {
            int rr = srow + p * 32;
            float4 va = *(const float4*)&A[(size_t)(row0 + rr) * K + k0 + scol];
            float4 vw = *(const float4*)&W[(size_t)(col0 + rr) * K + k0 + scol];
            s16x4 sa, sw;
            sa[0] = f2bf(va.x); sa[1] = f2bf(va.y); sa[2] = f2bf(va.z); sa[3] = f2bf(va.w);
            sw[0] = f2bf(vw.x); sw[1] = f2bf(vw.y); sw[2] = f2bf(vw.z); sw[3] = f2bf(vw.w);
            *(s16x4*)&Al[rr * 40 + scol] = sa;
            *(s16x4*)&Wl[rr * 40 + scol] = sw;
        }
        __syncthreads();
        s16x8 af[2], wf[2];
#pragma unroll
        for (int i = 0; i < 2; ++i) {
            af[i] = *(const s16x8*)&Al[(wr * 32 + i * 16 + lr) * 40 + lg * 8];
            wf[i] = *(const s16x8*)&Wl[(wc * 32 + i * 16 + lr) * 40 + lg * 8];
        }
#pragma unroll
        for (int i = 0; i < 2; ++i)
#pragma unroll
            for (int j = 0; j < 2; ++j)
                acc[i][j] = __builtin_amdgcn_mfma_f32_16x16x32_bf16(af[i], wf[j], acc[i][j], 0, 0, 0);
        __syncthreads();
    }

    if (TRANSOUT) {
        int b = row0 >> 10;
        int t0 = row0 & 1023;
#pragma unroll
        for (int i = 0; i < 2; ++i) {
            int tg = t0 + wr * 32 + i * 16 + lg * 4;
#pragma unroll
            for (int j = 0; j < 2; ++j) {
                int cg = col0 + wc * 32 + j * 16 + lr;
                float bv = bias[cg];
                float4 o;
                o.x = acc[i][j][0] + bv; o.y = acc[i][j][1] + bv;
                o.z = acc[i][j][2] + bv; o.w = acc[i][j][3] + bv;
                if (RELU) {
                    o.x = fmaxf(o.x, 0.f); o.y = fmaxf(o.y, 0.f);
                    o.z = fmaxf(o.z, 0.f); o.w = fmaxf(o.w, 0.f);
                }
                *(float4*)&Y[((size_t)(b * N + cg)) * 1024 + tg] = o;
            }
        }
    } else {
#pragma unroll
        for (int i = 0; i < 2; ++i) {
            int rg = row0 + wr * 32 + i * 16 + lg * 4;
#pragma unroll
            for (int j = 0; j < 2; ++j) {
                int cg = col0 + wc * 32 + j * 16 + lr;
                float bv = bias[cg];
#pragma unroll
                for (int q = 0; q < 4; ++q) {
                    float v = acc[i][j][q] + bv;
                    if (RELU) v = fmaxf(v, 0.f);
                    Y[(size_t)(rg + q) * N + cg] = v;
                }
            }
        }
    }
}

// ---------------- bf16-weight MFMA GEMM (QKV, FFN1): Y = A @ Wbf^T + bias
template <int RELU>
__global__ __launch_bounds__(256) void gemm64w(
    const float* __restrict__ A, const short* __restrict__ Wbf,
    const float* __restrict__ bias, float* __restrict__ Y,
    int M, int N, int K) {
    __shared__ short Al[64 * 40];
    __shared__ short Wl[64 * 40];
    int tid = threadIdx.x;
    int row0 = blockIdx.y * 64, col0 = blockIdx.x * 64;
    int wave = tid >> 6, lane = tid & 63;
    int wr = wave >> 1, wc = wave & 1;
    int lg = lane >> 4, lr = lane & 15;
    f32x4 acc[2][2] = {};

    int srow = tid >> 3;
    int scol = (tid & 7) * 4;
    for (int k0 = 0; k0 < K; k0 += 32) {
#pragma unroll
        for (int p = 0; p < 2; ++p) {
            int rr = srow + p * 32;
            float4 va = *(const float4*)&A[(size_t)(row0 + rr) * K + k0 + scol];
            s16x4 sa;
            sa[0] = f2bf(va.x); sa[1] = f2bf(va.y); sa[2] = f2bf(va.z); sa[3] = f2bf(va.w);
            *(s16x4*)&Al[rr * 40 + scol] = sa;
            *(s16x4*)&Wl[rr * 40 + scol] =
                *(const s16x4*)&Wbf[(size_t)(col0 + rr) * K + k0 + scol];
        }
        __syncthreads();
        s16x8 af[2], wf[2];
#pragma unroll
        for (int i = 0; i < 2; ++i) {
            af[i] = *(const s16x8*)&Al[(wr * 32 + i * 16 + lr) * 40 + lg * 8];
            wf[i] = *(const s16x8*)&Wl[(wc * 32 + i * 16 + lr) * 40 + lg * 8];
        }
#pragma unroll
        for (int i = 0; i < 2; ++i)
#pragma unroll
            for (int j = 0; j < 2; ++j)
                acc[i][j] = __builtin_amdgcn_mfma_f32_16x16x32_bf16(af[i], wf[j], acc[i][j], 0, 0, 0);
        __syncthreads();
    }
#pragma unroll
    for (int i = 0; i < 2; ++i) {
        int rg = row0 + wr * 32 + i * 16 + lg * 4;
#pragma unroll
        for (int j = 0; j < 2; ++j) {
            int cg = col0 + wc * 32 + j * 16 + lr;
            float bv = bias[cg];
#pragma unroll
            for (int q = 0; q < 4; ++q) {
                float v = acc[i][j][q] + bv;
                if (RELU) v = fmaxf(v, 0.f);
                Y[(size_t)(rg + q) * N + cg] = v;
            }
        }
    }
}

// ---------------- fused GEMM(N=256 full) + bias + residual + row-LN, in-place on H
// H[r] = LN(H[r] + A[r] @ Wbf^T + bias),  16 rows per block, grid M/16.
template <int KK>
__global__ __launch_bounds__(256) void gemm_ln(
    const float* __restrict__ A, const short* __restrict__ Wbf,
    const float* __restrict__ bias, float* __restrict__ H,
    const float* __restrict__ lnw, const float* __restrict__ lnb) {
    __shared__ short As[16 * 40];
    __shared__ short Ws[256 * 40];
    __shared__ float Gs[16][260];
    int tid = threadIdx.x;
    int wave = tid >> 6, lane = tid & 63;
    int lg = lane >> 4, lr = lane & 15;
    int m0 = blockIdx.x * 16;
    f32x4 acc[4] = {};

    for (int k0 = 0; k0 < KK; k0 += 32) {
        if (tid < 128) {
            int r = tid >> 3, c = (tid & 7) * 4;
            float4 va = *(const float4*)&A[(size_t)(m0 + r) * KK + k0 + c];
            s16x4 sa;
            sa[0] = f2bf(va.x); sa[1] = f2bf(va.y); sa[2] = f2bf(va.z); sa[3] = f2bf(va.w);
            *(s16x4*)&As[r * 40 + c] = sa;
        }
#pragma unroll
        for (int u = 0; u < 4; ++u) {
            int task = tid + 256 * u;      // 1024 tasks: 256 rows x 4 chunks of 8
            int r = task >> 2, c8 = (task & 3) * 8;
            *(s16x8*)&Ws[r * 40 + c8] = *(const s16x8*)&Wbf[(size_t)r * KK + k0 + c8];
        }
        __syncthreads();
        s16x8 af = *(const s16x8*)&As[lr * 40 + lg * 8];
#pragma unroll
        for (int j = 0; j < 4; ++j) {
            s16x8 wf = *(const s16x8*)&Ws[(wave * 64 + j * 16 + lr) * 40 + lg * 8];
            acc[j] = __builtin_amdgcn_mfma_f32_16x16x32_bf16(af, wf, acc[j], 0, 0, 0);
        }
        __syncthreads();
    }

    // epilogue: G tile to LDS (+bias)
#pragma unroll
    for (int j = 0; j < 4; ++j) {
        int col = wave * 64 + j * 16 + lr;
        float bv = bias[col];
#pragma unroll
        for (int q = 0; q < 4; ++q)
            Gs[lg * 4 + q][col] = acc[j][q] + bv;
    }
    __syncthreads();

    // residual + row LN: wave handles rows wave*4..+3
    for (int rr = 0; rr < 4; ++rr) {
        int row = wave * 4 + rr;
        size_t base = (size_t)(m0 + row) * D_;
        float x[4];
        float s = 0.f;
#pragma unroll
        for (int i = 0; i < 4; ++i) {
            int idx = i * 64 + lane;
            x[i] = H[base + idx] + Gs[row][idx];
            s += x[i];
        }
#pragma unroll
        for (int off = 32; off; off >>= 1) s += __shfl_xor(s, off);
        float mu = s * (1.f / D_);
        float ss = 0.f;
#pragma unroll
        for (int i = 0; i < 4; ++i) { float d = x[i] - mu; ss += d * d; }
#pragma unroll
        for (int off = 32; off; off >>= 1) ss += __shfl_xor(ss, off);
        float rstd = rsqrtf(ss * (1.f / D_) + 1e-5f);
#pragma unroll
        for (int i = 0; i < 4; ++i) {
            int idx = i * 64 + lane;
            H[base + idx] = (x[i] - mu) * rstd * lnw[idx] + lnb[idx];
        }
    }
}

// ---------------- MFMA banded attention: one block per (64-q tile, head, batch)
__global__ __launch_bounds__(256) void attn_mfma(
    const float* __restrict__ qkv, float* __restrict__ out) {
    int q0 = blockIdx.x * 64;
    int h = blockIdx.y, b = blockIdx.z;
    int tid = threadIdx.x;
    int wave = tid >> 6, lane = tid & 63;
    int lg = lane >> 4;
    int lr = lane & 15;
    const int j0 = q0 - 64;

    __shared__ short Qs[64][40];
    __shared__ short Ks[128][40];
    __shared__ short Vt[32][PSTR];
    __shared__ short Ps[64][PSTR];

#pragma unroll
    for (int u = 0; u < 2; ++u) {
        int task = tid + 256 * u;
        int r = task >> 3, c = (task & 7) * 4;
        float4 v = *(const float4*)&qkv[((size_t)(b * T_ + q0 + r)) * 768 + h * 32 + c];
        s16x4 sa;
        sa[0] = f2bf(v.x); sa[1] = f2bf(v.y); sa[2] = f2bf(v.z); sa[3] = f2bf(v.w);
        *(s16x4*)&Qs[r][c] = sa;
    }
#pragma unroll
    for (int u = 0; u < 4; ++u) {
        int task = tid + 256 * u;
        int r = task >> 3, c = (task & 7) * 4;
        int jg = j0 + r;
        s16x4 sa = {0, 0, 0, 0};
        if (jg >= 0) {
            float4 v = *(const float4*)&qkv[((size_t)(b * T_ + jg)) * 768 + 256 + h * 32 + c];
            sa[0] = f2bf(v.x); sa[1] = f2bf(v.y); sa[2] = f2bf(v.z); sa[3] = f2bf(v.w);
        }
        *(s16x4*)&Ks[r][c] = sa;
    }
#pragma unroll
    for (int u = 0; u < 4; ++u) {
        int task = tid + 256 * u;
        int r = task >> 3, c = (task & 7) * 4;
        int jg = j0 + r;
        float4 v = {0.f, 0.f, 0.f, 0.f};
        if (jg >= 0)
            v = *(const float4*)&qkv[((size_t)(b * T_ + jg)) * 768 + 512 + h * 32 + c];
        Vt[c + 0][r] = f2bf(v.x);
        Vt[c + 1][r] = f2bf(v.y);
        Vt[c + 2][r] = f2bf(v.z);
        Vt[c + 3][r] = f2bf(v.w);
    }
    __syncthreads();

    s16x8 aq = *(const s16x8*)&Qs[16 * wave + lr][lg * 8];
    f32x4 sacc[8];
#pragma unroll
    for (int j = 0; j < 8; ++j) {
        s16x8 bk = *(const s16x8*)&Ks[16 * j + lr][lg * 8];
        f32x4 z = {0.f, 0.f, 0.f, 0.f};
        sacc[j] = __builtin_amdgcn_mfma_f32_16x16x32_bf16(aq, bk, z, 0, 0, 0);
    }

    const float scale = 0.17677669529663687f;
#pragma unroll
    for (int j = 0; j < 8; ++j) {
        int jg = j0 + 16 * j + lr;
#pragma unroll
        for (int q = 0; q < 4; ++q) {
            int qi = q0 + 16 * wave + lg * 4 + q;
            bool ok = ((jg >= qi - WIN_) && (jg < qi) && (jg >= 0)) || (qi == 0 && jg == 0);
            sacc[j][q] = ok ? sacc[j][q] * scale : -1e30f;
        }
    }
#pragma unroll
    for (int q = 0; q < 4; ++q) {
        float m = sacc[0][q];
#pragma unroll
        for (int j = 1; j < 8; ++j) m = fmaxf(m, sacc[j][q]);
#pragma unroll
        for (int off = 1; off < 16; off <<= 1) m = fmaxf(m, __shfl_xor(m, off));
        float e[8], sum = 0.f;
#pragma unroll
        for (int j = 0; j < 8; ++j) { e[j] = __expf(sacc[j][q] - m); sum += e[j]; }
#pragma unroll
        for (int off = 1; off < 16; off <<= 1) sum += __shfl_xor(sum, off);
        float inv = 1.f / sum;
        int row = 16 * wave + lg * 4 + q;
#pragma unroll
        for (int j = 0; j < 8; ++j) Ps[row][16 * j + lr] = f2bf(e[j] * inv);
    }

    f32x4 oacc[2] = {};
#pragma unroll
    for (int kk = 0; kk < 4; ++kk) {
        s16x8 ap = *(const s16x8*)&Ps[16 * wave + lr][kk * 32 + lg * 8];
#pragma unroll
        for (int n = 0; n < 2; ++n) {
            s16x8 bv = *(const s16x8*)&Vt[16 * n + lr][kk * 32 + lg * 8];
            oacc[n] = __builtin_amdgcn_mfma_f32_16x16x32_bf16(ap, bv, oacc[n], 0, 0, 0);
        }
    }
#pragma unroll
    for (int n = 0; n < 2; ++n)
#pragma unroll
        for (int q = 0; q < 4; ++q) {
            int qi = q0 + 16 * wave + lg * 4 + q;
            out[((size_t)(b * T_ + qi)) * D_ + h * 32 + 16 * n + lr] = oacc[n][q];
        }
}

// ---------------- LN2d stage A: partial sums per (chunk, batch)
__global__ __launch_bounds__(256) void ln2d_partial(
    const float* __restrict__ x, float* __restrict__ part, int CT) {
    int b = blockIdx.y;
    int chunk = blockIdx.x;
    int n4 = CT / (4 * NC_);
    const float4* xb = (const float4*)(x + (size_t)b * CT) + (size_t)chunk * n4;
    float s = 0.f, ss = 0.f;
    for (int i = threadIdx.x; i < n4; i += 256) {
        float4 v = xb[i];
        s += v.x + v.y + v.z + v.w;
        ss += v.x * v.x + v.y * v.y + v.z * v.z + v.w * v.w;
    }
#pragma unroll
    for (int off = 32; off; off >>= 1) {
        s += __shfl_xor(s, off);
        ss += __shfl_xor(ss, off);
    }
    __shared__ float sh0[4], sh1[4];
    int wave = threadIdx.x >> 6;
    if ((threadIdx.x & 63) == 0) { sh0[wave] = s; sh1[wave] = ss; }
    __syncthreads();
    if (threadIdx.x == 0) {
        part[(size_t)(b * NC_ + chunk) * 2] = sh0[0] + sh0[1] + sh0[2] + sh0[3];
        part[(size_t)(b * NC_ + chunk) * 2 + 1] = sh1[0] + sh1[1] + sh1[2] + sh1[3];
    }
}

__device__ inline void ln2d_stats(const float* __restrict__ part, int b, int CT,
                                  float& mu, float& rstd) {
    float s = 0.f, ss = 0.f;
    const float2* p2 = (const float2*)(part + (size_t)b * NC_ * 2);
#pragma unroll
    for (int i = 0; i < NC_; ++i) { float2 v = p2[i]; s += v.x; ss += v.y; }
    mu = s / (float)CT;
    rstd = rsqrtf(ss / (float)CT - mu * mu + 1e-5f);
}

// ---------------- LN2d apply + ReLU (float4), final-reduce fused
__global__ __launch_bounds__(256) void ln2d_apply(
    const float* __restrict__ x, const float* __restrict__ w,
    const float* __restrict__ bb, const float* __restrict__ part,
    float* __restrict__ y, int CT) {
    int idx = blockIdx.x * 256 + threadIdx.x;
    int b = blockIdx.y;
    float mu, rstd;
    ln2d_stats(part, b, CT, mu, rstd);
    const float4* x4 = (const float4*)(x + (size_t)b * CT);
    const float4* w4 = (const float4*)w;
    const float4* b4 = (const float4*)bb;
    float4* y4 = (float4*)(y + (size_t)b * CT);
    float4 v = x4[idx], wv = w4[idx], bv = b4[idx];
    float4 r;
    r.x = fmaxf((v.x - mu) * rstd * wv.x + bv.x, 0.f);
    r.y = fmaxf((v.y - mu) * rstd * wv.y + bv.y, 0.f);
    r.z = fmaxf((v.z - mu) * rstd * wv.z + bv.z, 0.f);
    r.w = fmaxf((v.w - mu) * rstd * wv.w + bv.w, 0.f);
    y4[idx] = r;
}

// ---------------- LN2d apply + ReLU + transpose + pos add: [B,D,T] -> [B,T,D]
__global__ __launch_bounds__(256) void ln2d_apply_t(
    const float* __restrict__ x, const float* __restrict__ w,
    const float* __restrict__ bb, const float* __restrict__ part,
    const float* __restrict__ pos, float* __restrict__ h) {
    int t0 = blockIdx.x * 32;
    int d0 = blockIdx.y * 32;
    int b = blockIdx.z;
    float mu, rstd;
    ln2d_stats(part, b, D_ * T_, mu, rstd);
    __shared__ float xs[32][33];
    int tt = threadIdx.x & 31, dd = threadIdx.x >> 5;   // 8 d-rows per pass
#pragma unroll
    for (int p = 0; p < 4; ++p) {
        int d = d0 + dd + p * 8;
        size_t off = ((size_t)b * D_ + d) * T_ + t0 + tt;
        size_t woff = (size_t)d * T_ + t0 + tt;
        float v = (x[off] - mu) * rstd * w[woff] + bb[woff];
        xs[dd + p * 8][tt] = fmaxf(v, 0.f);
    }
    __syncthreads();
    int dd2 = threadIdx.x & 31, tt2 = threadIdx.x >> 5;
#pragma unroll
    for (int p = 0; p < 4; ++p) {
        int t = t0 + tt2 + p * 8;
        h[((size_t)(b * T_ + t)) * D_ + d0 + dd2] =
            xs[dd2][tt2 + p * 8] + pos[(size_t)t * D_ + d0 + dd2];
    }
}

extern "C" void kernel_launch(void* const* d_in, const int* in_sizes, int n_in,
                              void* d_out, int out_size, void* d_ws, size_t ws_size,
                              hipStream_t stream) {
    const float* x        = (const float*)d_in[0];
    const float* pre_w0   = (const float*)d_in[1];
    const float* pre_b0   = (const float*)d_in[2];
    const float* pre_lnw0 = (const float*)d_in[3];
    const float* pre_lnb0 = (const float*)d_in[4];
    const float* pre_w1   = (const float*)d_in[5];
    const float* pre_b1   = (const float*)d_in[6];
    const float* pre_lnw1 = (const float*)d_in[7];
    const float* pre_lnb1 = (const float*)d_in[8];
    const float* pos_emb  = (const float*)d_in[9];
    const float* Wqkv     = (const float*)d_in[10];
    const float* bqkv     = (const float*)d_in[11];
    const float* Wo       = (const float*)d_in[12];
    const float* bo       = (const float*)d_in[13];
    const float* ln1w     = (const float*)d_in[14];
    const float* ln1b     = (const float*)d_in[15];
    const float* W1       = (const float*)d_in[16];
    const float* b1       = (const float*)d_in[17];
    const float* W2       = (const float*)d_in[18];
    const float* b2       = (const float*)d_in[19];
    const float* ln2w     = (const float*)d_in[20];
    const float* ln2b     = (const float*)d_in[21];
    const float* post_w0  = (const float*)d_in[22];
    const float* post_b0  = (const float*)d_in[23];
    const float* post_lnw0= (const float*)d_in[24];
    const float* post_lnb0= (const float*)d_in[25];
    const float* post_w1  = (const float*)d_in[26];
    const float* post_b1  = (const float*)d_in[27];
    const float* post_lnw1= (const float*)d_in[28];
    const float* post_lnb1= (const float*)d_in[29];

    float* ws = (float*)d_ws;
    const size_t M1 = 1u << 20;           // 1M floats
    float* H    = ws;                     // [B,T,D]      1M
    float* QKV  = ws + 1 * M1;            // [B,T,3D]     3M (also A0/A1 conv bufs)
    float* A0   = QKV;                    // [B,D,T]      1M
    float* A1   = QKV + M1;               // [B,D,T]      1M
    float* F    = ws + 4 * M1;            // [B,T,DFF]    2M
    float* ATT  = ws + 6 * M1;            // [B,T,D]      1M
    float* Acol = F;                      // [B*T, 768]   3M (F..ATT; dead in transformer)
    short* wbf  = (short*)(ws + 7 * M1);  // 2M shorts = 4 MB bf16 weights
    short* wqkv_bf = wbf;                 // 4 x 768 x 256
    short* wo_bf   = wbf + 786432;        // 4 x 256 x 256
    short* w1_bf   = wbf + 1048576;       // 4 x 512 x 256
    short* w2_bf   = wbf + 1572864;       // 4 x 256 x 512
    float* part = ws + 8 * M1;            // B*NC*2 floats

    const int M = B_ * T_;  // 4096

    // ---- one-time bf16 weight prep (transformer weights)
    prep_w<<<2048, 256, 0, stream>>>(Wqkv, Wo, W1, W2, wbf);

    // ---- pre stage
    im2col_kernel<<<dim3(T_ / 32, B_), 256, CIN_ * 34 * 4, stream>>>(x, Acol, CIN_);
    gemm64<0, 1><<<dim3(D_ / 64, M / 64), 256, 0, stream>>>(
        Acol, pre_w0, pre_b0, A0, M, D_, CIN_ * 3);
    ln2d_partial<<<dim3(NC_, B_), 256, 0, stream>>>(A0, part, D_ * T_);
    ln2d_apply<<<dim3(D_ * T_ / 1024, B_), 256, 0, stream>>>(A0, pre_lnw0, pre_lnb0, part, A1, D_ * T_);

    im2col_kernel<<<dim3(T_ / 32, B_), 256, D_ * 34 * 4, stream>>>(A1, Acol, D_);
    gemm64<0, 1><<<dim3(D_ / 64, M / 64), 256, 0, stream>>>(
        Acol, pre_w1, pre_b1, A0, M, D_, D_ * 3);
    ln2d_partial<<<dim3(NC_, B_), 256, 0, stream>>>(A0, part, D_ * T_);
    ln2d_apply_t<<<dim3(T_ / 32, D_ / 32, B_), 256, 0, stream>>>(
        A0, pre_lnw1, pre_lnb1, part, pos_emb, H);

    // ---- transformer layers (5 dispatches each)
    for (int l = 0; l < L_; ++l) {
        gemm64w<0><<<dim3(768 / 64, M / 64), 256, 0, stream>>>(
            H, wqkv_bf + (size_t)l * 196608, bqkv + (size_t)l * 768, QKV, M, 768, D_);
        attn_mfma<<<dim3(T_ / 64, H_, B_), 256, 0, stream>>>(QKV, ATT);
        gemm_ln<256><<<M / 16, 256, 0, stream>>>(
            ATT, wo_bf + (size_t)l * 65536, bo + (size_t)l * D_, H,
            ln1w + (size_t)l * D_, ln1b + (size_t)l * D_);
        gemm64w<1><<<dim3(DFF_ / 64, M / 64), 256, 0, stream>>>(
            H, w1_bf + (size_t)l * 131072, b1 + (size_t)l * DFF_, F, M, DFF_, D_);
        gemm_ln<512><<<M / 16, 256, 0, stream>>>(
            F, w2_bf + (size_t)l * 131072, b2 + (size_t)l * D_, H,
            ln2w + (size_t)l * D_, ln2b + (size_t)l * D_);
    }

    // ---- post stage
    im2col_btd<<<dim3(T_ / 32, B_), 256, 0, stream>>>(H, Acol);
    gemm64<0, 1><<<dim3(D_ / 64, M / 64), 256, 0, stream>>>(
        Acol, post_w0, post_b0, A1, M, D_, D_ * 3);
    ln2d_partial<<<dim3(NC_, B_), 256, 0, stream>>>(A1, part, D_ * T_);
    ln2d_apply<<<dim3(D_ * T_ / 1024, B_), 256, 0, stream>>>(A1, post_lnw0, post_lnb0, part, A0, D_ * T_);

    im2col_kernel<<<dim3(T_ / 32, B_), 256, D_ * 34 * 4, stream>>>(A0, Acol, D_);
    gemm64<0, 1><<<dim3(CIN_ / 64, M / 64), 256, 0, stream>>>(
        Acol, post_w1, post_b1, A1, M, CIN_, D_ * 3);
    ln2d_partial<<<dim3(NC_, B_), 256, 0, stream>>>(A1, part, CIN_ * T_);
    ln2d_apply<<<dim3(CIN_ * T_ / 1024, B_), 256, 0, stream>>>(A1, post_lnw1, post_lnb1, part,
                                                               (float*)d_out, CIN_ * T_);
}

// Round 11
// 381.146 us; speedup vs baseline: 6.0535x; 1.0502x over previous
//
#include <hip/hip_runtime.h>
#include <hip/hip_bf16.h>

#define B_ 4
#define T_ 1024
#define D_ 256
#define H_ 8
#define WIN_ 64
#define CIN_ 128
#define DH_ 32
#define DFF_ 512
#define L_ 4
#define NC_ 32   // LN2d reduction chunks per batch
#define PSTR 152 // Ps/Vt LDS row stride (shorts)

typedef __attribute__((ext_vector_type(4))) short s16x4;
typedef __attribute__((ext_vector_type(8))) short s16x8;
typedef __attribute__((ext_vector_type(4))) float f32x4;

__device__ inline short f2bf(float f) {
    __hip_bfloat16 h = __float2bfloat16(f);
    return *reinterpret_cast<short*>(&h);
}

// ---------------- one-time weight prep:
// [0, 2097152): transformer Wqkv|Wo|W1|W2 fp32->bf16 (row-major [N][K])
// [2097152, 2686976): conv weights reordered [O][k*I+i] = w[o][i*3+k], bf16
__global__ __launch_bounds__(256) void prep_w(
    const float* __restrict__ wqkv, const float* __restrict__ wo,
    const float* __restrict__ w1, const float* __restrict__ w2,
    const float* __restrict__ pw0, const float* __restrict__ pw1,
    const float* __restrict__ qw0, const float* __restrict__ qw1,
    short* __restrict__ dst) {
    const int N0 = 786432, N1 = 1048576, N2 = 1572864, NT = 2097152;
    const int NTOT = 2686976;
    for (int i = blockIdx.x * 256 + threadIdx.x; i < NTOT; i += gridDim.x * 256) {
        float v;
        if (i < NT) {
            if (i < N0) v = wqkv[i];
            else if (i < N1) v = wo[i - N0];
            else if (i < N2) v = w1[i - N1];
            else v = w2[i - N2];
        } else {
            int j = i - NT;
            const float* src;
            int I;
            if (j < 98304)       { src = pw0; I = 128; }
            else if (j < 294912) { src = pw1; I = 256; j -= 98304; }
            else if (j < 491520) { src = qw0; I = 256; j -= 294912; }
            else                 { src = qw1; I = 256; j -= 491520; }
            int o = j / (3 * I);
            int rem = j - o * 3 * I;
            int k = rem / I, ii = rem - k * I;
            v = src[(size_t)(o * I + ii) * 3 + k];
        }
        dst[i] = f2bf(v);
    }
}

// ---------------- fused im2col + bf16 MFMA conv-GEMM, 64x64 tile, BK=32
// y[b,o,t] = bias[o] + sum_k sum_i x(b,i,t+k-1) * w[o,i,k];  Wr layout [O][k*I+i].
// BTD=0: input [B,I,T] (t contiguous). BTD=1: input [B,T,I] (i contiguous).
// Output: Y[B][O][1024] (channel-major), row r = b*1024+t.
template <int I_, int BTD>
__global__ __launch_bounds__(256) void gemm_conv(
    const float* __restrict__ x, const short* __restrict__ Wr,
    const float* __restrict__ bias, float* __restrict__ Y, int O) {
    const int K = 3 * I_;
    __shared__ short Al[64 * 40];
    __shared__ short Wl[64 * 40];
    int tid = threadIdx.x;
    int row0 = blockIdx.y * 64, col0 = blockIdx.x * 64;
    int b = row0 >> 10, t0 = row0 & 1023;
    int wave = tid >> 6, lane = tid & 63;
    int wr_ = wave >> 1, wc = wave & 1;
    int lg = lane >> 4, lr = lane & 15;
    f32x4 acc[2][2] = {};

    for (int k0 = 0; k0 < K; k0 += 32) {
        int k = k0 / I_;          // tap (chunk never crosses tap: I_ % 32 == 0)
        int i0 = k0 - k * I_;     // channel base
        if (BTD) {
#pragma unroll
            for (int p = 0; p < 8; ++p) {
                int e = p * 256 + tid;
                int rr = e >> 5, cc = e & 31;
                int tg = t0 + rr - 1 + k;
                float v = (tg >= 0 && tg < T_)
                              ? x[((size_t)(b * T_ + tg)) * I_ + i0 + cc] : 0.f;
                Al[rr * 40 + cc] = f2bf(v);
            }
        } else {
#pragma unroll
            for (int p = 0; p < 8; ++p) {
                int e = p * 256 + tid;
                int cc = e >> 6, rr = e & 63;
                int tg = t0 + rr - 1 + k;
                float v = (tg >= 0 && tg < T_)
                              ? x[((size_t)(b * I_ + i0 + cc)) * T_ + tg] : 0.f;
                Al[rr * 40 + cc] = f2bf(v);
            }
        }
#pragma unroll
        for (int p = 0; p < 2; ++p) {
            int rr = (tid >> 3) + p * 32;
            int ccc = (tid & 7) * 4;
            *(s16x4*)&Wl[rr * 40 + ccc] =
                *(const s16x4*)&Wr[(size_t)(col0 + rr) * K + k0 + ccc];
        }
        __syncthreads();
        s16x8 af[2], wf[2];
#pragma unroll
        for (int i = 0; i < 2; ++i) {
            af[i] = *(const s16x8*)&Al[(wr_ * 32 + i * 16 + lr) * 40 + lg * 8];
            wf[i] = *(const s16x8*)&Wl[(wc * 32 + i * 16 + lr) * 40 + lg * 8];
        }
#pragma unroll
        for (int i = 0; i < 2; ++i)
#pragma unroll
            for (int j = 0; j < 2; ++j)
                acc[i][j] = __builtin_amdgcn_mfma_f32_16x16x32_bf16(af[i], wf[j], acc[i][j], 0, 0, 0);
        __syncthreads();
    }

#pragma unroll
    for (int i = 0; i < 2; ++i) {
        int tg = t0 + wr_ * 32 + i * 16 + lg * 4;
#pragma unroll
        for (int j = 0; j < 2; ++j) {
            int cg = col0 + wc * 32 + j * 16 + lr;
            float bv = bias[cg];
            float4 o;
            o.x = acc[i][j][0] + bv; o.y = acc[i][j][1] + bv;
            o.z = acc[i][j][2] + bv; o.w = acc[i][j][3] + bv;
            *(float4*)&Y[((size_t)(b * O + cg)) * 1024 + tg] = o;
        }
    }
}

// ---------------- bf16-weight MFMA GEMM (QKV, FFN1): Y = A @ Wbf^T + bias
// BF16OUT=1: Y is bf16 (short*), else fp32.
template <int RELU, int BF16OUT>
__global__ __launch_bounds__(256) void gemm64w(
    const float* __restrict__ A, const short* __restrict__ Wbf,
    const float* __restrict__ bias, void* __restrict__ Yv,
    int M, int N, int K) {
    __shared__ short Al[64 * 40];
    __shared__ short Wl[64 * 40];
    int tid = threadIdx.x;
    int row0 = blockIdx.y * 64, col0 = blockIdx.x * 64;
    int wave = tid >> 6, lane = tid & 63;
    int wr = wave >> 1, wc = wave & 1;
    int lg = lane >> 4, lr = lane & 15;
    f32x4 acc[2][2] = {};

    int srow = tid >> 3;
    int scol = (tid & 7) * 4;
    for (int k0 = 0; k0 < K; k0 += 32) {
#pragma unroll
        for (int p = 0; p < 2; ++p) {
            int rr = srow + p * 32;
            float4 va = *(const float4*)&A[(size_t)(row0 + rr) * K + k0 + scol];
            s16x4 sa;
            sa[0] = f2bf(va.x); sa[1] = f2bf(va.y); sa[2] = f2bf(va.z); sa[3] = f2bf(va.w);
            *(s16x4*)&Al[rr * 40 + scol] = sa;
            *(s16x4*)&Wl[rr * 40 + scol] =
                *(const s16x4*)&Wbf[(size_t)(col0 + rr) * K + k0 + scol];
        }
        __syncthreads();
        s16x8 af[2], wf[2];
#pragma unroll
        for (int i = 0; i < 2; ++i) {
            af[i] = *(const s16x8*)&Al[(wr * 32 + i * 16 + lr) * 40 + lg * 8];
            wf[i] = *(const s16x8*)&Wl[(wc * 32 + i * 16 + lr) * 40 + lg * 8];
        }
#pragma unroll
        for (int i = 0; i < 2; ++i)
#pragma unroll
            for (int j = 0; j < 2; ++j)
                acc[i][j] = __builtin_amdgcn_mfma_f32_16x16x32_bf16(af[i], wf[j], acc[i][j], 0, 0, 0);
        __syncthreads();
    }
#pragma unroll
    for (int i = 0; i < 2; ++i) {
        int rg = row0 + wr * 32 + i * 16 + lg * 4;
#pragma unroll
        for (int j = 0; j < 2; ++j) {
            int cg = col0 + wc * 32 + j * 16 + lr;
            float bv = bias[cg];
#pragma unroll
            for (int q = 0; q < 4; ++q) {
                float v = acc[i][j][q] + bv;
                if (RELU) v = fmaxf(v, 0.f);
                if (BF16OUT) ((short*)Yv)[(size_t)(rg + q) * N + cg] = f2bf(v);
                else ((float*)Yv)[(size_t)(rg + q) * N + cg] = v;
            }
        }
    }
}

// ---------------- fused GEMM(full N=256) + bias + residual + row-LN, in-place on H
// H[r] = LN(H[r] + A[r] @ Wbf^T + bias), 16 rows/block, grid M/16.
// BF16A=1: A is bf16.
template <int KK, int BF16A>
__global__ __launch_bounds__(256) void gemm_ln(
    const void* __restrict__ Av, const short* __restrict__ Wbf,
    const float* __restrict__ bias, float* __restrict__ H,
    const float* __restrict__ lnw, const float* __restrict__ lnb) {
    __shared__ short As[16 * 40];
    __shared__ short Ws[256 * 40];
    __shared__ float Gs[16][260];
    int tid = threadIdx.x;
    int wave = tid >> 6, lane = tid & 63;
    int lg = lane >> 4, lr = lane & 15;
    int m0 = blockIdx.x * 16;
    f32x4 acc[4] = {};

    for (int k0 = 0; k0 < KK; k0 += 32) {
        if (tid < 128) {
            int r = tid >> 3, c = (tid & 7) * 4;
            if (BF16A) {
                *(s16x4*)&As[r * 40 + c] =
                    *(const s16x4*)&((const short*)Av)[(size_t)(m0 + r) * KK + k0 + c];
            } else {
                float4 va = *(const float4*)&((const float*)Av)[(size_t)(m0 + r) * KK + k0 + c];
                s16x4 sa;
                sa[0] = f2bf(va.x); sa[1] = f2bf(va.y); sa[2] = f2bf(va.z); sa[3] = f2bf(va.w);
                *(s16x4*)&As[r * 40 + c] = sa;
            }
        }
#pragma unroll
        for (int u = 0; u < 4; ++u) {
            int task = tid + 256 * u;      // 1024 tasks: 256 rows x 4 chunks of 8
            int r = task >> 2, c8 = (task & 3) * 8;
            *(s16x8*)&Ws[r * 40 + c8] = *(const s16x8*)&Wbf[(size_t)r * KK + k0 + c8];
        }
        __syncthreads();
        s16x8 af = *(const s16x8*)&As[lr * 40 + lg * 8];
#pragma unroll
        for (int j = 0; j < 4; ++j) {
            s16x8 wf = *(const s16x8*)&Ws[(wave * 64 + j * 16 + lr) * 40 + lg * 8];
            acc[j] = __builtin_amdgcn_mfma_f32_16x16x32_bf16(af, wf, acc[j], 0, 0, 0);
        }
        __syncthreads();
    }

#pragma unroll
    for (int j = 0; j < 4; ++j) {
        int col = wave * 64 + j * 16 + lr;
        float bv = bias[col];
#pragma unroll
        for (int q = 0; q < 4; ++q)
            Gs[lg * 4 + q][col] = acc[j][q] + bv;
    }
    __syncthreads();

    for (int rr = 0; rr < 4; ++rr) {
        int row = wave * 4 + rr;
        size_t base = (size_t)(m0 + row) * D_;
        float x[4];
        float s = 0.f;
#pragma unroll
        for (int i = 0; i < 4; ++i) {
            int idx = i * 64 + lane;
            x[i] = H[base + idx] + Gs[row][idx];
            s += x[i];
        }
#pragma unroll
        for (int off = 32; off; off >>= 1) s += __shfl_xor(s, off);
        float mu = s * (1.f / D_);
        float ss = 0.f;
#pragma unroll
        for (int i = 0; i < 4; ++i) { float d = x[i] - mu; ss += d * d; }
#pragma unroll
        for (int off = 32; off; off >>= 1) ss += __shfl_xor(ss, off);
        float rstd = rsqrtf(ss * (1.f / D_) + 1e-5f);
#pragma unroll
        for (int i = 0; i < 4; ++i) {
            int idx = i * 64 + lane;
            H[base + idx] = (x[i] - mu) * rstd * lnw[idx] + lnb[idx];
        }
    }
}

// ---------------- MFMA banded attention (bf16 in, bf16 out)
__global__ __launch_bounds__(256) void attn_mfma(
    const short* __restrict__ qkv, short* __restrict__ out) {
    int q0 = blockIdx.x * 64;
    int h = blockIdx.y, b = blockIdx.z;
    int tid = threadIdx.x;
    int wave = tid >> 6, lane = tid & 63;
    int lg = lane >> 4;
    int lr = lane & 15;
    const int j0 = q0 - 64;

    __shared__ short Qs[64][40];
    __shared__ short Ks[128][40];
    __shared__ short Vt[32][PSTR];
    __shared__ short Ps[64][PSTR];

#pragma unroll
    for (int u = 0; u < 2; ++u) {
        int task = tid + 256 * u;
        int r = task >> 3, c = (task & 7) * 4;
        *(s16x4*)&Qs[r][c] =
            *(const s16x4*)&qkv[((size_t)(b * T_ + q0 + r)) * 768 + h * 32 + c];
    }
#pragma unroll
    for (int u = 0; u < 4; ++u) {
        int task = tid + 256 * u;
        int r = task >> 3, c = (task & 7) * 4;
        int jg = j0 + r;
        s16x4 sa = {0, 0, 0, 0};
        if (jg >= 0)
            sa = *(const s16x4*)&qkv[((size_t)(b * T_ + jg)) * 768 + 256 + h * 32 + c];
        *(s16x4*)&Ks[r][c] = sa;
    }
#pragma unroll
    for (int u = 0; u < 4; ++u) {
        int task = tid + 256 * u;
        int r = task >> 3, c = (task & 7) * 4;
        int jg = j0 + r;
        s16x4 v4 = {0, 0, 0, 0};
        if (jg >= 0)
            v4 = *(const s16x4*)&qkv[((size_t)(b * T_ + jg)) * 768 + 512 + h * 32 + c];
        Vt[c + 0][r] = v4[0];
        Vt[c + 1][r] = v4[1];
        Vt[c + 2][r] = v4[2];
        Vt[c + 3][r] = v4[3];
    }
    __syncthreads();

    s16x8 aq = *(const s16x8*)&Qs[16 * wave + lr][lg * 8];
    f32x4 sacc[8];
#pragma unroll
    for (int j = 0; j < 8; ++j) {
        s16x8 bk = *(const s16x8*)&Ks[16 * j + lr][lg * 8];
        f32x4 z = {0.f, 0.f, 0.f, 0.f};
        sacc[j] = __builtin_amdgcn_mfma_f32_16x16x32_bf16(aq, bk, z, 0, 0, 0);
    }

    const float scale = 0.17677669529663687f;
#pragma unroll
    for (int j = 0; j < 8; ++j) {
        int jg = j0 + 16 * j + lr;
#pragma unroll
        for (int q = 0; q < 4; ++q) {
            int qi = q0 + 16 * wave + lg * 4 + q;
            bool ok = ((jg >= qi - WIN_) && (jg < qi) && (jg >= 0)) || (qi == 0 && jg == 0);
            sacc[j][q] = ok ? sacc[j][q] * scale : -1e30f;
        }
    }
#pragma unroll
    for (int q = 0; q < 4; ++q) {
        float m = sacc[0][q];
#pragma unroll
        for (int j = 1; j < 8; ++j) m = fmaxf(m, sacc[j][q]);
#pragma unroll
        for (int off = 1; off < 16; off <<= 1) m = fmaxf(m, __shfl_xor(m, off));
        float e[8], sum = 0.f;
#pragma unroll
        for (int j = 0; j < 8; ++j) { e[j] = __expf(sacc[j][q] - m); sum += e[j]; }
#pragma unroll
        for (int off = 1; off < 16; off <<= 1) sum += __shfl_xor(sum, off);
        float inv = 1.f / sum;
        int row = 16 * wave + lg * 4 + q;
#pragma unroll
        for (int j = 0; j < 8; ++j) Ps[row][16 * j + lr] = f2bf(e[j] * inv);
    }

    f32x4 oacc[2] = {};
#pragma unroll
    for (int kk = 0; kk < 4; ++kk) {
        s16x8 ap = *(const s16x8*)&Ps[16 * wave + lr][kk * 32 + lg * 8];
#pragma unroll
        for (int n = 0; n < 2; ++n) {
            s16x8 bv = *(const s16x8*)&Vt[16 * n + lr][kk * 32 + lg * 8];
            oacc[n] = __builtin_amdgcn_mfma_f32_16x16x32_bf16(ap, bv, oacc[n], 0, 0, 0);
        }
    }
#pragma unroll
    for (int n = 0; n < 2; ++n)
#pragma unroll
        for (int q = 0; q < 4; ++q) {
            int qi = q0 + 16 * wave + lg * 4 + q;
            out[((size_t)(b * T_ + qi)) * D_ + h * 32 + 16 * n + lr] = f2bf(oacc[n][q]);
        }
}

// ---------------- LN2d stage A: partial sums per (chunk, batch)
__global__ __launch_bounds__(256) void ln2d_partial(
    const float* __restrict__ x, float* __restrict__ part, int CT) {
    int b = blockIdx.y;
    int chunk = blockIdx.x;
    int n4 = CT / (4 * NC_);
    const float4* xb = (const float4*)(x + (size_t)b * CT) + (size_t)chunk * n4;
    float s = 0.f, ss = 0.f;
    for (int i = threadIdx.x; i < n4; i += 256) {
        float4 v = xb[i];
        s += v.x + v.y + v.z + v.w;
        ss += v.x * v.x + v.y * v.y + v.z * v.z + v.w * v.w;
    }
#pragma unroll
    for (int off = 32; off; off >>= 1) {
        s += __shfl_xor(s, off);
        ss += __shfl_xor(ss, off);
    }
    __shared__ float sh0[4], sh1[4];
    int wave = threadIdx.x >> 6;
    if ((threadIdx.x & 63) == 0) { sh0[wave] = s; sh1[wave] = ss; }
    __syncthreads();
    if (threadIdx.x == 0) {
        part[(size_t)(b * NC_ + chunk) * 2] = sh0[0] + sh0[1] + sh0[2] + sh0[3];
        part[(size_t)(b * NC_ + chunk) * 2 + 1] = sh1[0] + sh1[1] + sh1[2] + sh1[3];
    }
}

__device__ inline void ln2d_stats(const float* __restrict__ part, int b, int CT,
                                  float& mu, float& rstd) {
    float s = 0.f, ss = 0.f;
    const float2* p2 = (const float2*)(part + (size_t)b * NC_ * 2);
#pragma unroll
    for (int i = 0; i < NC_; ++i) { float2 v = p2[i]; s += v.x; ss += v.y; }
    mu = s / (float)CT;
    rstd = rsqrtf(ss / (float)CT - mu * mu + 1e-5f);
}

// ---------------- LN2d apply + ReLU (float4), final-reduce fused
__global__ __launch_bounds__(256) void ln2d_apply(
    const float* __restrict__ x, const float* __restrict__ w,
    const float* __restrict__ bb, const float* __restrict__ part,
    float* __restrict__ y, int CT) {
    int idx = blockIdx.x * 256 + threadIdx.x;
    int b = blockIdx.y;
    float mu, rstd;
    ln2d_stats(part, b, CT, mu, rstd);
    const float4* x4 = (const float4*)(x + (size_t)b * CT);
    const float4* w4 = (const float4*)w;
    const float4* b4 = (const float4*)bb;
    float4* y4 = (float4*)(y + (size_t)b * CT);
    float4 v = x4[idx], wv = w4[idx], bv = b4[idx];
    float4 r;
    r.x = fmaxf((v.x - mu) * rstd * wv.x + bv.x, 0.f);
    r.y = fmaxf((v.y - mu) * rstd * wv.y + bv.y, 0.f);
    r.z = fmaxf((v.z - mu) * rstd * wv.z + bv.z, 0.f);
    r.w = fmaxf((v.w - mu) * rstd * wv.w + bv.w, 0.f);
    y4[idx] = r;
}

// ---------------- LN2d apply + ReLU + transpose + pos add: [B,D,T] -> [B,T,D]
__global__ __launch_bounds__(256) void ln2d_apply_t(
    const float* __restrict__ x, const float* __restrict__ w,
    const float* __restrict__ bb, const float* __restrict__ part,
    const float* __restrict__ pos, float* __restrict__ h) {
    int t0 = blockIdx.x * 32;
    int d0 = blockIdx.y * 32;
    int b = blockIdx.z;
    float mu, rstd;
    ln2d_stats(part, b, D_ * T_, mu, rstd);
    __shared__ float xs[32][33];
    int tt = threadIdx.x & 31, dd = threadIdx.x >> 5;
#pragma unroll
    for (int p = 0; p < 4; ++p) {
        int d = d0 + dd + p * 8;
        size_t off = ((size_t)b * D_ + d) * T_ + t0 + tt;
        size_t woff = (size_t)d * T_ + t0 + tt;
        float v = (x[off] - mu) * rstd * w[woff] + bb[woff];
        xs[dd + p * 8][tt] = fmaxf(v, 0.f);
    }
    __syncthreads();
    int dd2 = threadIdx.x & 31, tt2 = threadIdx.x >> 5;
#pragma unroll
    for (int p = 0; p < 4; ++p) {
        int t = t0 + tt2 + p * 8;
        h[((size_t)(b * T_ + t)) * D_ + d0 + dd2] =
            xs[dd2][tt2 + p * 8] + pos[(size_t)t * D_ + d0 + dd2];
    }
}

extern "C" void kernel_launch(void* const* d_in, const int* in_sizes, int n_in,
                              void* d_out, int out_size, void* d_ws, size_t ws_size,
                              hipStream_t stream) {
    const float* x        = (const float*)d_in[0];
    const float* pre_w0   = (const float*)d_in[1];
    const float* pre_b0   = (const float*)d_in[2];
    const float* pre_lnw0 = (const float*)d_in[3];
    const float* pre_lnb0 = (const float*)d_in[4];
    const float* pre_w1   = (const float*)d_in[5];
    const float* pre_b1   = (const float*)d_in[6];
    const float* pre_lnw1 = (const float*)d_in[7];
    const float* pre_lnb1 = (const float*)d_in[8];
    const float* pos_emb  = (const float*)d_in[9];
    const float* Wqkv     = (const float*)d_in[10];
    const float* bqkv     = (const float*)d_in[11];
    const float* Wo       = (const float*)d_in[12];
    const float* bo       = (const float*)d_in[13];
    const float* ln1w     = (const float*)d_in[14];
    const float* ln1b     = (const float*)d_in[15];
    const float* W1       = (const float*)d_in[16];
    const float* b1       = (const float*)d_in[17];
    const float* W2       = (const float*)d_in[18];
    const float* b2       = (const float*)d_in[19];
    const float* ln2w     = (const float*)d_in[20];
    const float* ln2b     = (const float*)d_in[21];
    const float* post_w0  = (const float*)d_in[22];
    const float* post_b0  = (const float*)d_in[23];
    const float* post_lnw0= (const float*)d_in[24];
    const float* post_lnb0= (const float*)d_in[25];
    const float* post_w1  = (const float*)d_in[26];
    const float* post_b1  = (const float*)d_in[27];
    const float* post_lnw1= (const float*)d_in[28];
    const float* post_lnb1= (const float*)d_in[29];

    float* ws = (float*)d_ws;
    const size_t M1 = 1u << 20;              // 1M floats
    float* H     = ws;                       // [B,T,D] fp32          1M
    float* A0    = ws + 1 * M1;              // [B,D,T] fp32          1M (pre/post only)
    float* A1    = ws + 2 * M1;              // [B,D,T] fp32          1M (pre/post only)
    short* QKVb  = (short*)(ws + 1 * M1);    // [B,T,768] bf16        (transformer only; aliases A0/A1)
    short* Fb    = (short*)(ws + 4 * M1);    // [B,T,512] bf16
    short* ATTb  = (short*)(ws + 5 * M1);    // [B,T,256] bf16
    short* wbf   = (short*)(ws + 6 * M1);    // 2097152 shorts (transformer w)
    short* wqkv_bf = wbf;
    short* wo_bf   = wbf + 786432;
    short* w1_bf   = wbf + 1048576;
    short* w2_bf   = wbf + 1572864;
    short* cwbf  = wbf + 2097152;            // conv weights reordered
    short* cw_pre0  = cwbf;                  // [256][3*128]
    short* cw_pre1  = cwbf + 98304;          // [256][3*256]
    short* cw_post0 = cwbf + 294912;         // [256][3*256]
    short* cw_post1 = cwbf + 491520;         // [128][3*256]
    float* part  = ws + 8 * M1;

    const int M = B_ * T_;  // 4096

    // ---- one-time weight prep (bf16 + conv reorder) — dst MUST be wbf (bug fix R10)
    prep_w<<<2048, 256, 0, stream>>>(Wqkv, Wo, W1, W2,
                                     pre_w0, pre_w1, post_w0, post_w1, wbf);

    // ---- pre stage (fused im2col+GEMM)
    gemm_conv<128, 0><<<dim3(D_ / 64, M / 64), 256, 0, stream>>>(
        x, cw_pre0, pre_b0, A0, D_);
    ln2d_partial<<<dim3(NC_, B_), 256, 0, stream>>>(A0, part, D_ * T_);
    ln2d_apply<<<dim3(D_ * T_ / 1024, B_), 256, 0, stream>>>(A0, pre_lnw0, pre_lnb0, part, A1, D_ * T_);

    gemm_conv<256, 0><<<dim3(D_ / 64, M / 64), 256, 0, stream>>>(
        A1, cw_pre1, pre_b1, A0, D_);
    ln2d_partial<<<dim3(NC_, B_), 256, 0, stream>>>(A0, part, D_ * T_);
    ln2d_apply_t<<<dim3(T_ / 32, D_ / 32, B_), 256, 0, stream>>>(
        A0, pre_lnw1, pre_lnb1, part, pos_emb, H);

    // ---- transformer layers (5 dispatches each)
    for (int l = 0; l < L_; ++l) {
        gemm64w<0, 1><<<dim3(768 / 64, M / 64), 256, 0, stream>>>(
            H, wqkv_bf + (size_t)l * 196608, bqkv + (size_t)l * 768, QKVb, M, 768, D_);
        attn_mfma<<<dim3(T_ / 64, H_, B_), 256, 0, stream>>>(QKVb, ATTb);
        gemm_ln<256, 1><<<M / 16, 256, 0, stream>>>(
            ATTb, wo_bf + (size_t)l * 65536, bo + (size_t)l * D_, H,
            ln1w + (size_t)l * D_, ln1b + (size_t)l * D_);
        gemm64w<1, 1><<<dim3(DFF_ / 64, M / 64), 256, 0, stream>>>(
            H, w1_bf + (size_t)l * 131072, b1 + (size_t)l * DFF_, Fb, M, DFF_, D_);
        gemm_ln<512, 1><<<M / 16, 256, 0, stream>>>(
            Fb, w2_bf + (size_t)l * 131072, b2 + (size_t)l * D_, H,
            ln2w + (size_t)l * D_, ln2b + (size_t)l * D_);
    }

    // ---- post stage (conv1 reads H [B,T,D] directly via BTD staging)
    gemm_conv<256, 1><<<dim3(D_ / 64, M / 64), 256, 0, stream>>>(
        H, cw_post0, post_b0, A1, D_);
    ln2d_partial<<<dim3(NC_, B_), 256, 0, stream>>>(A1, part, D_ * T_);
    ln2d_apply<<<dim3(D_ * T_ / 1024, B_), 256, 0, stream>>>(A1, post_lnw0, post_lnb0, part, A0, D_ * T_);

    gemm_conv<256, 0><<<dim3(CIN_ / 64, M / 64), 256, 0, stream>>>(
        A0, cw_post1, post_b1, A1, CIN_);
    ln2d_partial<<<dim3(NC_, B_), 256, 0, stream>>>(A1, part, CIN_ * T_);
    ln2d_apply<<<dim3(CIN_ * T_ / 1024, B_), 256, 0, stream>>>(A1, post_lnw1, post_lnb1, part,
                                                               (float*)d_out, CIN_ * T_);
}

// Round 13
// 310.798 us; speedup vs baseline: 7.4237x; 1.2263x over previous
//
#include <hip/hip_runtime.h>
#include <hip/hip_bf16.h>

#define B_ 4
#define T_ 1024
#define D_ 256
#define H_ 8
#define WIN_ 64
#define CIN_ 128
#define DH_ 32
#define DFF_ 512
#define L_ 4
#define NC_ 32   // LN2d reduction chunks per batch
#define PSTR 152 // Ps/Vt LDS row stride (shorts)

typedef __attribute__((ext_vector_type(4))) short s16x4;
typedef __attribute__((ext_vector_type(8))) short s16x8;
typedef __attribute__((ext_vector_type(4))) float f32x4;

__device__ inline short f2bf(float f) {
    __hip_bfloat16 h = __float2bfloat16(f);
    return *reinterpret_cast<short*>(&h);
}

// ---------------- one-time weight prep:
// [0, 2097152): transformer Wqkv|Wo|W1|W2 fp32->bf16 (row-major [N][K])
// [2097152, 2686976): conv weights reordered [O][k*I+i] = w[o][i*3+k], bf16
__global__ __launch_bounds__(256) void prep_w(
    const float* __restrict__ wqkv, const float* __restrict__ wo,
    const float* __restrict__ w1, const float* __restrict__ w2,
    const float* __restrict__ pw0, const float* __restrict__ pw1,
    const float* __restrict__ qw0, const float* __restrict__ qw1,
    short* __restrict__ dst) {
    const int N0 = 786432, N1 = 1048576, N2 = 1572864, NT = 2097152;
    const int NTOT = 2686976;
    for (int i = blockIdx.x * 256 + threadIdx.x; i < NTOT; i += gridDim.x * 256) {
        float v;
        if (i < NT) {
            if (i < N0) v = wqkv[i];
            else if (i < N1) v = wo[i - N0];
            else if (i < N2) v = w1[i - N1];
            else v = w2[i - N2];
        } else {
            int j = i - NT;
            const float* src;
            int I;
            if (j < 98304)       { src = pw0; I = 128; }
            else if (j < 294912) { src = pw1; I = 256; j -= 98304; }
            else if (j < 491520) { src = qw0; I = 256; j -= 294912; }
            else                 { src = qw1; I = 256; j -= 491520; }
            int o = j / (3 * I);
            int rem = j - o * 3 * I;
            int k = rem / I, ii = rem - k * I;
            v = src[(size_t)(o * I + ii) * 3 + k];
        }
        dst[i] = f2bf(v);
    }
}

// ---------------- fused im2col + bf16 MFMA conv-GEMM, 16x64 tile, BK=32
// y[b,o,t] = bias[o] + sum_k sum_i x(b,i,t+k-1) * w[o,i,k];  Wr layout [O][k*I+i].
// BTD=0: input [B,I,T]. BTD=1: input [B,T,I]. Output Y[B][O][1024], row r=b*1024+t.
// Grid (O/64, M/16), 256 threads; wave w computes cols w*16..+15.
template <int I_, int BTD>
__global__ __launch_bounds__(256) void gemm_conv16(
    const float* __restrict__ x, const short* __restrict__ Wr,
    const float* __restrict__ bias, float* __restrict__ Y, int O) {
    const int K = 3 * I_;
    __shared__ short Al[16 * 40];
    __shared__ short Wl[64 * 40];
    int tid = threadIdx.x;
    int col0 = blockIdx.x * 64;
    int row0 = blockIdx.y * 16;
    int b = row0 >> 10, t0 = row0 & 1023;
    int wave = tid >> 6, lane = tid & 63;
    int lg = lane >> 4, lr = lane & 15;
    f32x4 acc = {0.f, 0.f, 0.f, 0.f};

    for (int k0 = 0; k0 < K; k0 += 32) {
        int k = k0 / I_;          // tap (chunk never crosses tap: I_ % 32 == 0)
        int i0 = k0 - k * I_;     // channel base
        // A tile: 16 rows (t) x 32 (channels), 512 elems, 2/thread
#pragma unroll
        for (int p = 0; p < 2; ++p) {
            int e = p * 256 + tid;
            int rr, cc;
            float v;
            if (BTD) {
                rr = e >> 5; cc = e & 31;
                int tg = t0 + rr - 1 + k;
                v = (tg >= 0 && tg < T_) ? x[((size_t)(b * T_ + tg)) * I_ + i0 + cc] : 0.f;
            } else {
                cc = e >> 4; rr = e & 15;
                int tg = t0 + rr - 1 + k;
                v = (tg >= 0 && tg < T_) ? x[((size_t)(b * I_ + i0 + cc)) * T_ + tg] : 0.f;
            }
            Al[rr * 40 + cc] = f2bf(v);
        }
        // W tile: 64 rows x 32, vectorized copy
#pragma unroll
        for (int p = 0; p < 2; ++p) {
            int rr = (tid >> 3) + p * 32;
            int ccc = (tid & 7) * 4;
            *(s16x4*)&Wl[rr * 40 + ccc] =
                *(const s16x4*)&Wr[(size_t)(col0 + rr) * K + k0 + ccc];
        }
        __syncthreads();
        s16x8 af = *(const s16x8*)&Al[lr * 40 + lg * 8];
        s16x8 wf = *(const s16x8*)&Wl[(wave * 16 + lr) * 40 + lg * 8];
        acc = __builtin_amdgcn_mfma_f32_16x16x32_bf16(af, wf, acc, 0, 0, 0);
        __syncthreads();
    }

    int cg = col0 + wave * 16 + lr;
    float bv = bias[cg];
    float4 o;
    o.x = acc[0] + bv; o.y = acc[1] + bv; o.z = acc[2] + bv; o.w = acc[3] + bv;
    *(float4*)&Y[((size_t)(b * O + cg)) * 1024 + t0 + lg * 4] = o;
}

// ---------------- bf16-weight MFMA GEMM (QKV, FFN1): Y = A @ Wbf^T + bias
// BF16OUT=1: Y is bf16 (short*), else fp32.
template <int RELU, int BF16OUT>
__global__ __launch_bounds__(256) void gemm64w(
    const float* __restrict__ A, const short* __restrict__ Wbf,
    const float* __restrict__ bias, void* __restrict__ Yv,
    int M, int N, int K) {
    __shared__ short Al[64 * 40];
    __shared__ short Wl[64 * 40];
    int tid = threadIdx.x;
    int row0 = blockIdx.y * 64, col0 = blockIdx.x * 64;
    int wave = tid >> 6, lane = tid & 63;
    int wr = wave >> 1, wc = wave & 1;
    int lg = lane >> 4, lr = lane & 15;
    f32x4 acc[2][2] = {};

    int srow = tid >> 3;
    int scol = (tid & 7) * 4;
    for (int k0 = 0; k0 < K; k0 += 32) {
#pragma unroll
        for (int p = 0; p < 2; ++p) {
            int rr = srow + p * 32;
            float4 va = *(const float4*)&A[(size_t)(row0 + rr) * K + k0 + scol];
            s16x4 sa;
            sa[0] = f2bf(va.x); sa[1] = f2bf(va.y); sa[2] = f2bf(va.z); sa[3] = f2bf(va.w);
            *(s16x4*)&Al[rr * 40 + scol] = sa;
            *(s16x4*)&Wl[rr * 40 + scol] =
                *(const s16x4*)&Wbf[(size_t)(col0 + rr) * K + k0 + scol];
        }
        __syncthreads();
        s16x8 af[2], wf[2];
#pragma unroll
        for (int i = 0; i < 2; ++i) {
            af[i] = *(const s16x8*)&Al[(wr * 32 + i * 16 + lr) * 40 + lg * 8];
            wf[i] = *(const s16x8*)&Wl[(wc * 32 + i * 16 + lr) * 40 + lg * 8];
        }
#pragma unroll
        for (int i = 0; i < 2; ++i)
#pragma unroll
            for (int j = 0; j < 2; ++j)
                acc[i][j] = __builtin_amdgcn_mfma_f32_16x16x32_bf16(af[i], wf[j], acc[i][j], 0, 0, 0);
        __syncthreads();
    }
#pragma unroll
    for (int i = 0; i < 2; ++i) {
        int rg = row0 + wr * 32 + i * 16 + lg * 4;
#pragma unroll
        for (int j = 0; j < 2; ++j) {
            int cg = col0 + wc * 32 + j * 16 + lr;
            float bv = bias[cg];
#pragma unroll
            for (int q = 0; q < 4; ++q) {
                float v = acc[i][j][q] + bv;
                if (RELU) v = fmaxf(v, 0.f);
                if (BF16OUT) ((short*)Yv)[(size_t)(rg + q) * N + cg] = f2bf(v);
                else ((float*)Yv)[(size_t)(rg + q) * N + cg] = v;
            }
        }
    }
}

// ---------------- fused GEMM(full N=256) + bias + residual + row-LN, in-place on H
// H[r] = LN(H[r] + A[r] @ Wbf^T + bias), 16 rows/block, grid M/16, 512 threads.
// Wave w owns cols w*32..+31 (2 MFMA frags). BF16A=1: A is bf16.
template <int KK, int BF16A>
__global__ __launch_bounds__(512) void gemm_ln(
    const void* __restrict__ Av, const short* __restrict__ Wbf,
    const float* __restrict__ bias, float* __restrict__ H,
    const float* __restrict__ lnw, const float* __restrict__ lnb) {
    __shared__ short As[16 * 40];
    __shared__ short Ws[256 * 40];
    __shared__ float Gs[16][260];
    int tid = threadIdx.x;
    int wave = tid >> 6, lane = tid & 63;
    int lg = lane >> 4, lr = lane & 15;
    int m0 = blockIdx.x * 16;
    f32x4 acc[2] = {};

    for (int k0 = 0; k0 < KK; k0 += 32) {
        if (tid < 128) {
            int r = tid >> 3, c = (tid & 7) * 4;
            if (BF16A) {
                *(s16x4*)&As[r * 40 + c] =
                    *(const s16x4*)&((const short*)Av)[(size_t)(m0 + r) * KK + k0 + c];
            } else {
                float4 va = *(const float4*)&((const float*)Av)[(size_t)(m0 + r) * KK + k0 + c];
                s16x4 sa;
                sa[0] = f2bf(va.x); sa[1] = f2bf(va.y); sa[2] = f2bf(va.z); sa[3] = f2bf(va.w);
                *(s16x4*)&As[r * 40 + c] = sa;
            }
        }
#pragma unroll
        for (int u = 0; u < 2; ++u) {
            int task = tid + 512 * u;      // 1024 tasks: 256 rows x 4 chunks of 8
            int r = task >> 2, c8 = (task & 3) * 8;
            *(s16x8*)&Ws[r * 40 + c8] = *(const s16x8*)&Wbf[(size_t)r * KK + k0 + c8];
        }
        __syncthreads();
        s16x8 af = *(const s16x8*)&As[lr * 40 + lg * 8];
#pragma unroll
        for (int j = 0; j < 2; ++j) {
            s16x8 wf = *(const s16x8*)&Ws[(wave * 32 + j * 16 + lr) * 40 + lg * 8];
            acc[j] = __builtin_amdgcn_mfma_f32_16x16x32_bf16(af, wf, acc[j], 0, 0, 0);
        }
        __syncthreads();
    }

#pragma unroll
    for (int j = 0; j < 2; ++j) {
        int col = wave * 32 + j * 16 + lr;
        float bv = bias[col];
#pragma unroll
        for (int q = 0; q < 4; ++q)
            Gs[lg * 4 + q][col] = acc[j][q] + bv;
    }
    __syncthreads();

    // residual + row LN: wave handles rows wave*2..+1
    for (int rr = 0; rr < 2; ++rr) {
        int row = wave * 2 + rr;
        size_t base = (size_t)(m0 + row) * D_;
        float x[4];
        float s = 0.f;
#pragma unroll
        for (int i = 0; i < 4; ++i) {
            int idx = i * 64 + lane;
            x[i] = H[base + idx] + Gs[row][idx];
            s += x[i];
        }
#pragma unroll
        for (int off = 32; off; off >>= 1) s += __shfl_xor(s, off);
        float mu = s * (1.f / D_);
        float ss = 0.f;
#pragma unroll
        for (int i = 0; i < 4; ++i) { float d = x[i] - mu; ss += d * d; }
#pragma unroll
        for (int off = 32; off; off >>= 1) ss += __shfl_xor(ss, off);
        float rstd = rsqrtf(ss * (1.f / D_) + 1e-5f);
#pragma unroll
        for (int i = 0; i < 4; ++i) {
            int idx = i * 64 + lane;
            H[base + idx] = (x[i] - mu) * rstd * lnw[idx] + lnb[idx];
        }
    }
}

// ---------------- MFMA banded attention (bf16 in, bf16 out)
__global__ __launch_bounds__(256) void attn_mfma(
    const short* __restrict__ qkv, short* __restrict__ out) {
    int q0 = blockIdx.x * 64;
    int h = blockIdx.y, b = blockIdx.z;
    int tid = threadIdx.x;
    int wave = tid >> 6, lane = tid & 63;
    int lg = lane >> 4;
    int lr = lane & 15;
    const int j0 = q0 - 64;

    __shared__ short Qs[64][40];
    __shared__ short Ks[128][40];
    __shared__ short Vt[32][PSTR];
    __shared__ short Ps[64][PSTR];

#pragma unroll
    for (int u = 0; u < 2; ++u) {
        int task = tid + 256 * u;
        int r = task >> 3, c = (task & 7) * 4;
        *(s16x4*)&Qs[r][c] =
            *(const s16x4*)&qkv[((size_t)(b * T_ + q0 + r)) * 768 + h * 32 + c];
    }
#pragma unroll
    for (int u = 0; u < 4; ++u) {
        int task = tid + 256 * u;
        int r = task >> 3, c = (task & 7) * 4;
        int jg = j0 + r;
        s16x4 sa = {0, 0, 0, 0};
        if (jg >= 0)
            sa = *(const s16x4*)&qkv[((size_t)(b * T_ + jg)) * 768 + 256 + h * 32 + c];
        *(s16x4*)&Ks[r][c] = sa;
    }
#pragma unroll
    for (int u = 0; u < 4; ++u) {
        int task = tid + 256 * u;
        int r = task >> 3, c = (task & 7) * 4;
        int jg = j0 + r;
        s16x4 v4 = {0, 0, 0, 0};
        if (jg >= 0)
            v4 = *(const s16x4*)&qkv[((size_t)(b * T_ + jg)) * 768 + 512 + h * 32 + c];
        Vt[c + 0][r] = v4[0];
        Vt[c + 1][r] = v4[1];
        Vt[c + 2][r] = v4[2];
        Vt[c + 3][r] = v4[3];
    }
    __syncthreads();

    s16x8 aq = *(const s16x8*)&Qs[16 * wave + lr][lg * 8];
    f32x4 sacc[8];
#pragma unroll
    for (int j = 0; j < 8; ++j) {
        s16x8 bk = *(const s16x8*)&Ks[16 * j + lr][lg * 8];
        f32x4 z = {0.f, 0.f, 0.f, 0.f};
        sacc[j] = __builtin_amdgcn_mfma_f32_16x16x32_bf16(aq, bk, z, 0, 0, 0);
    }

    const float scale = 0.17677669529663687f;
#pragma unroll
    for (int j = 0; j < 8; ++j) {
        int jg = j0 + 16 * j + lr;
#pragma unroll
        for (int q = 0; q < 4; ++q) {
            int qi = q0 + 16 * wave + lg * 4 + q;
            bool ok = ((jg >= qi - WIN_) && (jg < qi) && (jg >= 0)) || (qi == 0 && jg == 0);
            sacc[j][q] = ok ? sacc[j][q] * scale : -1e30f;
        }
    }
#pragma unroll
    for (int q = 0; q < 4; ++q) {
        float m = sacc[0][q];
#pragma unroll
        for (int j = 1; j < 8; ++j) m = fmaxf(m, sacc[j][q]);
#pragma unroll
        for (int off = 1; off < 16; off <<= 1) m = fmaxf(m, __shfl_xor(m, off));
        float e[8], sum = 0.f;
#pragma unroll
        for (int j = 0; j < 8; ++j) { e[j] = __expf(sacc[j][q] - m); sum += e[j]; }
#pragma unroll
        for (int off = 1; off < 16; off <<= 1) sum += __shfl_xor(sum, off);
        float inv = 1.f / sum;
        int row = 16 * wave + lg * 4 + q;
#pragma unroll
        for (int j = 0; j < 8; ++j) Ps[row][16 * j + lr] = f2bf(e[j] * inv);
    }

    f32x4 oacc[2] = {};
#pragma unroll
    for (int kk = 0; kk < 4; ++kk) {
        s16x8 ap = *(const s16x8*)&Ps[16 * wave + lr][kk * 32 + lg * 8];
#pragma unroll
        for (int n = 0; n < 2; ++n) {
            s16x8 bv = *(const s16x8*)&Vt[16 * n + lr][kk * 32 + lg * 8];
            oacc[n] = __builtin_amdgcn_mfma_f32_16x16x32_bf16(ap, bv, oacc[n], 0, 0, 0);
        }
    }
#pragma unroll
    for (int n = 0; n < 2; ++n)
#pragma unroll
        for (int q = 0; q < 4; ++q) {
            int qi = q0 + 16 * wave + lg * 4 + q;
            out[((size_t)(b * T_ + qi)) * D_ + h * 32 + 16 * n + lr] = f2bf(oacc[n][q]);
        }
}

// ---------------- LN2d stage A: partial sums per (chunk, batch)
__global__ __launch_bounds__(256) void ln2d_partial(
    const float* __restrict__ x, float* __restrict__ part, int CT) {
    int b = blockIdx.y;
    int chunk = blockIdx.x;
    int n4 = CT / (4 * NC_);
    const float4* xb = (const float4*)(x + (size_t)b * CT) + (size_t)chunk * n4;
    float s = 0.f, ss = 0.f;
    for (int i = threadIdx.x; i < n4; i += 256) {
        float4 v = xb[i];
        s += v.x + v.y + v.z + v.w;
        ss += v.x * v.x + v.y * v.y + v.z * v.z + v.w * v.w;
    }
#pragma unroll
    for (int off = 32; off; off >>= 1) {
        s += __shfl_xor(s, off);
        ss += __shfl_xor(ss, off);
    }
    __shared__ float sh0[4], sh1[4];
    int wave = threadIdx.x >> 6;
    if ((threadIdx.x & 63) == 0) { sh0[wave] = s; sh1[wave] = ss; }
    __syncthreads();
    if (threadIdx.x == 0) {
        part[(size_t)(b * NC_ + chunk) * 2] = sh0[0] + sh0[1] + sh0[2] + sh0[3];
        part[(size_t)(b * NC_ + chunk) * 2 + 1] = sh1[0] + sh1[1] + sh1[2] + sh1[3];
    }
}

__device__ inline void ln2d_stats(const float* __restrict__ part, int b, int CT,
                                  float& mu, float& rstd) {
    float s = 0.f, ss = 0.f;
    const float2* p2 = (const float2*)(part + (size_t)b * NC_ * 2);
#pragma unroll
    for (int i = 0; i < NC_; ++i) { float2 v = p2[i]; s += v.x; ss += v.y; }
    mu = s / (float)CT;
    rstd = rsqrtf(ss / (float)CT - mu * mu + 1e-5f);
}

// ---------------- LN2d apply + ReLU (float4), final-reduce fused
__global__ __launch_bounds__(256) void ln2d_apply(
    const float* __restrict__ x, const float* __restrict__ w,
    const float* __restrict__ bb, const float* __restrict__ part,
    float* __restrict__ y, int CT) {
    int idx = blockIdx.x * 256 + threadIdx.x;
    int b = blockIdx.y;
    float mu, rstd;
    ln2d_stats(part, b, CT, mu, rstd);
    const float4* x4 = (const float4*)(x + (size_t)b * CT);
    const float4* w4 = (const float4*)w;
    const float4* b4 = (const float4*)bb;
    float4* y4 = (float4*)(y + (size_t)b * CT);
    float4 v = x4[idx], wv = w4[idx], bv = b4[idx];
    float4 r;
    r.x = fmaxf((v.x - mu) * rstd * wv.x + bv.x, 0.f);
    r.y = fmaxf((v.y - mu) * rstd * wv.y + bv.y, 0.f);
    r.z = fmaxf((v.z - mu) * rstd * wv.z + bv.z, 0.f);
    r.w = fmaxf((v.w - mu) * rstd * wv.w + bv.w, 0.f);
    y4[idx] = r;
}

// ---------------- LN2d apply + ReLU + transpose + pos add: [B,D,T] -> [B,T,D]
__global__ __launch_bounds__(256) void ln2d_apply_t(
    const float* __restrict__ x, const float* __restrict__ w,
    const float* __restrict__ bb, const float* __restrict__ part,
    const float* __restrict__ pos, float* __restrict__ h) {
    int t0 = blockIdx.x * 32;
    int d0 = blockIdx.y * 32;
    int b = blockIdx.z;
    float mu, rstd;
    ln2d_stats(part, b, D_ * T_, mu, rstd);
    __shared__ float xs[32][33];
    int tt = threadIdx.x & 31, dd = threadIdx.x >> 5;
#pragma unroll
    for (int p = 0; p < 4; ++p) {
        int d = d0 + dd + p * 8;
        size_t off = ((size_t)b * D_ + d) * T_ + t0 + tt;
        size_t woff = (size_t)d * T_ + t0 + tt;
        float v = (x[off] - mu) * rstd * w[woff] + bb[woff];
        xs[dd + p * 8][tt] = fmaxf(v, 0.f);
    }
    __syncthreads();
    int dd2 = threadIdx.x & 31, tt2 = threadIdx.x >> 5;
#pragma unroll
    for (int p = 0; p < 4; ++p) {
        int t = t0 + tt2 + p * 8;
        h[((size_t)(b * T_ + t)) * D_ + d0 + dd2] =
            xs[dd2][tt2 + p * 8] + pos[(size_t)t * D_ + d0 + dd2];
    }
}

extern "C" void kernel_launch(void* const* d_in, const int* in_sizes, int n_in,
                              void* d_out, int out_size, void* d_ws, size_t ws_size,
                              hipStream_t stream) {
    const float* x        = (const float*)d_in[0];
    const float* pre_w0   = (const float*)d_in[1];
    const float* pre_b0   = (const float*)d_in[2];
    const float* pre_lnw0 = (const float*)d_in[3];
    const float* pre_lnb0 = (const float*)d_in[4];
    const float* pre_w1   = (const float*)d_in[5];
    const float* pre_b1   = (const float*)d_in[6];
    const float* pre_lnw1 = (const float*)d_in[7];
    const float* pre_lnb1 = (const float*)d_in[8];
    const float* pos_emb  = (const float*)d_in[9];
    const float* Wqkv     = (const float*)d_in[10];
    const float* bqkv     = (const float*)d_in[11];
    const float* Wo       = (const float*)d_in[12];
    const float* bo       = (const float*)d_in[13];
    const float* ln1w     = (const float*)d_in[14];
    const float* ln1b     = (const float*)d_in[15];
    const float* W1       = (const float*)d_in[16];
    const float* b1       = (const float*)d_in[17];
    const float* W2       = (const float*)d_in[18];
    const float* b2       = (const float*)d_in[19];
    const float* ln2w     = (const float*)d_in[20];
    const float* ln2b     = (const float*)d_in[21];
    const float* post_w0  = (const float*)d_in[22];
    const float* post_b0  = (const float*)d_in[23];
    const float* post_lnw0= (const float*)d_in[24];
    const float* post_lnb0= (const float*)d_in[25];
    const float* post_w1  = (const float*)d_in[26];
    const float* post_b1  = (const float*)d_in[27];
    const float* post_lnw1= (const float*)d_in[28];
    const float* post_lnb1= (const float*)d_in[29];

    float* ws = (float*)d_ws;
    const size_t M1 = 1u << 20;              // 1M floats
    float* H     = ws;                       // [B,T,D] fp32          1M
    float* A0    = ws + 1 * M1;              // [B,D,T] fp32          1M (pre/post only)
    float* A1    = ws + 2 * M1;              // [B,D,T] fp32          1M (pre/post only)
    short* QKVb  = (short*)(ws + 1 * M1);    // [B,T,768] bf16        (transformer only; aliases A0/A1)
    short* Fb    = (short*)(ws + 4 * M1);    // [B,T,512] bf16
    short* ATTb  = (short*)(ws + 5 * M1);    // [B,T,256] bf16
    short* wbf   = (short*)(ws + 6 * M1);    // 2097152 shorts (transformer w)
    short* wqkv_bf = wbf;
    short* wo_bf   = wbf + 786432;
    short* w1_bf   = wbf + 1048576;
    short* w2_bf   = wbf + 1572864;
    short* cwbf  = wbf + 2097152;            // conv weights reordered
    short* cw_pre0  = cwbf;                  // [256][3*128]
    short* cw_pre1  = cwbf + 98304;          // [256][3*256]
    short* cw_post0 = cwbf + 294912;         // [256][3*256]
    short* cw_post1 = cwbf + 491520;         // [128][3*256]
    float* part  = ws + 8 * M1;

    const int M = B_ * T_;  // 4096

    // ---- one-time weight prep (bf16 + conv reorder)
    prep_w<<<2048, 256, 0, stream>>>(Wqkv, Wo, W1, W2,
                                     pre_w0, pre_w1, post_w0, post_w1, wbf);

    // ---- pre stage (fused im2col+GEMM, 16x64 tiles -> 1024 blocks)
    gemm_conv16<128, 0><<<dim3(D_ / 64, M / 16), 256, 0, stream>>>(
        x, cw_pre0, pre_b0, A0, D_);
    ln2d_partial<<<dim3(NC_, B_), 256, 0, stream>>>(A0, part, D_ * T_);
    ln2d_apply<<<dim3(D_ * T_ / 1024, B_), 256, 0, stream>>>(A0, pre_lnw0, pre_lnb0, part, A1, D_ * T_);

    gemm_conv16<256, 0><<<dim3(D_ / 64, M / 16), 256, 0, stream>>>(
        A1, cw_pre1, pre_b1, A0, D_);
    ln2d_partial<<<dim3(NC_, B_), 256, 0, stream>>>(A0, part, D_ * T_);
    ln2d_apply_t<<<dim3(T_ / 32, D_ / 32, B_), 256, 0, stream>>>(
        A0, pre_lnw1, pre_lnb1, part, pos_emb, H);

    // ---- transformer layers (5 dispatches each)
    for (int l = 0; l < L_; ++l) {
        gemm64w<0, 1><<<dim3(768 / 64, M / 64), 256, 0, stream>>>(
            H, wqkv_bf + (size_t)l * 196608, bqkv + (size_t)l * 768, QKVb, M, 768, D_);
        attn_mfma<<<dim3(T_ / 64, H_, B_), 256, 0, stream>>>(QKVb, ATTb);
        gemm_ln<256, 1><<<M / 16, 512, 0, stream>>>(
            ATTb, wo_bf + (size_t)l * 65536, bo + (size_t)l * D_, H,
            ln1w + (size_t)l * D_, ln1b + (size_t)l * D_);
        gemm64w<1, 1><<<dim3(DFF_ / 64, M / 64), 256, 0, stream>>>(
            H, w1_bf + (size_t)l * 131072, b1 + (size_t)l * DFF_, Fb, M, DFF_, D_);
        gemm_ln<512, 1><<<M / 16, 512, 0, stream>>>(
            Fb, w2_bf + (size_t)l * 131072, b2 + (size_t)l * D_, H,
            ln2w + (size_t)l * D_, ln2b + (size_t)l * D_);
    }

    // ---- post stage (conv0 reads H [B,T,D] directly via BTD staging)
    gemm_conv16<256, 1><<<dim3(D_ / 64, M / 16), 256, 0, stream>>>(
        H, cw_post0, post_b0, A1, D_);
    ln2d_partial<<<dim3(NC_, B_), 256, 0, stream>>>(A1, part, D_ * T_);
    ln2d_apply<<<dim3(D_ * T_ / 1024, B_), 256, 0, stream>>>(A1, post_lnw0, post_lnb0, part, A0, D_ * T_);

    gemm_conv16<256, 0><<<dim3(CIN_ / 64, M / 16), 256, 0, stream>>>(
        A0, cw_post1, post_b1, A1, CIN_);
    ln2d_partial<<<dim3(NC_, B_), 256, 0, stream>>>(A1, part, CIN_ * T_);
    ln2d_apply<<<dim3(CIN_ * T_ / 1024, B_), 256, 0, stream>>>(A1, post_lnw1, post_lnb1, part,
                                                               (float*)d_out, CIN_ * T_);
}

// Round 14
// 282.632 us; speedup vs baseline: 8.1635x; 1.0997x over previous
//
#include <hip/hip_runtime.h>
#include <hip/hip_bf16.h>

#define B_ 4
#define T_ 1024
#define D_ 256
#define H_ 8
#define WIN_ 64
#define CIN_ 128
#define DH_ 32
#define DFF_ 512
#define L_ 4
#define PSTR 152 // attn Ps/Vt LDS row stride (shorts)
#define FSTR 520 // ffn F-tile LDS row stride (shorts)

typedef __attribute__((ext_vector_type(4))) short s16x4;
typedef __attribute__((ext_vector_type(8))) short s16x8;
typedef __attribute__((ext_vector_type(4))) float f32x4;

__device__ inline short f2bf(float f) {
    __hip_bfloat16 h = __float2bfloat16(f);
    return *reinterpret_cast<short*>(&h);
}

// ---------------- one-time weight prep:
// [0, 2097152): transformer Wqkv|Wo|W1|W2 fp32->bf16 (row-major [N][K])
// [2097152, 2686976): conv weights reordered [O][k*I+i] = w[o][i*3+k], bf16
__global__ __launch_bounds__(256) void prep_w(
    const float* __restrict__ wqkv, const float* __restrict__ wo,
    const float* __restrict__ w1, const float* __restrict__ w2,
    const float* __restrict__ pw0, const float* __restrict__ pw1,
    const float* __restrict__ qw0, const float* __restrict__ qw1,
    short* __restrict__ dst) {
    const int N0 = 786432, N1 = 1048576, N2 = 1572864, NT = 2097152;
    const int NTOT = 2686976;
    for (int i = blockIdx.x * 256 + threadIdx.x; i < NTOT; i += gridDim.x * 256) {
        float v;
        if (i < NT) {
            if (i < N0) v = wqkv[i];
            else if (i < N1) v = wo[i - N0];
            else if (i < N2) v = w1[i - N1];
            else v = w2[i - N2];
        } else {
            int j = i - NT;
            const float* src;
            int I;
            if (j < 98304)       { src = pw0; I = 128; }
            else if (j < 294912) { src = pw1; I = 256; j -= 98304; }
            else if (j < 491520) { src = qw0; I = 256; j -= 294912; }
            else                 { src = qw1; I = 256; j -= 491520; }
            int o = j / (3 * I);
            int rem = j - o * 3 * I;
            int k = rem / I, ii = rem - k * I;
            v = src[(size_t)(o * I + ii) * 3 + k];
        }
        dst[i] = f2bf(v);
    }
}

// ---------------- fused im2col + conv-GEMM + LN2d-partial epilogue, 16x64 tile
// Wr layout [O][k*I+i]. BTD=0: input [B,I,T]; BTD=1: [B,T,I].
// Output Y[B][O][1024]. Grid (O/64, M/16). Per-block (sum,sumsq) -> part2[slot].
template <int I_, int BTD>
__global__ __launch_bounds__(256) void gemm_conv16(
    const float* __restrict__ x, const short* __restrict__ Wr,
    const float* __restrict__ bias, float* __restrict__ Y, int O,
    float* __restrict__ part2) {
    const int K = 3 * I_;
    __shared__ short Al[16 * 40];
    __shared__ short Wl[64 * 40];
    __shared__ float sh[8];
    int tid = threadIdx.x;
    int col0 = blockIdx.x * 64;
    int row0 = blockIdx.y * 16;
    int b = row0 >> 10, t0 = row0 & 1023;
    int wave = tid >> 6, lane = tid & 63;
    int lg = lane >> 4, lr = lane & 15;
    f32x4 acc = {0.f, 0.f, 0.f, 0.f};

    for (int k0 = 0; k0 < K; k0 += 32) {
        int k = k0 / I_;
        int i0 = k0 - k * I_;
#pragma unroll
        for (int p = 0; p < 2; ++p) {
            int e = p * 256 + tid;
            int rr, cc;
            float v;
            if (BTD) {
                rr = e >> 5; cc = e & 31;
                int tg = t0 + rr - 1 + k;
                v = (tg >= 0 && tg < T_) ? x[((size_t)(b * T_ + tg)) * I_ + i0 + cc] : 0.f;
            } else {
                cc = e >> 4; rr = e & 15;
                int tg = t0 + rr - 1 + k;
                v = (tg >= 0 && tg < T_) ? x[((size_t)(b * I_ + i0 + cc)) * T_ + tg] : 0.f;
            }
            Al[rr * 40 + cc] = f2bf(v);
        }
#pragma unroll
        for (int p = 0; p < 2; ++p) {
            int rr = (tid >> 3) + p * 32;
            int ccc = (tid & 7) * 4;
            *(s16x4*)&Wl[rr * 40 + ccc] =
                *(const s16x4*)&Wr[(size_t)(col0 + rr) * K + k0 + ccc];
        }
        __syncthreads();
        s16x8 af = *(const s16x8*)&Al[lr * 40 + lg * 8];
        s16x8 wf = *(const s16x8*)&Wl[(wave * 16 + lr) * 40 + lg * 8];
        acc = __builtin_amdgcn_mfma_f32_16x16x32_bf16(af, wf, acc, 0, 0, 0);
        __syncthreads();
    }

    int cg = col0 + wave * 16 + lr;
    float bv = bias[cg];
    float4 o;
    o.x = acc[0] + bv; o.y = acc[1] + bv; o.z = acc[2] + bv; o.w = acc[3] + bv;
    *(float4*)&Y[((size_t)(b * O + cg)) * 1024 + t0 + lg * 4] = o;

    // LN2d partial: block-level (sum, sumsq), deterministic slot write
    float s = o.x + o.y + o.z + o.w;
    float ss = o.x * o.x + o.y * o.y + o.z * o.z + o.w * o.w;
#pragma unroll
    for (int off = 32; off; off >>= 1) {
        s += __shfl_xor(s, off);
        ss += __shfl_xor(ss, off);
    }
    if (lane == 0) { sh[wave * 2] = s; sh[wave * 2 + 1] = ss; }
    __syncthreads();
    if (tid == 0) {
        float ts = sh[0] + sh[2] + sh[4] + sh[6];
        float tss = sh[1] + sh[3] + sh[5] + sh[7];
        int slot = b * (gridDim.x * 64) + blockIdx.x * 64 + (blockIdx.y & 63);
        part2[slot * 2] = ts;
        part2[slot * 2 + 1] = tss;
    }
}

// ---------------- bf16-weight MFMA GEMM (QKV): Y = A @ Wbf^T + bias, bf16 out
template <int RELU, int BF16OUT>
__global__ __launch_bounds__(256) void gemm64w(
    const float* __restrict__ A, const short* __restrict__ Wbf,
    const float* __restrict__ bias, void* __restrict__ Yv,
    int M, int N, int K) {
    __shared__ short Al[64 * 40];
    __shared__ short Wl[64 * 40];
    int tid = threadIdx.x;
    int row0 = blockIdx.y * 64, col0 = blockIdx.x * 64;
    int wave = tid >> 6, lane = tid & 63;
    int wr = wave >> 1, wc = wave & 1;
    int lg = lane >> 4, lr = lane & 15;
    f32x4 acc[2][2] = {};

    int srow = tid >> 3;
    int scol = (tid & 7) * 4;
    for (int k0 = 0; k0 < K; k0 += 32) {
#pragma unroll
        for (int p = 0; p < 2; ++p) {
            int rr = srow + p * 32;
            float4 va = *(const float4*)&A[(size_t)(row0 + rr) * K + k0 + scol];
            s16x4 sa;
            sa[0] = f2bf(va.x); sa[1] = f2bf(va.y); sa[2] = f2bf(va.z); sa[3] = f2bf(va.w);
            *(s16x4*)&Al[rr * 40 + scol] = sa;
            *(s16x4*)&Wl[rr * 40 + scol] =
                *(const s16x4*)&Wbf[(size_t)(col0 + rr) * K + k0 + scol];
        }
        __syncthreads();
        s16x8 af[2], wf[2];
#pragma unroll
        for (int i = 0; i < 2; ++i) {
            af[i] = *(const s16x8*)&Al[(wr * 32 + i * 16 + lr) * 40 + lg * 8];
            wf[i] = *(const s16x8*)&Wl[(wc * 32 + i * 16 + lr) * 40 + lg * 8];
        }
#pragma unroll
        for (int i = 0; i < 2; ++i)
#pragma unroll
            for (int j = 0; j < 2; ++j)
                acc[i][j] = __builtin_amdgcn_mfma_f32_16x16x32_bf16(af[i], wf[j], acc[i][j], 0, 0, 0);
        __syncthreads();
    }
#pragma unroll
    for (int i = 0; i < 2; ++i) {
        int rg = row0 + wr * 32 + i * 16 + lg * 4;
#pragma unroll
        for (int j = 0; j < 2; ++j) {
            int cg = col0 + wc * 32 + j * 16 + lr;
            float bv = bias[cg];
#pragma unroll
            for (int q = 0; q < 4; ++q) {
                float v = acc[i][j][q] + bv;
                if (RELU) v = fmaxf(v, 0.f);
                if (BF16OUT) ((short*)Yv)[(size_t)(rg + q) * N + cg] = f2bf(v);
                else ((float*)Yv)[(size_t)(rg + q) * N + cg] = v;
            }
        }
    }
}

// ---------------- fused GEMM(N=256) + bias + residual + row-LN (Wo path)
// H[r] = LN(H[r] + A[r] @ Wbf^T + bias), 16 rows/block, grid M/16, 512 threads.
template <int KK, int BF16A>
__global__ __launch_bounds__(512) void gemm_ln(
    const void* __restrict__ Av, const short* __restrict__ Wbf,
    const float* __restrict__ bias, float* __restrict__ H,
    const float* __restrict__ lnw, const float* __restrict__ lnb) {
    __shared__ short As[16 * 40];
    __shared__ short Ws[256 * 40];
    __shared__ float Gs[16][260];
    int tid = threadIdx.x;
    int wave = tid >> 6, lane = tid & 63;
    int lg = lane >> 4, lr = lane & 15;
    int m0 = blockIdx.x * 16;
    f32x4 acc[2] = {};

    for (int k0 = 0; k0 < KK; k0 += 32) {
        if (tid < 128) {
            int r = tid >> 3, c = (tid & 7) * 4;
            if (BF16A) {
                *(s16x4*)&As[r * 40 + c] =
                    *(const s16x4*)&((const short*)Av)[(size_t)(m0 + r) * KK + k0 + c];
            } else {
                float4 va = *(const float4*)&((const float*)Av)[(size_t)(m0 + r) * KK + k0 + c];
                s16x4 sa;
                sa[0] = f2bf(va.x); sa[1] = f2bf(va.y); sa[2] = f2bf(va.z); sa[3] = f2bf(va.w);
                *(s16x4*)&As[r * 40 + c] = sa;
            }
        }
#pragma unroll
        for (int u = 0; u < 2; ++u) {
            int task = tid + 512 * u;
            int r = task >> 2, c8 = (task & 3) * 8;
            *(s16x8*)&Ws[r * 40 + c8] = *(const s16x8*)&Wbf[(size_t)r * KK + k0 + c8];
        }
        __syncthreads();
        s16x8 af = *(const s16x8*)&As[lr * 40 + lg * 8];
#pragma unroll
        for (int j = 0; j < 2; ++j) {
            s16x8 wf = *(const s16x8*)&Ws[(wave * 32 + j * 16 + lr) * 40 + lg * 8];
            acc[j] = __builtin_amdgcn_mfma_f32_16x16x32_bf16(af, wf, acc[j], 0, 0, 0);
        }
        __syncthreads();
    }

#pragma unroll
    for (int j = 0; j < 2; ++j) {
        int col = wave * 32 + j * 16 + lr;
        float bv = bias[col];
#pragma unroll
        for (int q = 0; q < 4; ++q)
            Gs[lg * 4 + q][col] = acc[j][q] + bv;
    }
    __syncthreads();

    for (int rr = 0; rr < 2; ++rr) {
        int row = wave * 2 + rr;
        size_t base = (size_t)(m0 + row) * D_;
        float x[4];
        float s = 0.f;
#pragma unroll
        for (int i = 0; i < 4; ++i) {
            int idx = i * 64 + lane;
            x[i] = H[base + idx] + Gs[row][idx];
            s += x[i];
        }
#pragma unroll
        for (int off = 32; off; off >>= 1) s += __shfl_xor(s, off);
        float mu = s * (1.f / D_);
        float ss = 0.f;
#pragma unroll
        for (int i = 0; i < 4; ++i) { float d = x[i] - mu; ss += d * d; }
#pragma unroll
        for (int off = 32; off; off >>= 1) ss += __shfl_xor(ss, off);
        float rstd = rsqrtf(ss * (1.f / D_) + 1e-5f);
#pragma unroll
        for (int i = 0; i < 4; ++i) {
            int idx = i * 64 + lane;
            H[base + idx] = (x[i] - mu) * rstd * lnw[idx] + lnb[idx];
        }
    }
}

// ---------------- fused FFN: H = LN2(H + relu(H@W1^T+b1)@W2^T + b2)
// 16 rows/block, grid M/16, 512 threads. F-tile kept in LDS (bf16, same
// rounding point as the old Fb store -> bit-identical).
__global__ __launch_bounds__(512) void ffn_ln(
    const float* __restrict__ Hin, const short* __restrict__ W1bf,
    const float* __restrict__ b1, const short* __restrict__ W2bf,
    const float* __restrict__ b2, float* __restrict__ H,
    const float* __restrict__ lnw, const float* __restrict__ lnb) {
    __shared__ short As[16 * 40];
    __shared__ short Ws[512 * 40];
    __shared__ short Fs[16 * FSTR];
    __shared__ float Gs[16][260];
    int tid = threadIdx.x;
    int wave = tid >> 6, lane = tid & 63;
    int lg = lane >> 4, lr = lane & 15;
    int m0 = blockIdx.x * 16;

    // ---- phase 1: F = relu(Hin @ W1^T + b1), K=256, N=512
    f32x4 acc1[4] = {};
    for (int k0 = 0; k0 < 256; k0 += 32) {
        if (tid < 128) {
            int r = tid >> 3, c = (tid & 7) * 4;
            float4 va = *(const float4*)&Hin[(size_t)(m0 + r) * 256 + k0 + c];
            s16x4 sa;
            sa[0] = f2bf(va.x); sa[1] = f2bf(va.y); sa[2] = f2bf(va.z); sa[3] = f2bf(va.w);
            *(s16x4*)&As[r * 40 + c] = sa;
        }
#pragma unroll
        for (int u = 0; u < 4; ++u) {
            int task = tid + 512 * u;      // 2048 tasks: 512 rows x 4 chunks of 8
            int r = task >> 2, c8 = (task & 3) * 8;
            *(s16x8*)&Ws[r * 40 + c8] = *(const s16x8*)&W1bf[(size_t)r * 256 + k0 + c8];
        }
        __syncthreads();
        s16x8 af = *(const s16x8*)&As[lr * 40 + lg * 8];
#pragma unroll
        for (int j = 0; j < 4; ++j) {
            s16x8 wf = *(const s16x8*)&Ws[(wave * 64 + j * 16 + lr) * 40 + lg * 8];
            acc1[j] = __builtin_amdgcn_mfma_f32_16x16x32_bf16(af, wf, acc1[j], 0, 0, 0);
        }
        __syncthreads();
    }
#pragma unroll
    for (int j = 0; j < 4; ++j) {
        int col = wave * 64 + j * 16 + lr;
        float bv = b1[col];
#pragma unroll
        for (int q = 0; q < 4; ++q)
            Fs[(lg * 4 + q) * FSTR + col] = f2bf(fmaxf(acc1[j][q] + bv, 0.f));
    }
    __syncthreads();

    // ---- phase 2: G = F @ W2^T + b2, K=512, N=256; residual + LN
    f32x4 acc2[2] = {};
    for (int k0 = 0; k0 < 512; k0 += 32) {
#pragma unroll
        for (int u = 0; u < 2; ++u) {
            int task = tid + 512 * u;      // 1024 tasks: 256 rows x 4 chunks of 8
            int r = task >> 2, c8 = (task & 3) * 8;
            *(s16x8*)&Ws[r * 40 + c8] = *(const s16x8*)&W2bf[(size_t)r * 512 + k0 + c8];
        }
        __syncthreads();
        s16x8 af = *(const s16x8*)&Fs[lr * FSTR + k0 + lg * 8];
#pragma unroll
        for (int j = 0; j < 2; ++j) {
            s16x8 wf = *(const s16x8*)&Ws[(wave * 32 + j * 16 + lr) * 40 + lg * 8];
            acc2[j] = __builtin_amdgcn_mfma_f32_16x16x32_bf16(af, wf, acc2[j], 0, 0, 0);
        }
        __syncthreads();
    }
#pragma unroll
    for (int j = 0; j < 2; ++j) {
        int col = wave * 32 + j * 16 + lr;
        float bv = b2[col];
#pragma unroll
        for (int q = 0; q < 4; ++q)
            Gs[lg * 4 + q][col] = acc2[j][q] + bv;
    }
    __syncthreads();

    for (int rr = 0; rr < 2; ++rr) {
        int row = wave * 2 + rr;
        size_t base = (size_t)(m0 + row) * D_;
        float x[4];
        float s = 0.f;
#pragma unroll
        for (int i = 0; i < 4; ++i) {
            int idx = i * 64 + lane;
            x[i] = H[base + idx] + Gs[row][idx];
            s += x[i];
        }
#pragma unroll
        for (int off = 32; off; off >>= 1) s += __shfl_xor(s, off);
        float mu = s * (1.f / D_);
        float ss = 0.f;
#pragma unroll
        for (int i = 0; i < 4; ++i) { float d = x[i] - mu; ss += d * d; }
#pragma unroll
        for (int off = 32; off; off >>= 1) ss += __shfl_xor(ss, off);
        float rstd = rsqrtf(ss * (1.f / D_) + 1e-5f);
#pragma unroll
        for (int i = 0; i < 4; ++i) {
            int idx = i * 64 + lane;
            H[base + idx] = (x[i] - mu) * rstd * lnw[idx] + lnb[idx];
        }
    }
}

// ---------------- MFMA banded attention (bf16 in, bf16 out)
__global__ __launch_bounds__(256) void attn_mfma(
    const short* __restrict__ qkv, short* __restrict__ out) {
    int q0 = blockIdx.x * 64;
    int h = blockIdx.y, b = blockIdx.z;
    int tid = threadIdx.x;
    int wave = tid >> 6, lane = tid & 63;
    int lg = lane >> 4;
    int lr = lane & 15;
    const int j0 = q0 - 64;

    __shared__ short Qs[64][40];
    __shared__ short Ks[128][40];
    __shared__ short Vt[32][PSTR];
    __shared__ short Ps[64][PSTR];

#pragma unroll
    for (int u = 0; u < 2; ++u) {
        int task = tid + 256 * u;
        int r = task >> 3, c = (task & 7) * 4;
        *(s16x4*)&Qs[r][c] =
            *(const s16x4*)&qkv[((size_t)(b * T_ + q0 + r)) * 768 + h * 32 + c];
    }
#pragma unroll
    for (int u = 0; u < 4; ++u) {
        int task = tid + 256 * u;
        int r = task >> 3, c = (task & 7) * 4;
        int jg = j0 + r;
        s16x4 sa = {0, 0, 0, 0};
        if (jg >= 0)
            sa = *(const s16x4*)&qkv[((size_t)(b * T_ + jg)) * 768 + 256 + h * 32 + c];
        *(s16x4*)&Ks[r][c] = sa;
    }
#pragma unroll
    for (int u = 0; u < 4; ++u) {
        int task = tid + 256 * u;
        int r = task >> 3, c = (task & 7) * 4;
        int jg = j0 + r;
        s16x4 v4 = {0, 0, 0, 0};
        if (jg >= 0)
            v4 = *(const s16x4*)&qkv[((size_t)(b * T_ + jg)) * 768 + 512 + h * 32 + c];
        Vt[c + 0][r] = v4[0];
        Vt[c + 1][r] = v4[1];
        Vt[c + 2][r] = v4[2];
        Vt[c + 3][r] = v4[3];
    }
    __syncthreads();

    s16x8 aq = *(const s16x8*)&Qs[16 * wave + lr][lg * 8];
    f32x4 sacc[8];
#pragma unroll
    for (int j = 0; j < 8; ++j) {
        s16x8 bk = *(const s16x8*)&Ks[16 * j + lr][lg * 8];
        f32x4 z = {0.f, 0.f, 0.f, 0.f};
        sacc[j] = __builtin_amdgcn_mfma_f32_16x16x32_bf16(aq, bk, z, 0, 0, 0);
    }

    const float scale = 0.17677669529663687f;
#pragma unroll
    for (int j = 0; j < 8; ++j) {
        int jg = j0 + 16 * j + lr;
#pragma unroll
        for (int q = 0; q < 4; ++q) {
            int qi = q0 + 16 * wave + lg * 4 + q;
            bool ok = ((jg >= qi - WIN_) && (jg < qi) && (jg >= 0)) || (qi == 0 && jg == 0);
            sacc[j][q] = ok ? sacc[j][q] * scale : -1e30f;
        }
    }
#pragma unroll
    for (int q = 0; q < 4; ++q) {
        float m = sacc[0][q];
#pragma unroll
        for (int j = 1; j < 8; ++j) m = fmaxf(m, sacc[j][q]);
#pragma unroll
        for (int off = 1; off < 16; off <<= 1) m = fmaxf(m, __shfl_xor(m, off));
        float e[8], sum = 0.f;
#pragma unroll
        for (int j = 0; j < 8; ++j) { e[j] = __expf(sacc[j][q] - m); sum += e[j]; }
#pragma unroll
        for (int off = 1; off < 16; off <<= 1) sum += __shfl_xor(sum, off);
        float inv = 1.f / sum;
        int row = 16 * wave + lg * 4 + q;
#pragma unroll
        for (int j = 0; j < 8; ++j) Ps[row][16 * j + lr] = f2bf(e[j] * inv);
    }

    f32x4 oacc[2] = {};
#pragma unroll
    for (int kk = 0; kk < 4; ++kk) {
        s16x8 ap = *(const s16x8*)&Ps[16 * wave + lr][kk * 32 + lg * 8];
#pragma unroll
        for (int n = 0; n < 2; ++n) {
            s16x8 bv = *(const s16x8*)&Vt[16 * n + lr][kk * 32 + lg * 8];
            oacc[n] = __builtin_amdgcn_mfma_f32_16x16x32_bf16(ap, bv, oacc[n], 0, 0, 0);
        }
    }
#pragma unroll
    for (int n = 0; n < 2; ++n)
#pragma unroll
        for (int q = 0; q < 4; ++q) {
            int qi = q0 + 16 * wave + lg * 4 + q;
            out[((size_t)(b * T_ + qi)) * D_ + h * 32 + 16 * n + lr] = f2bf(oacc[n][q]);
        }
}

// ---------------- LN2d apply + ReLU (float4); stats reduced from part2 in-kernel
__global__ __launch_bounds__(256) void ln2d_apply(
    const float* __restrict__ x, const float* __restrict__ w,
    const float* __restrict__ bb, const float* __restrict__ part2,
    float* __restrict__ y, int CT, int npart) {
    int b = blockIdx.y;
    int tid = threadIdx.x;
    __shared__ float sstat[2];
    if (tid < 64) {
        float s = 0.f, ss = 0.f;
        const float2* p2 = (const float2*)part2 + (size_t)b * npart;
        for (int i = tid; i < npart; i += 64) { float2 v = p2[i]; s += v.x; ss += v.y; }
#pragma unroll
        for (int off = 32; off; off >>= 1) {
            s += __shfl_xor(s, off);
            ss += __shfl_xor(ss, off);
        }
        if (tid == 0) {
            float mu = s / (float)CT;
            sstat[0] = mu;
            sstat[1] = rsqrtf(ss / (float)CT - mu * mu + 1e-5f);
        }
    }
    __syncthreads();
    float mu = sstat[0], rstd = sstat[1];
    int idx = blockIdx.x * 256 + tid;
    const float4* x4 = (const float4*)(x + (size_t)b * CT);
    const float4* w4 = (const float4*)w;
    const float4* b4 = (const float4*)bb;
    float4* y4 = (float4*)(y + (size_t)b * CT);
    float4 v = x4[idx], wv = w4[idx], bv = b4[idx];
    float4 r;
    r.x = fmaxf((v.x - mu) * rstd * wv.x + bv.x, 0.f);
    r.y = fmaxf((v.y - mu) * rstd * wv.y + bv.y, 0.f);
    r.z = fmaxf((v.z - mu) * rstd * wv.z + bv.z, 0.f);
    r.w = fmaxf((v.w - mu) * rstd * wv.w + bv.w, 0.f);
    y4[idx] = r;
}

// ---------------- LN2d apply + ReLU + transpose + pos add: [B,D,T] -> [B,T,D]
__global__ __launch_bounds__(256) void ln2d_apply_t(
    const float* __restrict__ x, const float* __restrict__ w,
    const float* __restrict__ bb, const float* __restrict__ part2,
    const float* __restrict__ pos, float* __restrict__ h, int npart) {
    int t0 = blockIdx.x * 32;
    int d0 = blockIdx.y * 32;
    int b = blockIdx.z;
    int tid = threadIdx.x;
    __shared__ float sstat[2];
    if (tid < 64) {
        float s = 0.f, ss = 0.f;
        const float2* p2 = (const float2*)part2 + (size_t)b * npart;
        for (int i = tid; i < npart; i += 64) { float2 v = p2[i]; s += v.x; ss += v.y; }
#pragma unroll
        for (int off = 32; off; off >>= 1) {
            s += __shfl_xor(s, off);
            ss += __shfl_xor(ss, off);
        }
        if (tid == 0) {
            float mu = s / (float)(D_ * T_);
            sstat[0] = mu;
            sstat[1] = rsqrtf(ss / (float)(D_ * T_) - mu * mu + 1e-5f);
        }
    }
    __syncthreads();
    float mu = sstat[0], rstd = sstat[1];
    __shared__ float xs[32][33];
    int tt = tid & 31, dd = tid >> 5;
#pragma unroll
    for (int p = 0; p < 4; ++p) {
        int d = d0 + dd + p * 8;
        size_t off = ((size_t)b * D_ + d) * T_ + t0 + tt;
        size_t woff = (size_t)d * T_ + t0 + tt;
        float v = (x[off] - mu) * rstd * w[woff] + bb[woff];
        xs[dd + p * 8][tt] = fmaxf(v, 0.f);
    }
    __syncthreads();
    int dd2 = tid & 31, tt2 = tid >> 5;
#pragma unroll
    for (int p = 0; p < 4; ++p) {
        int t = t0 + tt2 + p * 8;
        h[((size_t)(b * T_ + t)) * D_ + d0 + dd2] =
            xs[dd2][tt2 + p * 8] + pos[(size_t)t * D_ + d0 + dd2];
    }
}

extern "C" void kernel_launch(void* const* d_in, const int* in_sizes, int n_in,
                              void* d_out, int out_size, void* d_ws, size_t ws_size,
                              hipStream_t stream) {
    const float* x        = (const float*)d_in[0];
    const float* pre_w0   = (const float*)d_in[1];
    const float* pre_b0   = (const float*)d_in[2];
    const float* pre_lnw0 = (const float*)d_in[3];
    const float* pre_lnb0 = (const float*)d_in[4];
    const float* pre_w1   = (const float*)d_in[5];
    const float* pre_b1   = (const float*)d_in[6];
    const float* pre_lnw1 = (const float*)d_in[7];
    const float* pre_lnb1 = (const float*)d_in[8];
    const float* pos_emb  = (const float*)d_in[9];
    const float* Wqkv     = (const float*)d_in[10];
    const float* bqkv     = (const float*)d_in[11];
    const float* Wo       = (const float*)d_in[12];
    const float* bo       = (const float*)d_in[13];
    const float* ln1w     = (const float*)d_in[14];
    const float* ln1b     = (const float*)d_in[15];
    const float* W1       = (const float*)d_in[16];
    const float* b1       = (const float*)d_in[17];
    const float* W2       = (const float*)d_in[18];
    const float* b2       = (const float*)d_in[19];
    const float* ln2w     = (const float*)d_in[20];
    const float* ln2b     = (const float*)d_in[21];
    const float* post_w0  = (const float*)d_in[22];
    const float* post_b0  = (const float*)d_in[23];
    const float* post_lnw0= (const float*)d_in[24];
    const float* post_lnb0= (const float*)d_in[25];
    const float* post_w1  = (const float*)d_in[26];
    const float* post_b1  = (const float*)d_in[27];
    const float* post_lnw1= (const float*)d_in[28];
    const float* post_lnb1= (const float*)d_in[29];

    float* ws = (float*)d_ws;
    const size_t M1 = 1u << 20;              // 1M floats
    float* H     = ws;                       // [B,T,D] fp32
    float* A0    = ws + 1 * M1;              // [B,D,T] fp32 (pre/post only)
    float* A1    = ws + 2 * M1;              // [B,D,T] fp32 (pre/post only)
    short* QKVb  = (short*)(ws + 1 * M1);    // [B,T,768] bf16 (aliases A0/A1)
    short* ATTb  = (short*)(ws + 5 * M1);    // [B,T,256] bf16
    short* wbf   = (short*)(ws + 6 * M1);    // transformer weights bf16
    short* wqkv_bf = wbf;
    short* wo_bf   = wbf + 786432;
    short* w1_bf   = wbf + 1048576;
    short* w2_bf   = wbf + 1572864;
    short* cwbf  = wbf + 2097152;            // conv weights reordered
    short* cw_pre0  = cwbf;                  // [256][3*128]
    short* cw_pre1  = cwbf + 98304;          // [256][3*256]
    short* cw_post0 = cwbf + 294912;         // [256][3*256]
    short* cw_post1 = cwbf + 491520;         // [128][3*256]
    float* part2 = ws + 8 * M1;              // up to 4*256*2 floats

    const int M = B_ * T_;  // 4096

    // ---- one-time weight prep
    prep_w<<<2048, 256, 0, stream>>>(Wqkv, Wo, W1, W2,
                                     pre_w0, pre_w1, post_w0, post_w1, wbf);

    // ---- pre stage (conv + fused partial -> apply)
    gemm_conv16<128, 0><<<dim3(D_ / 64, M / 16), 256, 0, stream>>>(
        x, cw_pre0, pre_b0, A0, D_, part2);
    ln2d_apply<<<dim3(D_ * T_ / 1024, B_), 256, 0, stream>>>(
        A0, pre_lnw0, pre_lnb0, part2, A1, D_ * T_, 256);
    gemm_conv16<256, 0><<<dim3(D_ / 64, M / 16), 256, 0, stream>>>(
        A1, cw_pre1, pre_b1, A0, D_, part2);
    ln2d_apply_t<<<dim3(T_ / 32, D_ / 32, B_), 256, 0, stream>>>(
        A0, pre_lnw1, pre_lnb1, part2, pos_emb, H, 256);

    // ---- transformer layers (4 dispatches each)
    for (int l = 0; l < L_; ++l) {
        gemm64w<0, 1><<<dim3(768 / 64, M / 64), 256, 0, stream>>>(
            H, wqkv_bf + (size_t)l * 196608, bqkv + (size_t)l * 768, QKVb, M, 768, D_);
        attn_mfma<<<dim3(T_ / 64, H_, B_), 256, 0, stream>>>(QKVb, ATTb);
        gemm_ln<256, 1><<<M / 16, 512, 0, stream>>>(
            ATTb, wo_bf + (size_t)l * 65536, bo + (size_t)l * D_, H,
            ln1w + (size_t)l * D_, ln1b + (size_t)l * D_);
        ffn_ln<<<M / 16, 512, 0, stream>>>(
            H, w1_bf + (size_t)l * 131072, b1 + (size_t)l * DFF_,
            w2_bf + (size_t)l * 131072, b2 + (size_t)l * D_, H,
            ln2w + (size_t)l * D_, ln2b + (size_t)l * D_);
    }

    // ---- post stage
    gemm_conv16<256, 1><<<dim3(D_ / 64, M / 16), 256, 0, stream>>>(
        H, cw_post0, post_b0, A1, D_, part2);
    ln2d_apply<<<dim3(D_ * T_ / 1024, B_), 256, 0, stream>>>(
        A1, post_lnw0, post_lnb0, part2, A0, D_ * T_, 256);
    gemm_conv16<256, 0><<<dim3(CIN_ / 64, M / 16), 256, 0, stream>>>(
        A0, cw_post1, post_b1, A1, CIN_, part2);
    ln2d_apply<<<dim3(CIN_ * T_ / 1024, B_), 256, 0, stream>>>(
        A1, post_lnw1, post_lnb1, part2, (float*)d_out, CIN_ * T_, 128);
}

// Round 15
// 273.154 us; speedup vs baseline: 8.4468x; 1.0347x over previous
//
#include <hip/hip_runtime.h>
#include <hip/hip_bf16.h>

#define B_ 4
#define T_ 1024
#define D_ 256
#define H_ 8
#define WIN_ 64
#define CIN_ 128
#define DH_ 32
#define DFF_ 512
#define L_ 4
#define PSTR 152 // attn Ps/Vt LDS row stride (shorts)
#define FSTR 520 // ffn F-tile LDS row stride (shorts)
#define HSTR 264 // h1 bf16 LDS row stride (shorts)

typedef __attribute__((ext_vector_type(4))) short s16x4;
typedef __attribute__((ext_vector_type(8))) short s16x8;
typedef __attribute__((ext_vector_type(4))) float f32x4;

__device__ inline short f2bf(float f) {
    __hip_bfloat16 h = __float2bfloat16(f);
    return *reinterpret_cast<short*>(&h);
}

// ---------------- one-time weight prep:
// [0, 2097152): transformer Wqkv|Wo|W1|W2 fp32->bf16 (row-major [N][K])
// [2097152, 2686976): conv weights reordered [O][k*I+i] = w[o][i*3+k], bf16
__global__ __launch_bounds__(256) void prep_w(
    const float* __restrict__ wqkv, const float* __restrict__ wo,
    const float* __restrict__ w1, const float* __restrict__ w2,
    const float* __restrict__ pw0, const float* __restrict__ pw1,
    const float* __restrict__ qw0, const float* __restrict__ qw1,
    short* __restrict__ dst) {
    const int N0 = 786432, N1 = 1048576, N2 = 1572864, NT = 2097152;
    const int NTOT = 2686976;
    for (int i = blockIdx.x * 256 + threadIdx.x; i < NTOT; i += gridDim.x * 256) {
        float v;
        if (i < NT) {
            if (i < N0) v = wqkv[i];
            else if (i < N1) v = wo[i - N0];
            else if (i < N2) v = w1[i - N1];
            else v = w2[i - N2];
        } else {
            int j = i - NT;
            const float* src;
            int I;
            if (j < 98304)       { src = pw0; I = 128; }
            else if (j < 294912) { src = pw1; I = 256; j -= 98304; }
            else if (j < 491520) { src = qw0; I = 256; j -= 294912; }
            else                 { src = qw1; I = 256; j -= 491520; }
            int o = j / (3 * I);
            int rem = j - o * 3 * I;
            int k = rem / I, ii = rem - k * I;
            v = src[(size_t)(o * I + ii) * 3 + k];
        }
        dst[i] = f2bf(v);
    }
}

// ---------------- fused im2col + conv-GEMM + LN2d-partial epilogue, 16x64 tile
template <int I_, int BTD>
__global__ __launch_bounds__(256) void gemm_conv16(
    const float* __restrict__ x, const short* __restrict__ Wr,
    const float* __restrict__ bias, float* __restrict__ Y, int O,
    float* __restrict__ part2) {
    const int K = 3 * I_;
    __shared__ short Al[16 * 40];
    __shared__ short Wl[64 * 40];
    __shared__ float sh[8];
    int tid = threadIdx.x;
    int col0 = blockIdx.x * 64;
    int row0 = blockIdx.y * 16;
    int b = row0 >> 10, t0 = row0 & 1023;
    int wave = tid >> 6, lane = tid & 63;
    int lg = lane >> 4, lr = lane & 15;
    f32x4 acc = {0.f, 0.f, 0.f, 0.f};

    for (int k0 = 0; k0 < K; k0 += 32) {
        int k = k0 / I_;
        int i0 = k0 - k * I_;
#pragma unroll
        for (int p = 0; p < 2; ++p) {
            int e = p * 256 + tid;
            int rr, cc;
            float v;
            if (BTD) {
                rr = e >> 5; cc = e & 31;
                int tg = t0 + rr - 1 + k;
                v = (tg >= 0 && tg < T_) ? x[((size_t)(b * T_ + tg)) * I_ + i0 + cc] : 0.f;
            } else {
                cc = e >> 4; rr = e & 15;
                int tg = t0 + rr - 1 + k;
                v = (tg >= 0 && tg < T_) ? x[((size_t)(b * I_ + i0 + cc)) * T_ + tg] : 0.f;
            }
            Al[rr * 40 + cc] = f2bf(v);
        }
#pragma unroll
        for (int p = 0; p < 2; ++p) {
            int rr = (tid >> 3) + p * 32;
            int ccc = (tid & 7) * 4;
            *(s16x4*)&Wl[rr * 40 + ccc] =
                *(const s16x4*)&Wr[(size_t)(col0 + rr) * K + k0 + ccc];
        }
        __syncthreads();
        s16x8 af = *(const s16x8*)&Al[lr * 40 + lg * 8];
        s16x8 wf = *(const s16x8*)&Wl[(wave * 16 + lr) * 40 + lg * 8];
        acc = __builtin_amdgcn_mfma_f32_16x16x32_bf16(af, wf, acc, 0, 0, 0);
        __syncthreads();
    }

    int cg = col0 + wave * 16 + lr;
    float bv = bias[cg];
    float4 o;
    o.x = acc[0] + bv; o.y = acc[1] + bv; o.z = acc[2] + bv; o.w = acc[3] + bv;
    *(float4*)&Y[((size_t)(b * O + cg)) * 1024 + t0 + lg * 4] = o;

    float s = o.x + o.y + o.z + o.w;
    float ss = o.x * o.x + o.y * o.y + o.z * o.z + o.w * o.w;
#pragma unroll
    for (int off = 32; off; off >>= 1) {
        s += __shfl_xor(s, off);
        ss += __shfl_xor(ss, off);
    }
    if (lane == 0) { sh[wave * 2] = s; sh[wave * 2 + 1] = ss; }
    __syncthreads();
    if (tid == 0) {
        float ts = sh[0] + sh[2] + sh[4] + sh[6];
        float tss = sh[1] + sh[3] + sh[5] + sh[7];
        int slot = b * (gridDim.x * 64) + blockIdx.x * 64 + (blockIdx.y & 63);
        part2[slot * 2] = ts;
        part2[slot * 2 + 1] = tss;
    }
}

// ---------------- bf16-weight MFMA GEMM (QKV): Y = A @ Wbf^T + bias, bf16 out
template <int RELU, int BF16OUT>
__global__ __launch_bounds__(256) void gemm64w(
    const float* __restrict__ A, const short* __restrict__ Wbf,
    const float* __restrict__ bias, void* __restrict__ Yv,
    int M, int N, int K) {
    __shared__ short Al[64 * 40];
    __shared__ short Wl[64 * 40];
    int tid = threadIdx.x;
    int row0 = blockIdx.y * 64, col0 = blockIdx.x * 64;
    int wave = tid >> 6, lane = tid & 63;
    int wr = wave >> 1, wc = wave & 1;
    int lg = lane >> 4, lr = lane & 15;
    f32x4 acc[2][2] = {};

    int srow = tid >> 3;
    int scol = (tid & 7) * 4;
    for (int k0 = 0; k0 < K; k0 += 32) {
#pragma unroll
        for (int p = 0; p < 2; ++p) {
            int rr = srow + p * 32;
            float4 va = *(const float4*)&A[(size_t)(row0 + rr) * K + k0 + scol];
            s16x4 sa;
            sa[0] = f2bf(va.x); sa[1] = f2bf(va.y); sa[2] = f2bf(va.z); sa[3] = f2bf(va.w);
            *(s16x4*)&Al[rr * 40 + scol] = sa;
            *(s16x4*)&Wl[rr * 40 + scol] =
                *(const s16x4*)&Wbf[(size_t)(col0 + rr) * K + k0 + scol];
        }
        __syncthreads();
        s16x8 af[2], wf[2];
#pragma unroll
        for (int i = 0; i < 2; ++i) {
            af[i] = *(const s16x8*)&Al[(wr * 32 + i * 16 + lr) * 40 + lg * 8];
            wf[i] = *(const s16x8*)&Wl[(wc * 32 + i * 16 + lr) * 40 + lg * 8];
        }
#pragma unroll
        for (int i = 0; i < 2; ++i)
#pragma unroll
            for (int j = 0; j < 2; ++j)
                acc[i][j] = __builtin_amdgcn_mfma_f32_16x16x32_bf16(af[i], wf[j], acc[i][j], 0, 0, 0);
        __syncthreads();
    }
#pragma unroll
    for (int i = 0; i < 2; ++i) {
        int rg = row0 + wr * 32 + i * 16 + lg * 4;
#pragma unroll
        for (int j = 0; j < 2; ++j) {
            int cg = col0 + wc * 32 + j * 16 + lr;
            float bv = bias[cg];
#pragma unroll
            for (int q = 0; q < 4; ++q) {
                float v = acc[i][j][q] + bv;
                if (RELU) v = fmaxf(v, 0.f);
                if (BF16OUT) ((short*)Yv)[(size_t)(rg + q) * N + cg] = f2bf(v);
                else ((float*)Yv)[(size_t)(rg + q) * N + cg] = v;
            }
        }
    }
}

// ---------------- fused layer tail: Wo-GEMM + LN1 + FFN1 + FFN2 + LN2
// H[r] = LN2( h1 + relu(h1@W1^T+b1)@W2^T + b2 ),  h1 = LN1(H[r] + ATT@Wo^T + bo)
// 16 rows/block, grid M/16, 512 threads. Bit-identical to the former
// gemm_ln + ffn_ln pair (same rounding points).
__global__ __launch_bounds__(512) void layer_tail(
    const short* __restrict__ ATTb, const short* __restrict__ Wobf,
    const float* __restrict__ bo, const short* __restrict__ W1bf,
    const float* __restrict__ b1, const short* __restrict__ W2bf,
    const float* __restrict__ b2, float* __restrict__ H,
    const float* __restrict__ ln1w, const float* __restrict__ ln1b,
    const float* __restrict__ ln2w, const float* __restrict__ ln2b) {
    __shared__ short As[16 * 40];
    __shared__ short Ws[256 * 40];     // 20 KB weight stage (shared by all phases)
    __shared__ float Gf[16][260];      // G1, then h1 fp32
    __shared__ short h1b[16 * HSTR];   // h1 bf16
    __shared__ short Fs[16 * FSTR];    // FFN1 output bf16
    __shared__ float G2[16][260];
    int tid = threadIdx.x;
    int wave = tid >> 6, lane = tid & 63;
    int lg = lane >> 4, lr = lane & 15;
    int m0 = blockIdx.x * 16;

    // ---- phase A: G1 = ATT @ Wo^T + bo   (K=256, N=256)
    f32x4 accA[2] = {};
    for (int k0 = 0; k0 < 256; k0 += 32) {
        if (tid < 128) {
            int r = tid >> 3, c = (tid & 7) * 4;
            *(s16x4*)&As[r * 40 + c] =
                *(const s16x4*)&ATTb[(size_t)(m0 + r) * 256 + k0 + c];
        }
#pragma unroll
        for (int u = 0; u < 2; ++u) {
            int task = tid + 512 * u;
            int r = task >> 2, c8 = (task & 3) * 8;
            *(s16x8*)&Ws[r * 40 + c8] = *(const s16x8*)&Wobf[(size_t)r * 256 + k0 + c8];
        }
        __syncthreads();
        s16x8 af = *(const s16x8*)&As[lr * 40 + lg * 8];
#pragma unroll
        for (int j = 0; j < 2; ++j) {
            s16x8 wf = *(const s16x8*)&Ws[(wave * 32 + j * 16 + lr) * 40 + lg * 8];
            accA[j] = __builtin_amdgcn_mfma_f32_16x16x32_bf16(af, wf, accA[j], 0, 0, 0);
        }
        __syncthreads();
    }
#pragma unroll
    for (int j = 0; j < 2; ++j) {
        int col = wave * 32 + j * 16 + lr;
        float bv = bo[col];
#pragma unroll
        for (int q = 0; q < 4; ++q)
            Gf[lg * 4 + q][col] = accA[j][q] + bv;
    }
    __syncthreads();

    // ---- LN1: h1 = LN(H + G1); keep fp32 (Gf, in-place) and bf16 (h1b)
    for (int rr = 0; rr < 2; ++rr) {
        int row = wave * 2 + rr;
        size_t base = (size_t)(m0 + row) * D_;
        float x[4];
        float s = 0.f;
#pragma unroll
        for (int i = 0; i < 4; ++i) {
            int idx = i * 64 + lane;
            x[i] = H[base + idx] + Gf[row][idx];
            s += x[i];
        }
#pragma unroll
        for (int off = 32; off; off >>= 1) s += __shfl_xor(s, off);
        float mu = s * (1.f / D_);
        float ss = 0.f;
#pragma unroll
        for (int i = 0; i < 4; ++i) { float d = x[i] - mu; ss += d * d; }
#pragma unroll
        for (int off = 32; off; off >>= 1) ss += __shfl_xor(ss, off);
        float rstd = rsqrtf(ss * (1.f / D_) + 1e-5f);
#pragma unroll
        for (int i = 0; i < 4; ++i) {
            int idx = i * 64 + lane;
            float h1v = (x[i] - mu) * rstd * ln1w[idx] + ln1b[idx];
            Gf[row][idx] = h1v;
            h1b[row * HSTR + idx] = f2bf(h1v);
        }
    }
    __syncthreads();

    // ---- phase B: F = relu(h1 @ W1^T + b1)  (K=256, N=512 in two 256-col halves)
    for (int nh = 0; nh < 2; ++nh) {
        f32x4 acc1[2] = {};
        for (int k0 = 0; k0 < 256; k0 += 32) {
#pragma unroll
            for (int u = 0; u < 2; ++u) {
                int task = tid + 512 * u;
                int r = task >> 2, c8 = (task & 3) * 8;
                *(s16x8*)&Ws[r * 40 + c8] =
                    *(const s16x8*)&W1bf[(size_t)(nh * 256 + r) * 256 + k0 + c8];
            }
            __syncthreads();
            s16x8 af = *(const s16x8*)&h1b[lr * HSTR + k0 + lg * 8];
#pragma unroll
            for (int j = 0; j < 2; ++j) {
                s16x8 wf = *(const s16x8*)&Ws[(wave * 32 + j * 16 + lr) * 40 + lg * 8];
                acc1[j] = __builtin_amdgcn_mfma_f32_16x16x32_bf16(af, wf, acc1[j], 0, 0, 0);
            }
            __syncthreads();
        }
#pragma unroll
        for (int j = 0; j < 2; ++j) {
            int col = nh * 256 + wave * 32 + j * 16 + lr;
            float bv = b1[col];
#pragma unroll
            for (int q = 0; q < 4; ++q)
                Fs[(lg * 4 + q) * FSTR + col] = f2bf(fmaxf(acc1[j][q] + bv, 0.f));
        }
    }
    __syncthreads();

    // ---- phase C: G2 = F @ W2^T + b2  (K=512, N=256)
    f32x4 acc2[2] = {};
    for (int k0 = 0; k0 < 512; k0 += 32) {
#pragma unroll
        for (int u = 0; u < 2; ++u) {
            int task = tid + 512 * u;
            int r = task >> 2, c8 = (task & 3) * 8;
            *(s16x8*)&Ws[r * 40 + c8] = *(const s16x8*)&W2bf[(size_t)r * 512 + k0 + c8];
        }
        __syncthreads();
        s16x8 af = *(const s16x8*)&Fs[lr * FSTR + k0 + lg * 8];
#pragma unroll
        for (int j = 0; j < 2; ++j) {
            s16x8 wf = *(const s16x8*)&Ws[(wave * 32 + j * 16 + lr) * 40 + lg * 8];
            acc2[j] = __builtin_amdgcn_mfma_f32_16x16x32_bf16(af, wf, acc2[j], 0, 0, 0);
        }
        __syncthreads();
    }
#pragma unroll
    for (int j = 0; j < 2; ++j) {
        int col = wave * 32 + j * 16 + lr;
        float bv = b2[col];
#pragma unroll
        for (int q = 0; q < 4; ++q)
            G2[lg * 4 + q][col] = acc2[j][q] + bv;
    }
    __syncthreads();

    // ---- LN2: H = LN(h1 + G2)
    for (int rr = 0; rr < 2; ++rr) {
        int row = wave * 2 + rr;
        size_t base = (size_t)(m0 + row) * D_;
        float x[4];
        float s = 0.f;
#pragma unroll
        for (int i = 0; i < 4; ++i) {
            int idx = i * 64 + lane;
            x[i] = Gf[row][idx] + G2[row][idx];
            s += x[i];
        }
#pragma unroll
        for (int off = 32; off; off >>= 1) s += __shfl_xor(s, off);
        float mu = s * (1.f / D_);
        float ss = 0.f;
#pragma unroll
        for (int i = 0; i < 4; ++i) { float d = x[i] - mu; ss += d * d; }
#pragma unroll
        for (int off = 32; off; off >>= 1) ss += __shfl_xor(ss, off);
        float rstd = rsqrtf(ss * (1.f / D_) + 1e-5f);
#pragma unroll
        for (int i = 0; i < 4; ++i) {
            int idx = i * 64 + lane;
            H[base + idx] = (x[i] - mu) * rstd * ln2w[idx] + ln2b[idx];
        }
    }
}

// ---------------- MFMA banded attention (bf16 in, bf16 out)
__global__ __launch_bounds__(256) void attn_mfma(
    const short* __restrict__ qkv, short* __restrict__ out) {
    int q0 = blockIdx.x * 64;
    int h = blockIdx.y, b = blockIdx.z;
    int tid = threadIdx.x;
    int wave = tid >> 6, lane = tid & 63;
    int lg = lane >> 4;
    int lr = lane & 15;
    const int j0 = q0 - 64;

    __shared__ short Qs[64][40];
    __shared__ short Ks[128][40];
    __shared__ short Vt[32][PSTR];
    __shared__ short Ps[64][PSTR];

#pragma unroll
    for (int u = 0; u < 2; ++u) {
        int task = tid + 256 * u;
        int r = task >> 3, c = (task & 7) * 4;
        *(s16x4*)&Qs[r][c] =
            *(const s16x4*)&qkv[((size_t)(b * T_ + q0 + r)) * 768 + h * 32 + c];
    }
#pragma unroll
    for (int u = 0; u < 4; ++u) {
        int task = tid + 256 * u;
        int r = task >> 3, c = (task & 7) * 4;
        int jg = j0 + r;
        s16x4 sa = {0, 0, 0, 0};
        if (jg >= 0)
            sa = *(const s16x4*)&qkv[((size_t)(b * T_ + jg)) * 768 + 256 + h * 32 + c];
        *(s16x4*)&Ks[r][c] = sa;
    }
#pragma unroll
    for (int u = 0; u < 4; ++u) {
        int task = tid + 256 * u;
        int r = task >> 3, c = (task & 7) * 4;
        int jg = j0 + r;
        s16x4 v4 = {0, 0, 0, 0};
        if (jg >= 0)
            v4 = *(const s16x4*)&qkv[((size_t)(b * T_ + jg)) * 768 + 512 + h * 32 + c];
        Vt[c + 0][r] = v4[0];
        Vt[c + 1][r] = v4[1];
        Vt[c + 2][r] = v4[2];
        Vt[c + 3][r] = v4[3];
    }
    __syncthreads();

    s16x8 aq = *(const s16x8*)&Qs[16 * wave + lr][lg * 8];
    f32x4 sacc[8];
#pragma unroll
    for (int j = 0; j < 8; ++j) {
        s16x8 bk = *(const s16x8*)&Ks[16 * j + lr][lg * 8];
        f32x4 z = {0.f, 0.f, 0.f, 0.f};
        sacc[j] = __builtin_amdgcn_mfma_f32_16x16x32_bf16(aq, bk, z, 0, 0, 0);
    }

    const float scale = 0.17677669529663687f;
#pragma unroll
    for (int j = 0; j < 8; ++j) {
        int jg = j0 + 16 * j + lr;
#pragma unroll
        for (int q = 0; q < 4; ++q) {
            int qi = q0 + 16 * wave + lg * 4 + q;
            bool ok = ((jg >= qi - WIN_) && (jg < qi) && (jg >= 0)) || (qi == 0 && jg == 0);
            sacc[j][q] = ok ? sacc[j][q] * scale : -1e30f;
        }
    }
#pragma unroll
    for (int q = 0; q < 4; ++q) {
        float m = sacc[0][q];
#pragma unroll
        for (int j = 1; j < 8; ++j) m = fmaxf(m, sacc[j][q]);
#pragma unroll
        for (int off = 1; off < 16; off <<= 1) m = fmaxf(m, __shfl_xor(m, off));
        float e[8], sum = 0.f;
#pragma unroll
        for (int j = 0; j < 8; ++j) { e[j] = __expf(sacc[j][q] - m); sum += e[j]; }
#pragma unroll
        for (int off = 1; off < 16; off <<= 1) sum += __shfl_xor(sum, off);
        float inv = 1.f / sum;
        int row = 16 * wave + lg * 4 + q;
#pragma unroll
        for (int j = 0; j < 8; ++j) Ps[row][16 * j + lr] = f2bf(e[j] * inv);
    }

    f32x4 oacc[2] = {};
#pragma unroll
    for (int kk = 0; kk < 4; ++kk) {
        s16x8 ap = *(const s16x8*)&Ps[16 * wave + lr][kk * 32 + lg * 8];
#pragma unroll
        for (int n = 0; n < 2; ++n) {
            s16x8 bv = *(const s16x8*)&Vt[16 * n + lr][kk * 32 + lg * 8];
            oacc[n] = __builtin_amdgcn_mfma_f32_16x16x32_bf16(ap, bv, oacc[n], 0, 0, 0);
        }
    }
#pragma unroll
    for (int n = 0; n < 2; ++n)
#pragma unroll
        for (int q = 0; q < 4; ++q) {
            int qi = q0 + 16 * wave + lg * 4 + q;
            out[((size_t)(b * T_ + qi)) * D_ + h * 32 + 16 * n + lr] = f2bf(oacc[n][q]);
        }
}

// ---------------- LN2d apply + ReLU (float4); stats reduced from part2 in-kernel
__global__ __launch_bounds__(256) void ln2d_apply(
    const float* __restrict__ x, const float* __restrict__ w,
    const float* __restrict__ bb, const float* __restrict__ part2,
    float* __restrict__ y, int CT, int npart) {
    int b = blockIdx.y;
    int tid = threadIdx.x;
    __shared__ float sstat[2];
    if (tid < 64) {
        float s = 0.f, ss = 0.f;
        const float2* p2 = (const float2*)part2 + (size_t)b * npart;
        for (int i = tid; i < npart; i += 64) { float2 v = p2[i]; s += v.x; ss += v.y; }
#pragma unroll
        for (int off = 32; off; off >>= 1) {
            s += __shfl_xor(s, off);
            ss += __shfl_xor(ss, off);
        }
        if (tid == 0) {
            float mu = s / (float)CT;
            sstat[0] = mu;
            sstat[1] = rsqrtf(ss / (float)CT - mu * mu + 1e-5f);
        }
    }
    __syncthreads();
    float mu = sstat[0], rstd = sstat[1];
    int idx = blockIdx.x * 256 + tid;
    const float4* x4 = (const float4*)(x + (size_t)b * CT);
    const float4* w4 = (const float4*)w;
    const float4* b4 = (const float4*)bb;
    float4* y4 = (float4*)(y + (size_t)b * CT);
    float4 v = x4[idx], wv = w4[idx], bv = b4[idx];
    float4 r;
    r.x = fmaxf((v.x - mu) * rstd * wv.x + bv.x, 0.f);
    r.y = fmaxf((v.y - mu) * rstd * wv.y + bv.y, 0.f);
    r.z = fmaxf((v.z - mu) * rstd * wv.z + bv.z, 0.f);
    r.w = fmaxf((v.w - mu) * rstd * wv.w + bv.w, 0.f);
    y4[idx] = r;
}

// ---------------- LN2d apply + ReLU + transpose + pos add: [B,D,T] -> [B,T,D]
__global__ __launch_bounds__(256) void ln2d_apply_t(
    const float* __restrict__ x, const float* __restrict__ w,
    const float* __restrict__ bb, const float* __restrict__ part2,
    const float* __restrict__ pos, float* __restrict__ h, int npart) {
    int t0 = blockIdx.x * 32;
    int d0 = blockIdx.y * 32;
    int b = blockIdx.z;
    int tid = threadIdx.x;
    __shared__ float sstat[2];
    if (tid < 64) {
        float s = 0.f, ss = 0.f;
        const float2* p2 = (const float2*)part2 + (size_t)b * npart;
        for (int i = tid; i < npart; i += 64) { float2 v = p2[i]; s += v.x; ss += v.y; }
#pragma unroll
        for (int off = 32; off; off >>= 1) {
            s += __shfl_xor(s, off);
            ss += __shfl_xor(ss, off);
        }
        if (tid == 0) {
            float mu = s / (float)(D_ * T_);
            sstat[0] = mu;
            sstat[1] = rsqrtf(ss / (float)(D_ * T_) - mu * mu + 1e-5f);
        }
    }
    __syncthreads();
    float mu = sstat[0], rstd = sstat[1];
    __shared__ float xs[32][33];
    int tt = tid & 31, dd = tid >> 5;
#pragma unroll
    for (int p = 0; p < 4; ++p) {
        int d = d0 + dd + p * 8;
        size_t off = ((size_t)b * D_ + d) * T_ + t0 + tt;
        size_t woff = (size_t)d * T_ + t0 + tt;
        float v = (x[off] - mu) * rstd * w[woff] + bb[woff];
        xs[dd + p * 8][tt] = fmaxf(v, 0.f);
    }
    __syncthreads();
    int dd2 = tid & 31, tt2 = tid >> 5;
#pragma unroll
    for (int p = 0; p < 4; ++p) {
        int t = t0 + tt2 + p * 8;
        h[((size_t)(b * T_ + t)) * D_ + d0 + dd2] =
            xs[dd2][tt2 + p * 8] + pos[(size_t)t * D_ + d0 + dd2];
    }
}

extern "C" void kernel_launch(void* const* d_in, const int* in_sizes, int n_in,
                              void* d_out, int out_size, void* d_ws, size_t ws_size,
                              hipStream_t stream) {
    const float* x        = (const float*)d_in[0];
    const float* pre_w0   = (const float*)d_in[1];
    const float* pre_b0   = (const float*)d_in[2];
    const float* pre_lnw0 = (const float*)d_in[3];
    const float* pre_lnb0 = (const float*)d_in[4];
    const float* pre_w1   = (const float*)d_in[5];
    const float* pre_b1   = (const float*)d_in[6];
    const float* pre_lnw1 = (const float*)d_in[7];
    const float* pre_lnb1 = (const float*)d_in[8];
    const float* pos_emb  = (const float*)d_in[9];
    const float* Wqkv     = (const float*)d_in[10];
    const float* bqkv     = (const float*)d_in[11];
    const float* Wo       = (const float*)d_in[12];
    const float* bo       = (const float*)d_in[13];
    const float* ln1w     = (const float*)d_in[14];
    const float* ln1b     = (const float*)d_in[15];
    const float* W1       = (const float*)d_in[16];
    const float* b1       = (const float*)d_in[17];
    const float* W2       = (const float*)d_in[18];
    const float* b2       = (const float*)d_in[19];
    const float* ln2w     = (const float*)d_in[20];
    const float* ln2b     = (const float*)d_in[21];
    const float* post_w0  = (const float*)d_in[22];
    const float* post_b0  = (const float*)d_in[23];
    const float* post_lnw0= (const float*)d_in[24];
    const float* post_lnb0= (const float*)d_in[25];
    const float* post_w1  = (const float*)d_in[26];
    const float* post_b1  = (const float*)d_in[27];
    const float* post_lnw1= (const float*)d_in[28];
    const float* post_lnb1= (const float*)d_in[29];

    float* ws = (float*)d_ws;
    const size_t M1 = 1u << 20;              // 1M floats
    float* H     = ws;                       // [B,T,D] fp32
    float* A0    = ws + 1 * M1;              // [B,D,T] fp32 (pre/post only)
    float* A1    = ws + 2 * M1;              // [B,D,T] fp32 (pre/post only)
    short* QKVb  = (short*)(ws + 1 * M1);    // [B,T,768] bf16 (aliases A0/A1)
    short* ATTb  = (short*)(ws + 5 * M1);    // [B,T,256] bf16
    short* wbf   = (short*)(ws + 6 * M1);    // transformer weights bf16
    short* wqkv_bf = wbf;
    short* wo_bf   = wbf + 786432;
    short* w1_bf   = wbf + 1048576;
    short* w2_bf   = wbf + 1572864;
    short* cwbf  = wbf + 2097152;            // conv weights reordered
    short* cw_pre0  = cwbf;                  // [256][3*128]
    short* cw_pre1  = cwbf + 98304;          // [256][3*256]
    short* cw_post0 = cwbf + 294912;         // [256][3*256]
    short* cw_post1 = cwbf + 491520;         // [128][3*256]
    float* part2 = ws + 8 * M1;              // up to 4*256*2 floats

    const int M = B_ * T_;  // 4096

    // ---- one-time weight prep
    prep_w<<<2048, 256, 0, stream>>>(Wqkv, Wo, W1, W2,
                                     pre_w0, pre_w1, post_w0, post_w1, wbf);

    // ---- pre stage (conv + fused partial -> apply)
    gemm_conv16<128, 0><<<dim3(D_ / 64, M / 16), 256, 0, stream>>>(
        x, cw_pre0, pre_b0, A0, D_, part2);
    ln2d_apply<<<dim3(D_ * T_ / 1024, B_), 256, 0, stream>>>(
        A0, pre_lnw0, pre_lnb0, part2, A1, D_ * T_, 256);
    gemm_conv16<256, 0><<<dim3(D_ / 64, M / 16), 256, 0, stream>>>(
        A1, cw_pre1, pre_b1, A0, D_, part2);
    ln2d_apply_t<<<dim3(T_ / 32, D_ / 32, B_), 256, 0, stream>>>(
        A0, pre_lnw1, pre_lnb1, part2, pos_emb, H, 256);

    // ---- transformer layers (3 dispatches each)
    for (int l = 0; l < L_; ++l) {
        gemm64w<0, 1><<<dim3(768 / 64, M / 64), 256, 0, stream>>>(
            H, wqkv_bf + (size_t)l * 196608, bqkv + (size_t)l * 768, QKVb, M, 768, D_);
        attn_mfma<<<dim3(T_ / 64, H_, B_), 256, 0, stream>>>(QKVb, ATTb);
        layer_tail<<<M / 16, 512, 0, stream>>>(
            ATTb, wo_bf + (size_t)l * 65536, bo + (size_t)l * D_,
            w1_bf + (size_t)l * 131072, b1 + (size_t)l * DFF_,
            w2_bf + (size_t)l * 131072, b2 + (size_t)l * D_, H,
            ln1w + (size_t)l * D_, ln1b + (size_t)l * D_,
            ln2w + (size_t)l * D_, ln2b + (size_t)l * D_);
    }

    // ---- post stage
    gemm_conv16<256, 1><<<dim3(D_ / 64, M / 16), 256, 0, stream>>>(
        H, cw_post0, post_b0, A1, D_, part2);
    ln2d_apply<<<dim3(D_ * T_ / 1024, B_), 256, 0, stream>>>(
        A1, post_lnw0, post_lnb0, part2, A0, D_ * T_, 256);
    gemm_conv16<256, 0><<<dim3(CIN_ / 64, M / 16), 256, 0, stream>>>(
        A0, cw_post1, post_b1, A1, CIN_, part2);
    ln2d_apply<<<dim3(CIN_ * T_ / 1024, B_), 256, 0, stream>>>(
        A1, post_lnw1, post_lnb1, part2, (float*)d_out, CIN_ * T_, 128);
}

// Round 16
// 249.069 us; speedup vs baseline: 9.2636x; 1.0967x over previous
//
#include <hip/hip_runtime.h>
#include <hip/hip_bf16.h>

#define B_ 4
#define T_ 1024
#define D_ 256
#define H_ 8
#define WIN_ 64
#define CIN_ 128
#define DH_ 32
#define DFF_ 512
#define L_ 4
#define PSTR 152 // attn Ps/Vt LDS row stride (shorts)
#define FSTR 520 // ffn F-tile LDS row stride (shorts)
#define HSTR 264 // h1 bf16 LDS row stride (shorts)
#define WSTR 72  // BK=64 weight/A tile row stride (shorts)

typedef __attribute__((ext_vector_type(4))) short s16x4;
typedef __attribute__((ext_vector_type(8))) short s16x8;
typedef __attribute__((ext_vector_type(4))) float f32x4;

__device__ inline short f2bf(float f) {
    __hip_bfloat16 h = __float2bfloat16(f);
    return *reinterpret_cast<short*>(&h);
}

// ---------------- one-time weight prep
__global__ __launch_bounds__(256) void prep_w(
    const float* __restrict__ wqkv, const float* __restrict__ wo,
    const float* __restrict__ w1, const float* __restrict__ w2,
    const float* __restrict__ pw0, const float* __restrict__ pw1,
    const float* __restrict__ qw0, const float* __restrict__ qw1,
    short* __restrict__ dst) {
    const int N0 = 786432, N1 = 1048576, N2 = 1572864, NT = 2097152;
    const int NTOT = 2686976;
    for (int i = blockIdx.x * 256 + threadIdx.x; i < NTOT; i += gridDim.x * 256) {
        float v;
        if (i < NT) {
            if (i < N0) v = wqkv[i];
            else if (i < N1) v = wo[i - N0];
            else if (i < N2) v = w1[i - N1];
            else v = w2[i - N2];
        } else {
            int j = i - NT;
            const float* src;
            int I;
            if (j < 98304)       { src = pw0; I = 128; }
            else if (j < 294912) { src = pw1; I = 256; j -= 98304; }
            else if (j < 491520) { src = qw0; I = 256; j -= 294912; }
            else                 { src = qw1; I = 256; j -= 491520; }
            int o = j / (3 * I);
            int rem = j - o * 3 * I;
            int k = rem / I, ii = rem - k * I;
            v = src[(size_t)(o * I + ii) * 3 + k];
        }
        dst[i] = f2bf(v);
    }
}

// ---------------- fused im2col + conv-GEMM + LN2d-partial, 16x64 tile, BK=64
template <int I_, int BTD>
__global__ __launch_bounds__(256) void gemm_conv16(
    const float* __restrict__ x, const short* __restrict__ Wr,
    const float* __restrict__ bias, float* __restrict__ Y, int O,
    float* __restrict__ part2) {
    const int K = 3 * I_;
    __shared__ short Al[16 * WSTR];
    __shared__ short Wl[64 * WSTR];
    __shared__ float sh[8];
    int tid = threadIdx.x;
    int col0 = blockIdx.x * 64;
    int row0 = blockIdx.y * 16;
    int b = row0 >> 10, t0 = row0 & 1023;
    int wave = tid >> 6, lane = tid & 63;
    int lg = lane >> 4, lr = lane & 15;
    f32x4 acc = {0.f, 0.f, 0.f, 0.f};

    for (int k0 = 0; k0 < K; k0 += 64) {
        int k = k0 / I_;          // tap (chunk never crosses tap: I_ % 64 == 0)
        int i0 = k0 - k * I_;
        // A tile: 16 t-rows x 64 channels, 1024 elems, 4/thread
#pragma unroll
        for (int p = 0; p < 4; ++p) {
            int e = p * 256 + tid;
            int rr, cc;
            float v;
            if (BTD) {
                rr = e >> 6; cc = e & 63;
                int tg = t0 + rr - 1 + k;
                v = (tg >= 0 && tg < T_) ? x[((size_t)(b * T_ + tg)) * I_ + i0 + cc] : 0.f;
            } else {
                cc = e >> 4; rr = e & 15;
                int tg = t0 + rr - 1 + k;
                v = (tg >= 0 && tg < T_) ? x[((size_t)(b * I_ + i0 + cc)) * T_ + tg] : 0.f;
            }
            Al[rr * WSTR + cc] = f2bf(v);
        }
        // W tile: 64 rows x 64, s16x4 copies, 4/thread
#pragma unroll
        for (int p = 0; p < 4; ++p) {
            int e = p * 256 + tid;
            int rr = e >> 4, c4 = (e & 15) * 4;
            *(s16x4*)&Wl[rr * WSTR + c4] =
                *(const s16x4*)&Wr[(size_t)(col0 + rr) * K + k0 + c4];
        }
        __syncthreads();
        s16x8 af0 = *(const s16x8*)&Al[lr * WSTR + lg * 8];
        s16x8 af1 = *(const s16x8*)&Al[lr * WSTR + 32 + lg * 8];
        s16x8 wf0 = *(const s16x8*)&Wl[(wave * 16 + lr) * WSTR + lg * 8];
        s16x8 wf1 = *(const s16x8*)&Wl[(wave * 16 + lr) * WSTR + 32 + lg * 8];
        acc = __builtin_amdgcn_mfma_f32_16x16x32_bf16(af0, wf0, acc, 0, 0, 0);
        acc = __builtin_amdgcn_mfma_f32_16x16x32_bf16(af1, wf1, acc, 0, 0, 0);
        __syncthreads();
    }

    int cg = col0 + wave * 16 + lr;
    float bv = bias[cg];
    float4 o;
    o.x = acc[0] + bv; o.y = acc[1] + bv; o.z = acc[2] + bv; o.w = acc[3] + bv;
    *(float4*)&Y[((size_t)(b * O + cg)) * 1024 + t0 + lg * 4] = o;

    float s = o.x + o.y + o.z + o.w;
    float ss = o.x * o.x + o.y * o.y + o.z * o.z + o.w * o.w;
#pragma unroll
    for (int off = 32; off; off >>= 1) {
        s += __shfl_xor(s, off);
        ss += __shfl_xor(ss, off);
    }
    if (lane == 0) { sh[wave * 2] = s; sh[wave * 2 + 1] = ss; }
    __syncthreads();
    if (tid == 0) {
        float ts = sh[0] + sh[2] + sh[4] + sh[6];
        float tss = sh[1] + sh[3] + sh[5] + sh[7];
        int slot = b * (gridDim.x * 64) + blockIdx.x * 64 + (blockIdx.y & 63);
        part2[slot * 2] = ts;
        part2[slot * 2 + 1] = tss;
    }
}

// ---------------- bf16-weight MFMA GEMM (QKV), 64x64 tile, BK=64, bf16 out
template <int RELU, int BF16OUT>
__global__ __launch_bounds__(256) void gemm64w(
    const float* __restrict__ A, const short* __restrict__ Wbf,
    const float* __restrict__ bias, void* __restrict__ Yv,
    int M, int N, int K) {
    __shared__ short Al[64 * WSTR];
    __shared__ short Wl[64 * WSTR];
    int tid = threadIdx.x;
    int row0 = blockIdx.y * 64, col0 = blockIdx.x * 64;
    int wave = tid >> 6, lane = tid & 63;
    int wr = wave >> 1, wc = wave & 1;
    int lg = lane >> 4, lr = lane & 15;
    f32x4 acc[2][2] = {};

    for (int k0 = 0; k0 < K; k0 += 64) {
#pragma unroll
        for (int p = 0; p < 4; ++p) {
            int e = p * 256 + tid;
            int rr = e >> 4, c4 = (e & 15) * 4;
            float4 va = *(const float4*)&A[(size_t)(row0 + rr) * K + k0 + c4];
            s16x4 sa;
            sa[0] = f2bf(va.x); sa[1] = f2bf(va.y); sa[2] = f2bf(va.z); sa[3] = f2bf(va.w);
            *(s16x4*)&Al[rr * WSTR + c4] = sa;
            *(s16x4*)&Wl[rr * WSTR + c4] =
                *(const s16x4*)&Wbf[(size_t)(col0 + rr) * K + k0 + c4];
        }
        __syncthreads();
#pragma unroll
        for (int s = 0; s < 2; ++s) {
            s16x8 af[2], wf[2];
#pragma unroll
            for (int i = 0; i < 2; ++i) {
                af[i] = *(const s16x8*)&Al[(wr * 32 + i * 16 + lr) * WSTR + s * 32 + lg * 8];
                wf[i] = *(const s16x8*)&Wl[(wc * 32 + i * 16 + lr) * WSTR + s * 32 + lg * 8];
            }
#pragma unroll
            for (int i = 0; i < 2; ++i)
#pragma unroll
                for (int j = 0; j < 2; ++j)
                    acc[i][j] = __builtin_amdgcn_mfma_f32_16x16x32_bf16(af[i], wf[j], acc[i][j], 0, 0, 0);
        }
        __syncthreads();
    }
#pragma unroll
    for (int i = 0; i < 2; ++i) {
        int rg = row0 + wr * 32 + i * 16 + lg * 4;
#pragma unroll
        for (int j = 0; j < 2; ++j) {
            int cg = col0 + wc * 32 + j * 16 + lr;
            float bv = bias[cg];
#pragma unroll
            for (int q = 0; q < 4; ++q) {
                float v = acc[i][j][q] + bv;
                if (RELU) v = fmaxf(v, 0.f);
                if (BF16OUT) ((short*)Yv)[(size_t)(rg + q) * N + cg] = f2bf(v);
                else ((float*)Yv)[(size_t)(rg + q) * N + cg] = v;
            }
        }
    }
}

// ---------------- fused layer tail, BK=64: Wo-GEMM + LN1 + FFN1 + FFN2 + LN2
__global__ __launch_bounds__(512) void layer_tail(
    const short* __restrict__ ATTb, const short* __restrict__ Wobf,
    const float* __restrict__ bo, const short* __restrict__ W1bf,
    const float* __restrict__ b1, const short* __restrict__ W2bf,
    const float* __restrict__ b2, float* __restrict__ H,
    const float* __restrict__ ln1w, const float* __restrict__ ln1b,
    const float* __restrict__ ln2w, const float* __restrict__ ln2b) {
    __shared__ short As[16 * WSTR];
    __shared__ short Ws[256 * WSTR];   // 36.9 KB weight stage (all phases)
    __shared__ float Gf[16][260];      // G1, then h1 fp32
    __shared__ short h1b[16 * HSTR];   // h1 bf16
    __shared__ short Fs[16 * FSTR];    // FFN1 output bf16
    __shared__ float G2[16][260];
    int tid = threadIdx.x;
    int wave = tid >> 6, lane = tid & 63;
    int lg = lane >> 4, lr = lane & 15;
    int m0 = blockIdx.x * 16;

    // ---- phase A: G1 = ATT @ Wo^T + bo   (K=256, N=256, 4 iters)
    f32x4 accA[2] = {};
    for (int k0 = 0; k0 < 256; k0 += 64) {
        if (tid < 256) {               // A: 16x64 shorts, 256 s16x4 tasks
            int r = tid >> 4, c = (tid & 15) * 4;
            *(s16x4*)&As[r * WSTR + c] =
                *(const s16x4*)&ATTb[(size_t)(m0 + r) * 256 + k0 + c];
        }
#pragma unroll
        for (int u = 0; u < 4; ++u) {  // W: 256x64 shorts, 2048 s16x8 tasks
            int e = tid + 512 * u;
            int r = e >> 3, c8 = (e & 7) * 8;
            *(s16x8*)&Ws[r * WSTR + c8] = *(const s16x8*)&Wobf[(size_t)r * 256 + k0 + c8];
        }
        __syncthreads();
#pragma unroll
        for (int s = 0; s < 2; ++s) {
            s16x8 af = *(const s16x8*)&As[lr * WSTR + s * 32 + lg * 8];
#pragma unroll
            for (int j = 0; j < 2; ++j) {
                s16x8 wf = *(const s16x8*)&Ws[(wave * 32 + j * 16 + lr) * WSTR + s * 32 + lg * 8];
                accA[j] = __builtin_amdgcn_mfma_f32_16x16x32_bf16(af, wf, accA[j], 0, 0, 0);
            }
        }
        __syncthreads();
    }
#pragma unroll
    for (int j = 0; j < 2; ++j) {
        int col = wave * 32 + j * 16 + lr;
        float bv = bo[col];
#pragma unroll
        for (int q = 0; q < 4; ++q)
            Gf[lg * 4 + q][col] = accA[j][q] + bv;
    }
    __syncthreads();

    // ---- LN1: h1 = LN(H + G1); fp32 in Gf, bf16 in h1b
    for (int rr = 0; rr < 2; ++rr) {
        int row = wave * 2 + rr;
        size_t base = (size_t)(m0 + row) * D_;
        float x[4];
        float s = 0.f;
#pragma unroll
        for (int i = 0; i < 4; ++i) {
            int idx = i * 64 + lane;
            x[i] = H[base + idx] + Gf[row][idx];
            s += x[i];
        }
#pragma unroll
        for (int off = 32; off; off >>= 1) s += __shfl_xor(s, off);
        float mu = s * (1.f / D_);
        float ss = 0.f;
#pragma unroll
        for (int i = 0; i < 4; ++i) { float d = x[i] - mu; ss += d * d; }
#pragma unroll
        for (int off = 32; off; off >>= 1) ss += __shfl_xor(ss, off);
        float rstd = rsqrtf(ss * (1.f / D_) + 1e-5f);
#pragma unroll
        for (int i = 0; i < 4; ++i) {
            int idx = i * 64 + lane;
            float h1v = (x[i] - mu) * rstd * ln1w[idx] + ln1b[idx];
            Gf[row][idx] = h1v;
            h1b[row * HSTR + idx] = f2bf(h1v);
        }
    }
    __syncthreads();

    // ---- phase B: F = relu(h1 @ W1^T + b1)  (K=256, two 256-col halves, 4 iters each)
    for (int nh = 0; nh < 2; ++nh) {
        f32x4 acc1[2] = {};
        for (int k0 = 0; k0 < 256; k0 += 64) {
#pragma unroll
            for (int u = 0; u < 4; ++u) {
                int e = tid + 512 * u;
                int r = e >> 3, c8 = (e & 7) * 8;
                *(s16x8*)&Ws[r * WSTR + c8] =
                    *(const s16x8*)&W1bf[(size_t)(nh * 256 + r) * 256 + k0 + c8];
            }
            __syncthreads();
#pragma unroll
            for (int s = 0; s < 2; ++s) {
                s16x8 af = *(const s16x8*)&h1b[lr * HSTR + k0 + s * 32 + lg * 8];
#pragma unroll
                for (int j = 0; j < 2; ++j) {
                    s16x8 wf = *(const s16x8*)&Ws[(wave * 32 + j * 16 + lr) * WSTR + s * 32 + lg * 8];
                    acc1[j] = __builtin_amdgcn_mfma_f32_16x16x32_bf16(af, wf, acc1[j], 0, 0, 0);
                }
            }
            __syncthreads();
        }
#pragma unroll
        for (int j = 0; j < 2; ++j) {
            int col = nh * 256 + wave * 32 + j * 16 + lr;
            float bv = b1[col];
#pragma unroll
            for (int q = 0; q < 4; ++q)
                Fs[(lg * 4 + q) * FSTR + col] = f2bf(fmaxf(acc1[j][q] + bv, 0.f));
        }
        __syncthreads();
    }

    // ---- phase C: G2 = F @ W2^T + b2  (K=512, 8 iters)
    f32x4 acc2[2] = {};
    for (int k0 = 0; k0 < 512; k0 += 64) {
#pragma unroll
        for (int u = 0; u < 4; ++u) {
            int e = tid + 512 * u;
            int r = e >> 3, c8 = (e & 7) * 8;
            *(s16x8*)&Ws[r * WSTR + c8] = *(const s16x8*)&W2bf[(size_t)r * 512 + k0 + c8];
        }
        __syncthreads();
#pragma unroll
        for (int s = 0; s < 2; ++s) {
            s16x8 af = *(const s16x8*)&Fs[lr * FSTR + k0 + s * 32 + lg * 8];
#pragma unroll
            for (int j = 0; j < 2; ++j) {
                s16x8 wf = *(const s16x8*)&Ws[(wave * 32 + j * 16 + lr) * WSTR + s * 32 + lg * 8];
                acc2[j] = __builtin_amdgcn_mfma_f32_16x16x32_bf16(af, wf, acc2[j], 0, 0, 0);
            }
        }
        __syncthreads();
    }
#pragma unroll
    for (int j = 0; j < 2; ++j) {
        int col = wave * 32 + j * 16 + lr;
        float bv = b2[col];
#pragma unroll
        for (int q = 0; q < 4; ++q)
            G2[lg * 4 + q][col] = acc2[j][q] + bv;
    }
    __syncthreads();

    // ---- LN2: H = LN(h1 + G2)
    for (int rr = 0; rr < 2; ++rr) {
        int row = wave * 2 + rr;
        size_t base = (size_t)(m0 + row) * D_;
        float x[4];
        float s = 0.f;
#pragma unroll
        for (int i = 0; i < 4; ++i) {
            int idx = i * 64 + lane;
            x[i] = Gf[row][idx] + G2[row][idx];
            s += x[i];
        }
#pragma unroll
        for (int off = 32; off; off >>= 1) s += __shfl_xor(s, off);
        float mu = s * (1.f / D_);
        float ss = 0.f;
#pragma unroll
        for (int i = 0; i < 4; ++i) { float d = x[i] - mu; ss += d * d; }
#pragma unroll
        for (int off = 32; off; off >>= 1) ss += __shfl_xor(ss, off);
        float rstd = rsqrtf(ss * (1.f / D_) + 1e-5f);
#pragma unroll
        for (int i = 0; i < 4; ++i) {
            int idx = i * 64 + lane;
            H[base + idx] = (x[i] - mu) * rstd * ln2w[idx] + ln2b[idx];
        }
    }
}

// ---------------- MFMA banded attention (bf16 in, bf16 out)
__global__ __launch_bounds__(256) void attn_mfma(
    const short* __restrict__ qkv, short* __restrict__ out) {
    int q0 = blockIdx.x * 64;
    int h = blockIdx.y, b = blockIdx.z;
    int tid = threadIdx.x;
    int wave = tid >> 6, lane = tid & 63;
    int lg = lane >> 4;
    int lr = lane & 15;
    const int j0 = q0 - 64;

    __shared__ short Qs[64][40];
    __shared__ short Ks[128][40];
    __shared__ short Vt[32][PSTR];
    __shared__ short Ps[64][PSTR];

#pragma unroll
    for (int u = 0; u < 2; ++u) {
        int task = tid + 256 * u;
        int r = task >> 3, c = (task & 7) * 4;
        *(s16x4*)&Qs[r][c] =
            *(const s16x4*)&qkv[((size_t)(b * T_ + q0 + r)) * 768 + h * 32 + c];
    }
#pragma unroll
    for (int u = 0; u < 4; ++u) {
        int task = tid + 256 * u;
        int r = task >> 3, c = (task & 7) * 4;
        int jg = j0 + r;
        s16x4 sa = {0, 0, 0, 0};
        if (jg >= 0)
            sa = *(const s16x4*)&qkv[((size_t)(b * T_ + jg)) * 768 + 256 + h * 32 + c];
        *(s16x4*)&Ks[r][c] = sa;
    }
#pragma unroll
    for (int u = 0; u < 4; ++u) {
        int task = tid + 256 * u;
        int r = task >> 3, c = (task & 7) * 4;
        int jg = j0 + r;
        s16x4 v4 = {0, 0, 0, 0};
        if (jg >= 0)
            v4 = *(const s16x4*)&qkv[((size_t)(b * T_ + jg)) * 768 + 512 + h * 32 + c];
        Vt[c + 0][r] = v4[0];
        Vt[c + 1][r] = v4[1];
        Vt[c + 2][r] = v4[2];
        Vt[c + 3][r] = v4[3];
    }
    __syncthreads();

    s16x8 aq = *(const s16x8*)&Qs[16 * wave + lr][lg * 8];
    f32x4 sacc[8];
#pragma unroll
    for (int j = 0; j < 8; ++j) {
        s16x8 bk = *(const s16x8*)&Ks[16 * j + lr][lg * 8];
        f32x4 z = {0.f, 0.f, 0.f, 0.f};
        sacc[j] = __builtin_amdgcn_mfma_f32_16x16x32_bf16(aq, bk, z, 0, 0, 0);
    }

    const float scale = 0.17677669529663687f;
#pragma unroll
    for (int j = 0; j < 8; ++j) {
        int jg = j0 + 16 * j + lr;
#pragma unroll
        for (int q = 0; q < 4; ++q) {
            int qi = q0 + 16 * wave + lg * 4 + q;
            bool ok = ((jg >= qi - WIN_) && (jg < qi) && (jg >= 0)) || (qi == 0 && jg == 0);
            sacc[j][q] = ok ? sacc[j][q] * scale : -1e30f;
        }
    }
#pragma unroll
    for (int q = 0; q < 4; ++q) {
        float m = sacc[0][q];
#pragma unroll
        for (int j = 1; j < 8; ++j) m = fmaxf(m, sacc[j][q]);
#pragma unroll
        for (int off = 1; off < 16; off <<= 1) m = fmaxf(m, __shfl_xor(m, off));
        float e[8], sum = 0.f;
#pragma unroll
        for (int j = 0; j < 8; ++j) { e[j] = __expf(sacc[j][q] - m); sum += e[j]; }
#pragma unroll
        for (int off = 1; off < 16; off <<= 1) sum += __shfl_xor(sum, off);
        float inv = 1.f / sum;
        int row = 16 * wave + lg * 4 + q;
#pragma unroll
        for (int j = 0; j < 8; ++j) Ps[row][16 * j + lr] = f2bf(e[j] * inv);
    }

    f32x4 oacc[2] = {};
#pragma unroll
    for (int kk = 0; kk < 4; ++kk) {
        s16x8 ap = *(const s16x8*)&Ps[16 * wave + lr][kk * 32 + lg * 8];
#pragma unroll
        for (int n = 0; n < 2; ++n) {
            s16x8 bv = *(const s16x8*)&Vt[16 * n + lr][kk * 32 + lg * 8];
            oacc[n] = __builtin_amdgcn_mfma_f32_16x16x32_bf16(ap, bv, oacc[n], 0, 0, 0);
        }
    }
#pragma unroll
    for (int n = 0; n < 2; ++n)
#pragma unroll
        for (int q = 0; q < 4; ++q) {
            int qi = q0 + 16 * wave + lg * 4 + q;
            out[((size_t)(b * T_ + qi)) * D_ + h * 32 + 16 * n + lr] = f2bf(oacc[n][q]);
        }
}

// ---------------- LN2d apply + ReLU (float4); stats reduced from part2 in-kernel
__global__ __launch_bounds__(256) void ln2d_apply(
    const float* __restrict__ x, const float* __restrict__ w,
    const float* __restrict__ bb, const float* __restrict__ part2,
    float* __restrict__ y, int CT, int npart) {
    int b = blockIdx.y;
    int tid = threadIdx.x;
    __shared__ float sstat[2];
    if (tid < 64) {
        float s = 0.f, ss = 0.f;
        const float2* p2 = (const float2*)part2 + (size_t)b * npart;
        for (int i = tid; i < npart; i += 64) { float2 v = p2[i]; s += v.x; ss += v.y; }
#pragma unroll
        for (int off = 32; off; off >>= 1) {
            s += __shfl_xor(s, off);
            ss += __shfl_xor(ss, off);
        }
        if (tid == 0) {
            float mu = s / (float)CT;
            sstat[0] = mu;
            sstat[1] = rsqrtf(ss / (float)CT - mu * mu + 1e-5f);
        }
    }
    __syncthreads();
    float mu = sstat[0], rstd = sstat[1];
    int idx = blockIdx.x * 256 + tid;
    const float4* x4 = (const float4*)(x + (size_t)b * CT);
    const float4* w4 = (const float4*)w;
    const float4* b4 = (const float4*)bb;
    float4* y4 = (float4*)(y + (size_t)b * CT);
    float4 v = x4[idx], wv = w4[idx], bv = b4[idx];
    float4 r;
    r.x = fmaxf((v.x - mu) * rstd * wv.x + bv.x, 0.f);
    r.y = fmaxf((v.y - mu) * rstd * wv.y + bv.y, 0.f);
    r.z = fmaxf((v.z - mu) * rstd * wv.z + bv.z, 0.f);
    r.w = fmaxf((v.w - mu) * rstd * wv.w + bv.w, 0.f);
    y4[idx] = r;
}

// ---------------- LN2d apply + ReLU + transpose + pos add: [B,D,T] -> [B,T,D]
__global__ __launch_bounds__(256) void ln2d_apply_t(
    const float* __restrict__ x, const float* __restrict__ w,
    const float* __restrict__ bb, const float* __restrict__ part2,
    const float* __restrict__ pos, float* __restrict__ h, int npart) {
    int t0 = blockIdx.x * 32;
    int d0 = blockIdx.y * 32;
    int b = blockIdx.z;
    int tid = threadIdx.x;
    __shared__ float sstat[2];
    if (tid < 64) {
        float s = 0.f, ss = 0.f;
        const float2* p2 = (const float2*)part2 + (size_t)b * npart;
        for (int i = tid; i < npart; i += 64) { float2 v = p2[i]; s += v.x; ss += v.y; }
#pragma unroll
        for (int off = 32; off; off >>= 1) {
            s += __shfl_xor(s, off);
            ss += __shfl_xor(ss, off);
        }
        if (tid == 0) {
            float mu = s / (float)(D_ * T_);
            sstat[0] = mu;
            sstat[1] = rsqrtf(ss / (float)(D_ * T_) - mu * mu + 1e-5f);
        }
    }
    __syncthreads();
    float mu = sstat[0], rstd = sstat[1];
    __shared__ float xs[32][33];
    int tt = tid & 31, dd = tid >> 5;
#pragma unroll
    for (int p = 0; p < 4; ++p) {
        int d = d0 + dd + p * 8;
        size_t off = ((size_t)b * D_ + d) * T_ + t0 + tt;
        size_t woff = (size_t)d * T_ + t0 + tt;
        float v = (x[off] - mu) * rstd * w[woff] + bb[woff];
        xs[dd + p * 8][tt] = fmaxf(v, 0.f);
    }
    __syncthreads();
    int dd2 = tid & 31, tt2 = tid >> 5;
#pragma unroll
    for (int p = 0; p < 4; ++p) {
        int t = t0 + tt2 + p * 8;
        h[((size_t)(b * T_ + t)) * D_ + d0 + dd2] =
            xs[dd2][tt2 + p * 8] + pos[(size_t)t * D_ + d0 + dd2];
    }
}

extern "C" void kernel_launch(void* const* d_in, const int* in_sizes, int n_in,
                              void* d_out, int out_size, void* d_ws, size_t ws_size,
                              hipStream_t stream) {
    const float* x        = (const float*)d_in[0];
    const float* pre_w0   = (const float*)d_in[1];
    const float* pre_b0   = (const float*)d_in[2];
    const float* pre_lnw0 = (const float*)d_in[3];
    const float* pre_lnb0 = (const float*)d_in[4];
    const float* pre_w1   = (const float*)d_in[5];
    const float* pre_b1   = (const float*)d_in[6];
    const float* pre_lnw1 = (const float*)d_in[7];
    const float* pre_lnb1 = (const float*)d_in[8];
    const float* pos_emb  = (const float*)d_in[9];
    const float* Wqkv     = (const float*)d_in[10];
    const float* bqkv     = (const float*)d_in[11];
    const float* Wo       = (const float*)d_in[12];
    const float* bo       = (const float*)d_in[13];
    const float* ln1w     = (const float*)d_in[14];
    const float* ln1b     = (const float*)d_in[15];
    const float* W1       = (const float*)d_in[16];
    const float* b1       = (const float*)d_in[17];
    const float* W2       = (const float*)d_in[18];
    const float* b2       = (const float*)d_in[19];
    const float* ln2w     = (const float*)d_in[20];
    const float* ln2b     = (const float*)d_in[21];
    const float* post_w0  = (const float*)d_in[22];
    const float* post_b0  = (const float*)d_in[23];
    const float* post_lnw0= (const float*)d_in[24];
    const float* post_lnb0= (const float*)d_in[25];
    const float* post_w1  = (const float*)d_in[26];
    const float* post_b1  = (const float*)d_in[27];
    const float* post_lnw1= (const float*)d_in[28];
    const float* post_lnb1= (const float*)d_in[29];

    float* ws = (float*)d_ws;
    const size_t M1 = 1u << 20;              // 1M floats
    float* H     = ws;                       // [B,T,D] fp32
    float* A0    = ws + 1 * M1;              // [B,D,T] fp32 (pre/post only)
    float* A1    = ws + 2 * M1;              // [B,D,T] fp32 (pre/post only)
    short* QKVb  = (short*)(ws + 1 * M1);    // [B,T,768] bf16 (aliases A0/A1)
    short* ATTb  = (short*)(ws + 5 * M1);    // [B,T,256] bf16
    short* wbf   = (short*)(ws + 6 * M1);    // transformer weights bf16
    short* wqkv_bf = wbf;
    short* wo_bf   = wbf + 786432;
    short* w1_bf   = wbf + 1048576;
    short* w2_bf   = wbf + 1572864;
    short* cwbf  = wbf + 2097152;            // conv weights reordered
    short* cw_pre0  = cwbf;                  // [256][3*128]
    short* cw_pre1  = cwbf + 98304;          // [256][3*256]
    short* cw_post0 = cwbf + 294912;         // [256][3*256]
    short* cw_post1 = cwbf + 491520;         // [128][3*256]
    float* part2 = ws + 8 * M1;              // up to 4*256*2 floats

    const int M = B_ * T_;  // 4096

    // ---- one-time weight prep
    prep_w<<<2048, 256, 0, stream>>>(Wqkv, Wo, W1, W2,
                                     pre_w0, pre_w1, post_w0, post_w1, wbf);

    // ---- pre stage
    gemm_conv16<128, 0><<<dim3(D_ / 64, M / 16), 256, 0, stream>>>(
        x, cw_pre0, pre_b0, A0, D_, part2);
    ln2d_apply<<<dim3(D_ * T_ / 1024, B_), 256, 0, stream>>>(
        A0, pre_lnw0, pre_lnb0, part2, A1, D_ * T_, 256);
    gemm_conv16<256, 0><<<dim3(D_ / 64, M / 16), 256, 0, stream>>>(
        A1, cw_pre1, pre_b1, A0, D_, part2);
    ln2d_apply_t<<<dim3(T_ / 32, D_ / 32, B_), 256, 0, stream>>>(
        A0, pre_lnw1, pre_lnb1, part2, pos_emb, H, 256);

    // ---- transformer layers (3 dispatches each)
    for (int l = 0; l < L_; ++l) {
        gemm64w<0, 1><<<dim3(768 / 64, M / 64), 256, 0, stream>>>(
            H, wqkv_bf + (size_t)l * 196608, bqkv + (size_t)l * 768, QKVb, M, 768, D_);
        attn_mfma<<<dim3(T_ / 64, H_, B_), 256, 0, stream>>>(QKVb, ATTb);
        layer_tail<<<M / 16, 512, 0, stream>>>(
            ATTb, wo_bf + (size_t)l * 65536, bo + (size_t)l * D_,
            w1_bf + (size_t)l * 131072, b1 + (size_t)l * DFF_,
            w2_bf + (size_t)l * 131072, b2 + (size_t)l * D_, H,
            ln1w + (size_t)l * D_, ln1b + (size_t)l * D_,
            ln2w + (size_t)l * D_, ln2b + (size_t)l * D_);
    }

    // ---- post stage
    gemm_conv16<256, 1><<<dim3(D_ / 64, M / 16), 256, 0, stream>>>(
        H, cw_post0, post_b0, A1, D_, part2);
    ln2d_apply<<<dim3(D_ * T_ / 1024, B_), 256, 0, stream>>>(
        A1, post_lnw0, post_lnb0, part2, A0, D_ * T_, 256);
    gemm_conv16<256, 0><<<dim3(CIN_ / 64, M / 16), 256, 0, stream>>>(
        A0, cw_post1, post_b1, A1, CIN_, part2);
    ln2d_apply<<<dim3(CIN_ * T_ / 1024, B_), 256, 0, stream>>>(
        A1, post_lnw1, post_lnb1, part2, (float*)d_out, CIN_ * T_, 128);
}

// Round 17
// 234.708 us; speedup vs baseline: 9.8305x; 1.0612x over previous
//
#include <hip/hip_runtime.h>
#include <hip/hip_bf16.h>

#define B_ 4
#define T_ 1024
#define D_ 256
#define H_ 8
#define WIN_ 64
#define CIN_ 128
#define DH_ 32
#define DFF_ 512
#define L_ 4
#define PSTR 152 // attn Ps/Vt LDS row stride (shorts)
#define FSTR 520 // ffn F-tile LDS row stride (shorts)
#define HSTR 264 // h1 bf16 LDS row stride (shorts)
#define WSTR 72  // BK=64 weight/A tile row stride (shorts)

typedef __attribute__((ext_vector_type(4))) short s16x4;
typedef __attribute__((ext_vector_type(8))) short s16x8;
typedef __attribute__((ext_vector_type(4))) float f32x4;

__device__ inline short f2bf(float f) {
    __hip_bfloat16 h = __float2bfloat16(f);
    return *reinterpret_cast<short*>(&h);
}

// ---------------- one-time weight prep
__global__ __launch_bounds__(256) void prep_w(
    const float* __restrict__ wqkv, const float* __restrict__ wo,
    const float* __restrict__ w1, const float* __restrict__ w2,
    const float* __restrict__ pw0, const float* __restrict__ pw1,
    const float* __restrict__ qw0, const float* __restrict__ qw1,
    short* __restrict__ dst) {
    const int N0 = 786432, N1 = 1048576, N2 = 1572864, NT = 2097152;
    const int NTOT = 2686976;
    for (int i = blockIdx.x * 256 + threadIdx.x; i < NTOT; i += gridDim.x * 256) {
        float v;
        if (i < NT) {
            if (i < N0) v = wqkv[i];
            else if (i < N1) v = wo[i - N0];
            else if (i < N2) v = w1[i - N1];
            else v = w2[i - N2];
        } else {
            int j = i - NT;
            const float* src;
            int I;
            if (j < 98304)       { src = pw0; I = 128; }
            else if (j < 294912) { src = pw1; I = 256; j -= 98304; }
            else if (j < 491520) { src = qw0; I = 256; j -= 294912; }
            else                 { src = qw1; I = 256; j -= 491520; }
            int o = j / (3 * I);
            int rem = j - o * 3 * I;
            int k = rem / I, ii = rem - k * I;
            v = src[(size_t)(o * I + ii) * 3 + k];
        }
        dst[i] = f2bf(v);
    }
}

// ---------------- fused im2col + conv-GEMM + LN2d-partial, 16x64 tile, BK=64
template <int I_, int BTD>
__global__ __launch_bounds__(256) void gemm_conv16(
    const float* __restrict__ x, const short* __restrict__ Wr,
    const float* __restrict__ bias, float* __restrict__ Y, int O,
    float* __restrict__ part2) {
    const int K = 3 * I_;
    __shared__ short Al[16 * WSTR];
    __shared__ short Wl[64 * WSTR];
    __shared__ float sh[8];
    int tid = threadIdx.x;
    int col0 = blockIdx.x * 64;
    int row0 = blockIdx.y * 16;
    int b = row0 >> 10, t0 = row0 & 1023;
    int wave = tid >> 6, lane = tid & 63;
    int lg = lane >> 4, lr = lane & 15;
    f32x4 acc = {0.f, 0.f, 0.f, 0.f};

    for (int k0 = 0; k0 < K; k0 += 64) {
        int k = k0 / I_;
        int i0 = k0 - k * I_;
#pragma unroll
        for (int p = 0; p < 4; ++p) {
            int e = p * 256 + tid;
            int rr, cc;
            float v;
            if (BTD) {
                rr = e >> 6; cc = e & 63;
                int tg = t0 + rr - 1 + k;
                v = (tg >= 0 && tg < T_) ? x[((size_t)(b * T_ + tg)) * I_ + i0 + cc] : 0.f;
            } else {
                cc = e >> 4; rr = e & 15;
                int tg = t0 + rr - 1 + k;
                v = (tg >= 0 && tg < T_) ? x[((size_t)(b * I_ + i0 + cc)) * T_ + tg] : 0.f;
            }
            Al[rr * WSTR + cc] = f2bf(v);
        }
#pragma unroll
        for (int p = 0; p < 4; ++p) {
            int e = p * 256 + tid;
            int rr = e >> 4, c4 = (e & 15) * 4;
            *(s16x4*)&Wl[rr * WSTR + c4] =
                *(const s16x4*)&Wr[(size_t)(col0 + rr) * K + k0 + c4];
        }
        __syncthreads();
        s16x8 af0 = *(const s16x8*)&Al[lr * WSTR + lg * 8];
        s16x8 af1 = *(const s16x8*)&Al[lr * WSTR + 32 + lg * 8];
        s16x8 wf0 = *(const s16x8*)&Wl[(wave * 16 + lr) * WSTR + lg * 8];
        s16x8 wf1 = *(const s16x8*)&Wl[(wave * 16 + lr) * WSTR + 32 + lg * 8];
        acc = __builtin_amdgcn_mfma_f32_16x16x32_bf16(af0, wf0, acc, 0, 0, 0);
        acc = __builtin_amdgcn_mfma_f32_16x16x32_bf16(af1, wf1, acc, 0, 0, 0);
        __syncthreads();
    }

    int cg = col0 + wave * 16 + lr;
    float bv = bias[cg];
    float4 o;
    o.x = acc[0] + bv; o.y = acc[1] + bv; o.z = acc[2] + bv; o.w = acc[3] + bv;
    *(float4*)&Y[((size_t)(b * O + cg)) * 1024 + t0 + lg * 4] = o;

    float s = o.x + o.y + o.z + o.w;
    float ss = o.x * o.x + o.y * o.y + o.z * o.z + o.w * o.w;
#pragma unroll
    for (int off = 32; off; off >>= 1) {
        s += __shfl_xor(s, off);
        ss += __shfl_xor(ss, off);
    }
    if (lane == 0) { sh[wave * 2] = s; sh[wave * 2 + 1] = ss; }
    __syncthreads();
    if (tid == 0) {
        float ts = sh[0] + sh[2] + sh[4] + sh[6];
        float tss = sh[1] + sh[3] + sh[5] + sh[7];
        int slot = b * (gridDim.x * 64) + blockIdx.x * 64 + (blockIdx.y & 63);
        part2[slot * 2] = ts;
        part2[slot * 2 + 1] = tss;
    }
}

// ---------------- bf16-weight MFMA GEMM (QKV), 64x64 tile, BK=64, bf16 out
template <int RELU, int BF16OUT>
__global__ __launch_bounds__(256) void gemm64w(
    const float* __restrict__ A, const short* __restrict__ Wbf,
    const float* __restrict__ bias, void* __restrict__ Yv,
    int M, int N, int K) {
    __shared__ short Al[64 * WSTR];
    __shared__ short Wl[64 * WSTR];
    int tid = threadIdx.x;
    int row0 = blockIdx.y * 64, col0 = blockIdx.x * 64;
    int wave = tid >> 6, lane = tid & 63;
    int wr = wave >> 1, wc = wave & 1;
    int lg = lane >> 4, lr = lane & 15;
    f32x4 acc[2][2] = {};

    for (int k0 = 0; k0 < K; k0 += 64) {
#pragma unroll
        for (int p = 0; p < 4; ++p) {
            int e = p * 256 + tid;
            int rr = e >> 4, c4 = (e & 15) * 4;
            float4 va = *(const float4*)&A[(size_t)(row0 + rr) * K + k0 + c4];
            s16x4 sa;
            sa[0] = f2bf(va.x); sa[1] = f2bf(va.y); sa[2] = f2bf(va.z); sa[3] = f2bf(va.w);
            *(s16x4*)&Al[rr * WSTR + c4] = sa;
            *(s16x4*)&Wl[rr * WSTR + c4] =
                *(const s16x4*)&Wbf[(size_t)(col0 + rr) * K + k0 + c4];
        }
        __syncthreads();
#pragma unroll
        for (int s = 0; s < 2; ++s) {
            s16x8 af[2], wf[2];
#pragma unroll
            for (int i = 0; i < 2; ++i) {
                af[i] = *(const s16x8*)&Al[(wr * 32 + i * 16 + lr) * WSTR + s * 32 + lg * 8];
                wf[i] = *(const s16x8*)&Wl[(wc * 32 + i * 16 + lr) * WSTR + s * 32 + lg * 8];
            }
#pragma unroll
            for (int i = 0; i < 2; ++i)
#pragma unroll
                for (int j = 0; j < 2; ++j)
                    acc[i][j] = __builtin_amdgcn_mfma_f32_16x16x32_bf16(af[i], wf[j], acc[i][j], 0, 0, 0);
        }
        __syncthreads();
    }
#pragma unroll
    for (int i = 0; i < 2; ++i) {
        int rg = row0 + wr * 32 + i * 16 + lg * 4;
#pragma unroll
        for (int j = 0; j < 2; ++j) {
            int cg = col0 + wc * 32 + j * 16 + lr;
            float bv = bias[cg];
#pragma unroll
            for (int q = 0; q < 4; ++q) {
                float v = acc[i][j][q] + bv;
                if (RELU) v = fmaxf(v, 0.f);
                if (BF16OUT) ((short*)Yv)[(size_t)(rg + q) * N + cg] = f2bf(v);
                else ((float*)Yv)[(size_t)(rg + q) * N + cg] = v;
            }
        }
    }
}

// ---------------- fused layer tail, BK=64 + register prefetch (T14):
// Wo-GEMM + LN1 + FFN1 + FFN2 + LN2. Bit-identical MFMA order.
__global__ __launch_bounds__(512) void layer_tail(
    const short* __restrict__ ATTb, const short* __restrict__ Wobf,
    const float* __restrict__ bo, const short* __restrict__ W1bf,
    const float* __restrict__ b1, const short* __restrict__ W2bf,
    const float* __restrict__ b2, float* __restrict__ H,
    const float* __restrict__ ln1w, const float* __restrict__ ln1b,
    const float* __restrict__ ln2w, const float* __restrict__ ln2b) {
    __shared__ short As[16 * WSTR];
    __shared__ short Ws[256 * WSTR];   // 36.9 KB weight stage (all phases)
    __shared__ float Gf[16][260];      // G1, then h1 fp32
    __shared__ short h1b[16 * HSTR];   // h1 bf16
    __shared__ short Fs[16 * FSTR];    // FFN1 output bf16
    __shared__ float G2[16][260];
    int tid = threadIdx.x;
    int wave = tid >> 6, lane = tid & 63;
    int lg = lane >> 4, lr = lane & 15;
    int m0 = blockIdx.x * 16;

    int wrow = tid >> 3, wc8 = (tid & 7) * 8;     // Ws task base (×4 with +64-row steps)
    int arow = tid >> 4, ac4 = (tid & 15) * 4;    // As task (tid<256)

    s16x8 wreg[4];
    s16x4 areg;

    // ---- phase A: G1 = ATT @ Wo^T + bo   (K=256, 4 iters, prefetched)
    f32x4 accA[2] = {};
    if (tid < 256)
        areg = *(const s16x4*)&ATTb[(size_t)(m0 + arow) * 256 + ac4];
#pragma unroll
    for (int u = 0; u < 4; ++u)
        wreg[u] = *(const s16x8*)&Wobf[(size_t)(wrow + u * 64) * 256 + wc8];
    for (int k0 = 0; k0 < 256; k0 += 64) {
        if (tid < 256) *(s16x4*)&As[arow * WSTR + ac4] = areg;
#pragma unroll
        for (int u = 0; u < 4; ++u)
            *(s16x8*)&Ws[(wrow + u * 64) * WSTR + wc8] = wreg[u];
        __syncthreads();
        int kn = k0 + 64;
        if (kn < 256) {
            if (tid < 256)
                areg = *(const s16x4*)&ATTb[(size_t)(m0 + arow) * 256 + kn + ac4];
#pragma unroll
            for (int u = 0; u < 4; ++u)
                wreg[u] = *(const s16x8*)&Wobf[(size_t)(wrow + u * 64) * 256 + kn + wc8];
        }
#pragma unroll
        for (int s = 0; s < 2; ++s) {
            s16x8 af = *(const s16x8*)&As[lr * WSTR + s * 32 + lg * 8];
#pragma unroll
            for (int j = 0; j < 2; ++j) {
                s16x8 wf = *(const s16x8*)&Ws[(wave * 32 + j * 16 + lr) * WSTR + s * 32 + lg * 8];
                accA[j] = __builtin_amdgcn_mfma_f32_16x16x32_bf16(af, wf, accA[j], 0, 0, 0);
            }
        }
        __syncthreads();
    }
#pragma unroll
    for (int j = 0; j < 2; ++j) {
        int col = wave * 32 + j * 16 + lr;
        float bv = bo[col];
#pragma unroll
        for (int q = 0; q < 4; ++q)
            Gf[lg * 4 + q][col] = accA[j][q] + bv;
    }
    __syncthreads();

    // ---- LN1: h1 = LN(H + G1); fp32 in Gf, bf16 in h1b
    for (int rr = 0; rr < 2; ++rr) {
        int row = wave * 2 + rr;
        size_t base = (size_t)(m0 + row) * D_;
        float x[4];
        float s = 0.f;
#pragma unroll
        for (int i = 0; i < 4; ++i) {
            int idx = i * 64 + lane;
            x[i] = H[base + idx] + Gf[row][idx];
            s += x[i];
        }
#pragma unroll
        for (int off = 32; off; off >>= 1) s += __shfl_xor(s, off);
        float mu = s * (1.f / D_);
        float ss = 0.f;
#pragma unroll
        for (int i = 0; i < 4; ++i) { float d = x[i] - mu; ss += d * d; }
#pragma unroll
        for (int off = 32; off; off >>= 1) ss += __shfl_xor(ss, off);
        float rstd = rsqrtf(ss * (1.f / D_) + 1e-5f);
#pragma unroll
        for (int i = 0; i < 4; ++i) {
            int idx = i * 64 + lane;
            float h1v = (x[i] - mu) * rstd * ln1w[idx] + ln1b[idx];
            Gf[row][idx] = h1v;
            h1b[row * HSTR + idx] = f2bf(h1v);
        }
    }
    __syncthreads();

    // ---- phase B: F = relu(h1 @ W1^T + b1)  (two 256-col halves, prefetched)
    for (int nh = 0; nh < 2; ++nh) {
        const short* Wh = W1bf + (size_t)nh * 256 * 256;
        f32x4 acc1[2] = {};
#pragma unroll
        for (int u = 0; u < 4; ++u)
            wreg[u] = *(const s16x8*)&Wh[(size_t)(wrow + u * 64) * 256 + wc8];
        for (int k0 = 0; k0 < 256; k0 += 64) {
#pragma unroll
            for (int u = 0; u < 4; ++u)
                *(s16x8*)&Ws[(wrow + u * 64) * WSTR + wc8] = wreg[u];
            __syncthreads();
            int kn = k0 + 64;
            if (kn < 256) {
#pragma unroll
                for (int u = 0; u < 4; ++u)
                    wreg[u] = *(const s16x8*)&Wh[(size_t)(wrow + u * 64) * 256 + kn + wc8];
            }
#pragma unroll
            for (int s = 0; s < 2; ++s) {
                s16x8 af = *(const s16x8*)&h1b[lr * HSTR + k0 + s * 32 + lg * 8];
#pragma unroll
                for (int j = 0; j < 2; ++j) {
                    s16x8 wf = *(const s16x8*)&Ws[(wave * 32 + j * 16 + lr) * WSTR + s * 32 + lg * 8];
                    acc1[j] = __builtin_amdgcn_mfma_f32_16x16x32_bf16(af, wf, acc1[j], 0, 0, 0);
                }
            }
            __syncthreads();
        }
#pragma unroll
        for (int j = 0; j < 2; ++j) {
            int col = nh * 256 + wave * 32 + j * 16 + lr;
            float bv = b1[col];
#pragma unroll
            for (int q = 0; q < 4; ++q)
                Fs[(lg * 4 + q) * FSTR + col] = f2bf(fmaxf(acc1[j][q] + bv, 0.f));
        }
        __syncthreads();
    }

    // ---- phase C: G2 = F @ W2^T + b2  (K=512, 8 iters, prefetched)
    f32x4 acc2[2] = {};
#pragma unroll
    for (int u = 0; u < 4; ++u)
        wreg[u] = *(const s16x8*)&W2bf[(size_t)(wrow + u * 64) * 512 + wc8];
    for (int k0 = 0; k0 < 512; k0 += 64) {
#pragma unroll
        for (int u = 0; u < 4; ++u)
            *(s16x8*)&Ws[(wrow + u * 64) * WSTR + wc8] = wreg[u];
        __syncthreads();
        int kn = k0 + 64;
        if (kn < 512) {
#pragma unroll
            for (int u = 0; u < 4; ++u)
                wreg[u] = *(const s16x8*)&W2bf[(size_t)(wrow + u * 64) * 512 + kn + wc8];
        }
#pragma unroll
        for (int s = 0; s < 2; ++s) {
            s16x8 af = *(const s16x8*)&Fs[lr * FSTR + k0 + s * 32 + lg * 8];
#pragma unroll
            for (int j = 0; j < 2; ++j) {
                s16x8 wf = *(const s16x8*)&Ws[(wave * 32 + j * 16 + lr) * WSTR + s * 32 + lg * 8];
                acc2[j] = __builtin_amdgcn_mfma_f32_16x16x32_bf16(af, wf, acc2[j], 0, 0, 0);
            }
        }
        __syncthreads();
    }
#pragma unroll
    for (int j = 0; j < 2; ++j) {
        int col = wave * 32 + j * 16 + lr;
        float bv = b2[col];
#pragma unroll
        for (int q = 0; q < 4; ++q)
            G2[lg * 4 + q][col] = acc2[j][q] + bv;
    }
    __syncthreads();

    // ---- LN2: H = LN(h1 + G2)
    for (int rr = 0; rr < 2; ++rr) {
        int row = wave * 2 + rr;
        size_t base = (size_t)(m0 + row) * D_;
        float x[4];
        float s = 0.f;
#pragma unroll
        for (int i = 0; i < 4; ++i) {
            int idx = i * 64 + lane;
            x[i] = Gf[row][idx] + G2[row][idx];
            s += x[i];
        }
#pragma unroll
        for (int off = 32; off; off >>= 1) s += __shfl_xor(s, off);
        float mu = s * (1.f / D_);
        float ss = 0.f;
#pragma unroll
        for (int i = 0; i < 4; ++i) { float d = x[i] - mu; ss += d * d; }
#pragma unroll
        for (int off = 32; off; off >>= 1) ss += __shfl_xor(ss, off);
        float rstd = rsqrtf(ss * (1.f / D_) + 1e-5f);
#pragma unroll
        for (int i = 0; i < 4; ++i) {
            int idx = i * 64 + lane;
            H[base + idx] = (x[i] - mu) * rstd * ln2w[idx] + ln2b[idx];
        }
    }
}

// ---------------- MFMA banded attention (bf16 in, bf16 out)
__global__ __launch_bounds__(256) void attn_mfma(
    const short* __restrict__ qkv, short* __restrict__ out) {
    int q0 = blockIdx.x * 64;
    int h = blockIdx.y, b = blockIdx.z;
    int tid = threadIdx.x;
    int wave = tid >> 6, lane = tid & 63;
    int lg = lane >> 4;
    int lr = lane & 15;
    const int j0 = q0 - 64;

    __shared__ short Qs[64][40];
    __shared__ short Ks[128][40];
    __shared__ short Vt[32][PSTR];
    __shared__ short Ps[64][PSTR];

#pragma unroll
    for (int u = 0; u < 2; ++u) {
        int task = tid + 256 * u;
        int r = task >> 3, c = (task & 7) * 4;
        *(s16x4*)&Qs[r][c] =
            *(const s16x4*)&qkv[((size_t)(b * T_ + q0 + r)) * 768 + h * 32 + c];
    }
#pragma unroll
    for (int u = 0; u < 4; ++u) {
        int task = tid + 256 * u;
        int r = task >> 3, c = (task & 7) * 4;
        int jg = j0 + r;
        s16x4 sa = {0, 0, 0, 0};
        if (jg >= 0)
            sa = *(const s16x4*)&qkv[((size_t)(b * T_ + jg)) * 768 + 256 + h * 32 + c];
        *(s16x4*)&Ks[r][c] = sa;
    }
#pragma unroll
    for (int u = 0; u < 4; ++u) {
        int task = tid + 256 * u;
        int r = task >> 3, c = (task & 7) * 4;
        int jg = j0 + r;
        s16x4 v4 = {0, 0, 0, 0};
        if (jg >= 0)
            v4 = *(const s16x4*)&qkv[((size_t)(b * T_ + jg)) * 768 + 512 + h * 32 + c];
        Vt[c + 0][r] = v4[0];
        Vt[c + 1][r] = v4[1];
        Vt[c + 2][r] = v4[2];
        Vt[c + 3][r] = v4[3];
    }
    __syncthreads();

    s16x8 aq = *(const s16x8*)&Qs[16 * wave + lr][lg * 8];
    f32x4 sacc[8];
#pragma unroll
    for (int j = 0; j < 8; ++j) {
        s16x8 bk = *(const s16x8*)&Ks[16 * j + lr][lg * 8];
        f32x4 z = {0.f, 0.f, 0.f, 0.f};
        sacc[j] = __builtin_amdgcn_mfma_f32_16x16x32_bf16(aq, bk, z, 0, 0, 0);
    }

    const float scale = 0.17677669529663687f;
#pragma unroll
    for (int j = 0; j < 8; ++j) {
        int jg = j0 + 16 * j + lr;
#pragma unroll
        for (int q = 0; q < 4; ++q) {
            int qi = q0 + 16 * wave + lg * 4 + q;
            bool ok = ((jg >= qi - WIN_) && (jg < qi) && (jg >= 0)) || (qi == 0 && jg == 0);
            sacc[j][q] = ok ? sacc[j][q] * scale : -1e30f;
        }
    }
#pragma unroll
    for (int q = 0; q < 4; ++q) {
        float m = sacc[0][q];
#pragma unroll
        for (int j = 1; j < 8; ++j) m = fmaxf(m, sacc[j][q]);
#pragma unroll
        for (int off = 1; off < 16; off <<= 1) m = fmaxf(m, __shfl_xor(m, off));
        float e[8], sum = 0.f;
#pragma unroll
        for (int j = 0; j < 8; ++j) { e[j] = __expf(sacc[j][q] - m); sum += e[j]; }
#pragma unroll
        for (int off = 1; off < 16; off <<= 1) sum += __shfl_xor(sum, off);
        float inv = 1.f / sum;
        int row = 16 * wave + lg * 4 + q;
#pragma unroll
        for (int j = 0; j < 8; ++j) Ps[row][16 * j + lr] = f2bf(e[j] * inv);
    }

    f32x4 oacc[2] = {};
#pragma unroll
    for (int kk = 0; kk < 4; ++kk) {
        s16x8 ap = *(const s16x8*)&Ps[16 * wave + lr][kk * 32 + lg * 8];
#pragma unroll
        for (int n = 0; n < 2; ++n) {
            s16x8 bv = *(const s16x8*)&Vt[16 * n + lr][kk * 32 + lg * 8];
            oacc[n] = __builtin_amdgcn_mfma_f32_16x16x32_bf16(ap, bv, oacc[n], 0, 0, 0);
        }
    }
#pragma unroll
    for (int n = 0; n < 2; ++n)
#pragma unroll
        for (int q = 0; q < 4; ++q) {
            int qi = q0 + 16 * wave + lg * 4 + q;
            out[((size_t)(b * T_ + qi)) * D_ + h * 32 + 16 * n + lr] = f2bf(oacc[n][q]);
        }
}

// ---------------- LN2d apply + ReLU (float4); stats reduced from part2 in-kernel
__global__ __launch_bounds__(256) void ln2d_apply(
    const float* __restrict__ x, const float* __restrict__ w,
    const float* __restrict__ bb, const float* __restrict__ part2,
    float* __restrict__ y, int CT, int npart) {
    int b = blockIdx.y;
    int tid = threadIdx.x;
    __shared__ float sstat[2];
    if (tid < 64) {
        float s = 0.f, ss = 0.f;
        const float2* p2 = (const float2*)part2 + (size_t)b * npart;
        for (int i = tid; i < npart; i += 64) { float2 v = p2[i]; s += v.x; ss += v.y; }
#pragma unroll
        for (int off = 32; off; off >>= 1) {
            s += __shfl_xor(s, off);
            ss += __shfl_xor(ss, off);
        }
        if (tid == 0) {
            float mu = s / (float)CT;
            sstat[0] = mu;
            sstat[1] = rsqrtf(ss / (float)CT - mu * mu + 1e-5f);
        }
    }
    __syncthreads();
    float mu = sstat[0], rstd = sstat[1];
    int idx = blockIdx.x * 256 + tid;
    const float4* x4 = (const float4*)(x + (size_t)b * CT);
    const float4* w4 = (const float4*)w;
    const float4* b4 = (const float4*)bb;
    float4* y4 = (float4*)(y + (size_t)b * CT);
    float4 v = x4[idx], wv = w4[idx], bv = b4[idx];
    float4 r;
    r.x = fmaxf((v.x - mu) * rstd * wv.x + bv.x, 0.f);
    r.y = fmaxf((v.y - mu) * rstd * wv.y + bv.y, 0.f);
    r.z = fmaxf((v.z - mu) * rstd * wv.z + bv.z, 0.f);
    r.w = fmaxf((v.w - mu) * rstd * wv.w + bv.w, 0.f);
    y4[idx] = r;
}

// ---------------- LN2d apply + ReLU + transpose + pos add: [B,D,T] -> [B,T,D]
__global__ __launch_bounds__(256) void ln2d_apply_t(
    const float* __restrict__ x, const float* __restrict__ w,
    const float* __restrict__ bb, const float* __restrict__ part2,
    const float* __restrict__ pos, float* __restrict__ h, int npart) {
    int t0 = blockIdx.x * 32;
    int d0 = blockIdx.y * 32;
    int b = blockIdx.z;
    int tid = threadIdx.x;
    __shared__ float sstat[2];
    if (tid < 64) {
        float s = 0.f, ss = 0.f;
        const float2* p2 = (const float2*)part2 + (size_t)b * npart;
        for (int i = tid; i < npart; i += 64) { float2 v = p2[i]; s += v.x; ss += v.y; }
#pragma unroll
        for (int off = 32; off; off >>= 1) {
            s += __shfl_xor(s, off);
            ss += __shfl_xor(ss, off);
        }
        if (tid == 0) {
            float mu = s / (float)(D_ * T_);
            sstat[0] = mu;
            sstat[1] = rsqrtf(ss / (float)(D_ * T_) - mu * mu + 1e-5f);
        }
    }
    __syncthreads();
    float mu = sstat[0], rstd = sstat[1];
    __shared__ float xs[32][33];
    int tt = tid & 31, dd = tid >> 5;
#pragma unroll
    for (int p = 0; p < 4; ++p) {
        int d = d0 + dd + p * 8;
        size_t off = ((size_t)b * D_ + d) * T_ + t0 + tt;
        size_t woff = (size_t)d * T_ + t0 + tt;
        float v = (x[off] - mu) * rstd * w[woff] + bb[woff];
        xs[dd + p * 8][tt] = fmaxf(v, 0.f);
    }
    __syncthreads();
    int dd2 = tid & 31, tt2 = tid >> 5;
#pragma unroll
    for (int p = 0; p < 4; ++p) {
        int t = t0 + tt2 + p * 8;
        h[((size_t)(b * T_ + t)) * D_ + d0 + dd2] =
            xs[dd2][tt2 + p * 8] + pos[(size_t)t * D_ + d0 + dd2];
    }
}

extern "C" void kernel_launch(void* const* d_in, const int* in_sizes, int n_in,
                              void* d_out, int out_size, void* d_ws, size_t ws_size,
                              hipStream_t stream) {
    const float* x        = (const float*)d_in[0];
    const float* pre_w0   = (const float*)d_in[1];
    const float* pre_b0   = (const float*)d_in[2];
    const float* pre_lnw0 = (const float*)d_in[3];
    const float* pre_lnb0 = (const float*)d_in[4];
    const float* pre_w1   = (const float*)d_in[5];
    const float* pre_b1   = (const float*)d_in[6];
    const float* pre_lnw1 = (const float*)d_in[7];
    const float* pre_lnb1 = (const float*)d_in[8];
    const float* pos_emb  = (const float*)d_in[9];
    const float* Wqkv     = (const float*)d_in[10];
    const float* bqkv     = (const float*)d_in[11];
    const float* Wo       = (const float*)d_in[12];
    const float* bo       = (const float*)d_in[13];
    const float* ln1w     = (const float*)d_in[14];
    const float* ln1b     = (const float*)d_in[15];
    const float* W1       = (const float*)d_in[16];
    const float* b1       = (const float*)d_in[17];
    const float* W2       = (const float*)d_in[18];
    const float* b2       = (const float*)d_in[19];
    const float* ln2w     = (const float*)d_in[20];
    const float* ln2b     = (const float*)d_in[21];
    const float* post_w0  = (const float*)d_in[22];
    const float* post_b0  = (const float*)d_in[23];
    const float* post_lnw0= (const float*)d_in[24];
    const float* post_lnb0= (const float*)d_in[25];
    const float* post_w1  = (const float*)d_in[26];
    const float* post_b1  = (const float*)d_in[27];
    const float* post_lnw1= (const float*)d_in[28];
    const float* post_lnb1= (const float*)d_in[29];

    float* ws = (float*)d_ws;
    const size_t M1 = 1u << 20;              // 1M floats
    float* H     = ws;                       // [B,T,D] fp32
    float* A0    = ws + 1 * M1;              // [B,D,T] fp32 (pre/post only)
    float* A1    = ws + 2 * M1;              // [B,D,T] fp32 (pre/post only)
    short* QKVb  = (short*)(ws + 1 * M1);    // [B,T,768] bf16 (aliases A0/A1)
    short* ATTb  = (short*)(ws + 5 * M1);    // [B,T,256] bf16
    short* wbf   = (short*)(ws + 6 * M1);    // transformer weights bf16
    short* wqkv_bf = wbf;
    short* wo_bf   = wbf + 786432;
    short* w1_bf   = wbf + 1048576;
    short* w2_bf   = wbf + 1572864;
    short* cwbf  = wbf + 2097152;            // conv weights reordered
    short* cw_pre0  = cwbf;                  // [256][3*128]
    short* cw_pre1  = cwbf + 98304;          // [256][3*256]
    short* cw_post0 = cwbf + 294912;         // [256][3*256]
    short* cw_post1 = cwbf + 491520;         // [128][3*256]
    float* part2 = ws + 8 * M1;              // up to 4*256*2 floats

    const int M = B_ * T_;  // 4096

    // ---- one-time weight prep
    prep_w<<<2048, 256, 0, stream>>>(Wqkv, Wo, W1, W2,
                                     pre_w0, pre_w1, post_w0, post_w1, wbf);

    // ---- pre stage
    gemm_conv16<128, 0><<<dim3(D_ / 64, M / 16), 256, 0, stream>>>(
        x, cw_pre0, pre_b0, A0, D_, part2);
    ln2d_apply<<<dim3(D_ * T_ / 1024, B_), 256, 0, stream>>>(
        A0, pre_lnw0, pre_lnb0, part2, A1, D_ * T_, 256);
    gemm_conv16<256, 0><<<dim3(D_ / 64, M / 16), 256, 0, stream>>>(
        A1, cw_pre1, pre_b1, A0, D_, part2);
    ln2d_apply_t<<<dim3(T_ / 32, D_ / 32, B_), 256, 0, stream>>>(
        A0, pre_lnw1, pre_lnb1, part2, pos_emb, H, 256);

    // ---- transformer layers (3 dispatches each)
    for (int l = 0; l < L_; ++l) {
        gemm64w<0, 1><<<dim3(768 / 64, M / 64), 256, 0, stream>>>(
            H, wqkv_bf + (size_t)l * 196608, bqkv + (size_t)l * 768, QKVb, M, 768, D_);
        attn_mfma<<<dim3(T_ / 64, H_, B_), 256, 0, stream>>>(QKVb, ATTb);
        layer_tail<<<M / 16, 512, 0, stream>>>(
            ATTb, wo_bf + (size_t)l * 65536, bo + (size_t)l * D_,
            w1_bf + (size_t)l * 131072, b1 + (size_t)l * DFF_,
            w2_bf + (size_t)l * 131072, b2 + (size_t)l * D_, H,
            ln1w + (size_t)l * D_, ln1b + (size_t)l * D_,
            ln2w + (size_t)l * D_, ln2b + (size_t)l * D_);
    }

    // ---- post stage
    gemm_conv16<256, 1><<<dim3(D_ / 64, M / 16), 256, 0, stream>>>(
        H, cw_post0, post_b0, A1, D_, part2);
    ln2d_apply<<<dim3(D_ * T_ / 1024, B_), 256, 0, stream>>>(
        A1, post_lnw0, post_lnb0, part2, A0, D_ * T_, 256);
    gemm_conv16<256, 0><<<dim3(CIN_ / 64, M / 16), 256, 0, stream>>>(
        A0, cw_post1, post_b1, A1, CIN_, part2);
    ln2d_apply<<<dim3(CIN_ * T_ / 1024, B_), 256, 0, stream>>>(
        A1, post_lnw1, post_lnb1, part2, (float*)d_out, CIN_ * T_, 128);
}

// Round 18
// 221.303 us; speedup vs baseline: 10.4259x; 1.0606x over previous
//
#include <hip/hip_runtime.h>
#include <hip/hip_bf16.h>

#define B_ 4
#define T_ 1024
#define D_ 256
#define H_ 8
#define WIN_ 64
#define CIN_ 128
#define DH_ 32
#define DFF_ 512
#define L_ 4
#define PSTR 152 // attn Ps/Vt LDS row stride (shorts)
#define FSTR 520 // ffn F-tile LDS row stride (shorts)
#define HSTR 264 // h1 bf16 LDS row stride (shorts)
#define WSTR 72  // BK=64 weight/A tile row stride (shorts)

typedef __attribute__((ext_vector_type(4))) short s16x4;
typedef __attribute__((ext_vector_type(8))) short s16x8;
typedef __attribute__((ext_vector_type(4))) float f32x4;

__device__ inline short f2bf(float f) {
    __hip_bfloat16 h = __float2bfloat16(f);
    return *reinterpret_cast<short*>(&h);
}

// ---------------- one-time weight prep
__global__ __launch_bounds__(256) void prep_w(
    const float* __restrict__ wqkv, const float* __restrict__ wo,
    const float* __restrict__ w1, const float* __restrict__ w2,
    const float* __restrict__ pw0, const float* __restrict__ pw1,
    const float* __restrict__ qw0, const float* __restrict__ qw1,
    short* __restrict__ dst) {
    const int N0 = 786432, N1 = 1048576, N2 = 1572864, NT = 2097152;
    const int NTOT = 2686976;
    for (int i = blockIdx.x * 256 + threadIdx.x; i < NTOT; i += gridDim.x * 256) {
        float v;
        if (i < NT) {
            if (i < N0) v = wqkv[i];
            else if (i < N1) v = wo[i - N0];
            else if (i < N2) v = w1[i - N1];
            else v = w2[i - N2];
        } else {
            int j = i - NT;
            const float* src;
            int I;
            if (j < 98304)       { src = pw0; I = 128; }
            else if (j < 294912) { src = pw1; I = 256; j -= 98304; }
            else if (j < 491520) { src = qw0; I = 256; j -= 294912; }
            else                 { src = qw1; I = 256; j -= 491520; }
            int o = j / (3 * I);
            int rem = j - o * 3 * I;
            int k = rem / I, ii = rem - k * I;
            v = src[(size_t)(o * I + ii) * 3 + k];
        }
        dst[i] = f2bf(v);
    }
}

// ---------------- fused im2col + conv-GEMM + LN2d-partial, 16x64 tile, BK=64,
// register-prefetched (T14)
template <int I_, int BTD>
__global__ __launch_bounds__(256) void gemm_conv16(
    const float* __restrict__ x, const short* __restrict__ Wr,
    const float* __restrict__ bias, float* __restrict__ Y, int O,
    float* __restrict__ part2) {
    const int K = 3 * I_;
    __shared__ short Al[16 * WSTR];
    __shared__ short Wl[64 * WSTR];
    __shared__ float sh[8];
    int tid = threadIdx.x;
    int col0 = blockIdx.x * 64;
    int row0 = blockIdx.y * 16;
    int b = row0 >> 10, t0 = row0 & 1023;
    int wave = tid >> 6, lane = tid & 63;
    int lg = lane >> 4, lr = lane & 15;
    f32x4 acc = {0.f, 0.f, 0.f, 0.f};

    float areg[4];
    s16x4 wreg[4];

    // prologue: chunk 0
    {
        int k = 0, i0 = 0;
#pragma unroll
        for (int p = 0; p < 4; ++p) {
            int e = p * 256 + tid;
            int rr, cc;
            if (BTD) { rr = e >> 6; cc = e & 63; }
            else     { cc = e >> 4; rr = e & 15; }
            int tg = t0 + rr - 1 + k;
            areg[p] = (tg >= 0 && tg < T_)
                          ? (BTD ? x[((size_t)(b * T_ + tg)) * I_ + i0 + cc]
                                 : x[((size_t)(b * I_ + i0 + cc)) * T_ + tg])
                          : 0.f;
        }
#pragma unroll
        for (int p = 0; p < 4; ++p) {
            int e = p * 256 + tid;
            int rr = e >> 4, c4 = (e & 15) * 4;
            wreg[p] = *(const s16x4*)&Wr[(size_t)(col0 + rr) * K + c4];
        }
    }

    for (int k0 = 0; k0 < K; k0 += 64) {
#pragma unroll
        for (int p = 0; p < 4; ++p) {
            int e = p * 256 + tid;
            int rr, cc;
            if (BTD) { rr = e >> 6; cc = e & 63; }
            else     { cc = e >> 4; rr = e & 15; }
            Al[rr * WSTR + cc] = f2bf(areg[p]);
        }
#pragma unroll
        for (int p = 0; p < 4; ++p) {
            int e = p * 256 + tid;
            int rr = e >> 4, c4 = (e & 15) * 4;
            *(s16x4*)&Wl[rr * WSTR + c4] = wreg[p];
        }
        __syncthreads();
        int kn = k0 + 64;
        if (kn < K) {
            int k = kn / I_;
            int i0 = kn - k * I_;
#pragma unroll
            for (int p = 0; p < 4; ++p) {
                int e = p * 256 + tid;
                int rr, cc;
                if (BTD) { rr = e >> 6; cc = e & 63; }
                else     { cc = e >> 4; rr = e & 15; }
                int tg = t0 + rr - 1 + k;
                areg[p] = (tg >= 0 && tg < T_)
                              ? (BTD ? x[((size_t)(b * T_ + tg)) * I_ + i0 + cc]
                                     : x[((size_t)(b * I_ + i0 + cc)) * T_ + tg])
                              : 0.f;
            }
#pragma unroll
            for (int p = 0; p < 4; ++p) {
                int e = p * 256 + tid;
                int rr = e >> 4, c4 = (e & 15) * 4;
                wreg[p] = *(const s16x4*)&Wr[(size_t)(col0 + rr) * K + kn + c4];
            }
        }
        s16x8 af0 = *(const s16x8*)&Al[lr * WSTR + lg * 8];
        s16x8 af1 = *(const s16x8*)&Al[lr * WSTR + 32 + lg * 8];
        s16x8 wf0 = *(const s16x8*)&Wl[(wave * 16 + lr) * WSTR + lg * 8];
        s16x8 wf1 = *(const s16x8*)&Wl[(wave * 16 + lr) * WSTR + 32 + lg * 8];
        acc = __builtin_amdgcn_mfma_f32_16x16x32_bf16(af0, wf0, acc, 0, 0, 0);
        acc = __builtin_amdgcn_mfma_f32_16x16x32_bf16(af1, wf1, acc, 0, 0, 0);
        __syncthreads();
    }

    int cg = col0 + wave * 16 + lr;
    float bv = bias[cg];
    float4 o;
    o.x = acc[0] + bv; o.y = acc[1] + bv; o.z = acc[2] + bv; o.w = acc[3] + bv;
    *(float4*)&Y[((size_t)(b * O + cg)) * 1024 + t0 + lg * 4] = o;

    float s = o.x + o.y + o.z + o.w;
    float ss = o.x * o.x + o.y * o.y + o.z * o.z + o.w * o.w;
#pragma unroll
    for (int off = 32; off; off >>= 1) {
        s += __shfl_xor(s, off);
        ss += __shfl_xor(ss, off);
    }
    if (lane == 0) { sh[wave * 2] = s; sh[wave * 2 + 1] = ss; }
    __syncthreads();
    if (tid == 0) {
        float ts = sh[0] + sh[2] + sh[4] + sh[6];
        float tss = sh[1] + sh[3] + sh[5] + sh[7];
        int slot = b * (gridDim.x * 64) + blockIdx.x * 64 + (blockIdx.y & 63);
        part2[slot * 2] = ts;
        part2[slot * 2 + 1] = tss;
    }
}

// ---------------- bf16-weight MFMA GEMM (QKV), 64x64 tile, BK=64, prefetched
template <int RELU, int BF16OUT>
__global__ __launch_bounds__(256) void gemm64w(
    const float* __restrict__ A, const short* __restrict__ Wbf,
    const float* __restrict__ bias, void* __restrict__ Yv,
    int M, int N, int K) {
    __shared__ short Al[64 * WSTR];
    __shared__ short Wl[64 * WSTR];
    int tid = threadIdx.x;
    int row0 = blockIdx.y * 64, col0 = blockIdx.x * 64;
    int wave = tid >> 6, lane = tid & 63;
    int wr = wave >> 1, wc = wave & 1;
    int lg = lane >> 4, lr = lane & 15;
    f32x4 acc[2][2] = {};

    float4 areg[4];
    s16x4 wreg[4];
#pragma unroll
    for (int p = 0; p < 4; ++p) {
        int e = p * 256 + tid;
        int rr = e >> 4, c4 = (e & 15) * 4;
        areg[p] = *(const float4*)&A[(size_t)(row0 + rr) * K + c4];
        wreg[p] = *(const s16x4*)&Wbf[(size_t)(col0 + rr) * K + c4];
    }

    for (int k0 = 0; k0 < K; k0 += 64) {
#pragma unroll
        for (int p = 0; p < 4; ++p) {
            int e = p * 256 + tid;
            int rr = e >> 4, c4 = (e & 15) * 4;
            s16x4 sa;
            sa[0] = f2bf(areg[p].x); sa[1] = f2bf(areg[p].y);
            sa[2] = f2bf(areg[p].z); sa[3] = f2bf(areg[p].w);
            *(s16x4*)&Al[rr * WSTR + c4] = sa;
            *(s16x4*)&Wl[rr * WSTR + c4] = wreg[p];
        }
        __syncthreads();
        int kn = k0 + 64;
        if (kn < K) {
#pragma unroll
            for (int p = 0; p < 4; ++p) {
                int e = p * 256 + tid;
                int rr = e >> 4, c4 = (e & 15) * 4;
                areg[p] = *(const float4*)&A[(size_t)(row0 + rr) * K + kn + c4];
                wreg[p] = *(const s16x4*)&Wbf[(size_t)(col0 + rr) * K + kn + c4];
            }
        }
#pragma unroll
        for (int s = 0; s < 2; ++s) {
            s16x8 af[2], wf[2];
#pragma unroll
            for (int i = 0; i < 2; ++i) {
                af[i] = *(const s16x8*)&Al[(wr * 32 + i * 16 + lr) * WSTR + s * 32 + lg * 8];
                wf[i] = *(const s16x8*)&Wl[(wc * 32 + i * 16 + lr) * WSTR + s * 32 + lg * 8];
            }
#pragma unroll
            for (int i = 0; i < 2; ++i)
#pragma unroll
                for (int j = 0; j < 2; ++j)
                    acc[i][j] = __builtin_amdgcn_mfma_f32_16x16x32_bf16(af[i], wf[j], acc[i][j], 0, 0, 0);
        }
        __syncthreads();
    }
#pragma unroll
    for (int i = 0; i < 2; ++i) {
        int rg = row0 + wr * 32 + i * 16 + lg * 4;
#pragma unroll
        for (int j = 0; j < 2; ++j) {
            int cg = col0 + wc * 32 + j * 16 + lr;
            float bv = bias[cg];
#pragma unroll
            for (int q = 0; q < 4; ++q) {
                float v = acc[i][j][q] + bv;
                if (RELU) v = fmaxf(v, 0.f);
                if (BF16OUT) ((short*)Yv)[(size_t)(rg + q) * N + cg] = f2bf(v);
                else ((float*)Yv)[(size_t)(rg + q) * N + cg] = v;
            }
        }
    }
}

// ---------------- fused layer tail, BK=64 + register prefetch (T14)
__global__ __launch_bounds__(512) void layer_tail(
    const short* __restrict__ ATTb, const short* __restrict__ Wobf,
    const float* __restrict__ bo, const short* __restrict__ W1bf,
    const float* __restrict__ b1, const short* __restrict__ W2bf,
    const float* __restrict__ b2, float* __restrict__ H,
    const float* __restrict__ ln1w, const float* __restrict__ ln1b,
    const float* __restrict__ ln2w, const float* __restrict__ ln2b) {
    __shared__ short As[16 * WSTR];
    __shared__ short Ws[256 * WSTR];
    __shared__ float Gf[16][260];
    __shared__ short h1b[16 * HSTR];
    __shared__ short Fs[16 * FSTR];
    __shared__ float G2[16][260];
    int tid = threadIdx.x;
    int wave = tid >> 6, lane = tid & 63;
    int lg = lane >> 4, lr = lane & 15;
    int m0 = blockIdx.x * 16;

    int wrow = tid >> 3, wc8 = (tid & 7) * 8;
    int arow = tid >> 4, ac4 = (tid & 15) * 4;

    s16x8 wreg[4];
    s16x4 areg;

    // ---- phase A: G1 = ATT @ Wo^T + bo
    f32x4 accA[2] = {};
    if (tid < 256)
        areg = *(const s16x4*)&ATTb[(size_t)(m0 + arow) * 256 + ac4];
#pragma unroll
    for (int u = 0; u < 4; ++u)
        wreg[u] = *(const s16x8*)&Wobf[(size_t)(wrow + u * 64) * 256 + wc8];
    for (int k0 = 0; k0 < 256; k0 += 64) {
        if (tid < 256) *(s16x4*)&As[arow * WSTR + ac4] = areg;
#pragma unroll
        for (int u = 0; u < 4; ++u)
            *(s16x8*)&Ws[(wrow + u * 64) * WSTR + wc8] = wreg[u];
        __syncthreads();
        int kn = k0 + 64;
        if (kn < 256) {
            if (tid < 256)
                areg = *(const s16x4*)&ATTb[(size_t)(m0 + arow) * 256 + kn + ac4];
#pragma unroll
            for (int u = 0; u < 4; ++u)
                wreg[u] = *(const s16x8*)&Wobf[(size_t)(wrow + u * 64) * 256 + kn + wc8];
        }
#pragma unroll
        for (int s = 0; s < 2; ++s) {
            s16x8 af = *(const s16x8*)&As[lr * WSTR + s * 32 + lg * 8];
#pragma unroll
            for (int j = 0; j < 2; ++j) {
                s16x8 wf = *(const s16x8*)&Ws[(wave * 32 + j * 16 + lr) * WSTR + s * 32 + lg * 8];
                accA[j] = __builtin_amdgcn_mfma_f32_16x16x32_bf16(af, wf, accA[j], 0, 0, 0);
            }
        }
        __syncthreads();
    }
#pragma unroll
    for (int j = 0; j < 2; ++j) {
        int col = wave * 32 + j * 16 + lr;
        float bv = bo[col];
#pragma unroll
        for (int q = 0; q < 4; ++q)
            Gf[lg * 4 + q][col] = accA[j][q] + bv;
    }
    __syncthreads();

    // ---- LN1
    for (int rr = 0; rr < 2; ++rr) {
        int row = wave * 2 + rr;
        size_t base = (size_t)(m0 + row) * D_;
        float x[4];
        float s = 0.f;
#pragma unroll
        for (int i = 0; i < 4; ++i) {
            int idx = i * 64 + lane;
            x[i] = H[base + idx] + Gf[row][idx];
            s += x[i];
        }
#pragma unroll
        for (int off = 32; off; off >>= 1) s += __shfl_xor(s, off);
        float mu = s * (1.f / D_);
        float ss = 0.f;
#pragma unroll
        for (int i = 0; i < 4; ++i) { float d = x[i] - mu; ss += d * d; }
#pragma unroll
        for (int off = 32; off; off >>= 1) ss += __shfl_xor(ss, off);
        float rstd = rsqrtf(ss * (1.f / D_) + 1e-5f);
#pragma unroll
        for (int i = 0; i < 4; ++i) {
            int idx = i * 64 + lane;
            float h1v = (x[i] - mu) * rstd * ln1w[idx] + ln1b[idx];
            Gf[row][idx] = h1v;
            h1b[row * HSTR + idx] = f2bf(h1v);
        }
    }
    __syncthreads();

    // ---- phase B: F = relu(h1 @ W1^T + b1)
    for (int nh = 0; nh < 2; ++nh) {
        const short* Wh = W1bf + (size_t)nh * 256 * 256;
        f32x4 acc1[2] = {};
#pragma unroll
        for (int u = 0; u < 4; ++u)
            wreg[u] = *(const s16x8*)&Wh[(size_t)(wrow + u * 64) * 256 + wc8];
        for (int k0 = 0; k0 < 256; k0 += 64) {
#pragma unroll
            for (int u = 0; u < 4; ++u)
                *(s16x8*)&Ws[(wrow + u * 64) * WSTR + wc8] = wreg[u];
            __syncthreads();
            int kn = k0 + 64;
            if (kn < 256) {
#pragma unroll
                for (int u = 0; u < 4; ++u)
                    wreg[u] = *(const s16x8*)&Wh[(size_t)(wrow + u * 64) * 256 + kn + wc8];
            }
#pragma unroll
            for (int s = 0; s < 2; ++s) {
                s16x8 af = *(const s16x8*)&h1b[lr * HSTR + k0 + s * 32 + lg * 8];
#pragma unroll
                for (int j = 0; j < 2; ++j) {
                    s16x8 wf = *(const s16x8*)&Ws[(wave * 32 + j * 16 + lr) * WSTR + s * 32 + lg * 8];
                    acc1[j] = __builtin_amdgcn_mfma_f32_16x16x32_bf16(af, wf, acc1[j], 0, 0, 0);
                }
            }
            __syncthreads();
        }
#pragma unroll
        for (int j = 0; j < 2; ++j) {
            int col = nh * 256 + wave * 32 + j * 16 + lr;
            float bv = b1[col];
#pragma unroll
            for (int q = 0; q < 4; ++q)
                Fs[(lg * 4 + q) * FSTR + col] = f2bf(fmaxf(acc1[j][q] + bv, 0.f));
        }
        __syncthreads();
    }

    // ---- phase C: G2 = F @ W2^T + b2
    f32x4 acc2[2] = {};
#pragma unroll
    for (int u = 0; u < 4; ++u)
        wreg[u] = *(const s16x8*)&W2bf[(size_t)(wrow + u * 64) * 512 + wc8];
    for (int k0 = 0; k0 < 512; k0 += 64) {
#pragma unroll
        for (int u = 0; u < 4; ++u)
            *(s16x8*)&Ws[(wrow + u * 64) * WSTR + wc8] = wreg[u];
        __syncthreads();
        int kn = k0 + 64;
        if (kn < 512) {
#pragma unroll
            for (int u = 0; u < 4; ++u)
                wreg[u] = *(const s16x8*)&W2bf[(size_t)(wrow + u * 64) * 512 + kn + wc8];
        }
#pragma unroll
        for (int s = 0; s < 2; ++s) {
            s16x8 af = *(const s16x8*)&Fs[lr * FSTR + k0 + s * 32 + lg * 8];
#pragma unroll
            for (int j = 0; j < 2; ++j) {
                s16x8 wf = *(const s16x8*)&Ws[(wave * 32 + j * 16 + lr) * WSTR + s * 32 + lg * 8];
                acc2[j] = __builtin_amdgcn_mfma_f32_16x16x32_bf16(af, wf, acc2[j], 0, 0, 0);
            }
        }
        __syncthreads();
    }
#pragma unroll
    for (int j = 0; j < 2; ++j) {
        int col = wave * 32 + j * 16 + lr;
        float bv = b2[col];
#pragma unroll
        for (int q = 0; q < 4; ++q)
            G2[lg * 4 + q][col] = acc2[j][q] + bv;
    }
    __syncthreads();

    // ---- LN2
    for (int rr = 0; rr < 2; ++rr) {
        int row = wave * 2 + rr;
        size_t base = (size_t)(m0 + row) * D_;
        float x[4];
        float s = 0.f;
#pragma unroll
        for (int i = 0; i < 4; ++i) {
            int idx = i * 64 + lane;
            x[i] = Gf[row][idx] + G2[row][idx];
            s += x[i];
        }
#pragma unroll
        for (int off = 32; off; off >>= 1) s += __shfl_xor(s, off);
        float mu = s * (1.f / D_);
        float ss = 0.f;
#pragma unroll
        for (int i = 0; i < 4; ++i) { float d = x[i] - mu; ss += d * d; }
#pragma unroll
        for (int off = 32; off; off >>= 1) ss += __shfl_xor(ss, off);
        float rstd = rsqrtf(ss * (1.f / D_) + 1e-5f);
#pragma unroll
        for (int i = 0; i < 4; ++i) {
            int idx = i * 64 + lane;
            H[base + idx] = (x[i] - mu) * rstd * ln2w[idx] + ln2b[idx];
        }
    }
}

// ---------------- MFMA banded attention (bf16 in, bf16 out)
__global__ __launch_bounds__(256) void attn_mfma(
    const short* __restrict__ qkv, short* __restrict__ out) {
    int q0 = blockIdx.x * 64;
    int h = blockIdx.y, b = blockIdx.z;
    int tid = threadIdx.x;
    int wave = tid >> 6, lane = tid & 63;
    int lg = lane >> 4;
    int lr = lane & 15;
    const int j0 = q0 - 64;

    __shared__ short Qs[64][40];
    __shared__ short Ks[128][40];
    __shared__ short Vt[32][PSTR];
    __shared__ short Ps[64][PSTR];

#pragma unroll
    for (int u = 0; u < 2; ++u) {
        int task = tid + 256 * u;
        int r = task >> 3, c = (task & 7) * 4;
        *(s16x4*)&Qs[r][c] =
            *(const s16x4*)&qkv[((size_t)(b * T_ + q0 + r)) * 768 + h * 32 + c];
    }
#pragma unroll
    for (int u = 0; u < 4; ++u) {
        int task = tid + 256 * u;
        int r = task >> 3, c = (task & 7) * 4;
        int jg = j0 + r;
        s16x4 sa = {0, 0, 0, 0};
        if (jg >= 0)
            sa = *(const s16x4*)&qkv[((size_t)(b * T_ + jg)) * 768 + 256 + h * 32 + c];
        *(s16x4*)&Ks[r][c] = sa;
    }
#pragma unroll
    for (int u = 0; u < 4; ++u) {
        int task = tid + 256 * u;
        int r = task >> 3, c = (task & 7) * 4;
        int jg = j0 + r;
        s16x4 v4 = {0, 0, 0, 0};
        if (jg >= 0)
            v4 = *(const s16x4*)&qkv[((size_t)(b * T_ + jg)) * 768 + 512 + h * 32 + c];
        Vt[c + 0][r] = v4[0];
        Vt[c + 1][r] = v4[1];
        Vt[c + 2][r] = v4[2];
        Vt[c + 3][r] = v4[3];
    }
    __syncthreads();

    s16x8 aq = *(const s16x8*)&Qs[16 * wave + lr][lg * 8];
    f32x4 sacc[8];
#pragma unroll
    for (int j = 0; j < 8; ++j) {
        s16x8 bk = *(const s16x8*)&Ks[16 * j + lr][lg * 8];
        f32x4 z = {0.f, 0.f, 0.f, 0.f};
        sacc[j] = __builtin_amdgcn_mfma_f32_16x16x32_bf16(aq, bk, z, 0, 0, 0);
    }

    const float scale = 0.17677669529663687f;
#pragma unroll
    for (int j = 0; j < 8; ++j) {
        int jg = j0 + 16 * j + lr;
#pragma unroll
        for (int q = 0; q < 4; ++q) {
            int qi = q0 + 16 * wave + lg * 4 + q;
            bool ok = ((jg >= qi - WIN_) && (jg < qi) && (jg >= 0)) || (qi == 0 && jg == 0);
            sacc[j][q] = ok ? sacc[j][q] * scale : -1e30f;
        }
    }
#pragma unroll
    for (int q = 0; q < 4; ++q) {
        float m = sacc[0][q];
#pragma unroll
        for (int j = 1; j < 8; ++j) m = fmaxf(m, sacc[j][q]);
#pragma unroll
        for (int off = 1; off < 16; off <<= 1) m = fmaxf(m, __shfl_xor(m, off));
        float e[8], sum = 0.f;
#pragma unroll
        for (int j = 0; j < 8; ++j) { e[j] = __expf(sacc[j][q] - m); sum += e[j]; }
#pragma unroll
        for (int off = 1; off < 16; off <<= 1) sum += __shfl_xor(sum, off);
        float inv = 1.f / sum;
        int row = 16 * wave + lg * 4 + q;
#pragma unroll
        for (int j = 0; j < 8; ++j) Ps[row][16 * j + lr] = f2bf(e[j] * inv);
    }

    f32x4 oacc[2] = {};
#pragma unroll
    for (int kk = 0; kk < 4; ++kk) {
        s16x8 ap = *(const s16x8*)&Ps[16 * wave + lr][kk * 32 + lg * 8];
#pragma unroll
        for (int n = 0; n < 2; ++n) {
            s16x8 bv = *(const s16x8*)&Vt[16 * n + lr][kk * 32 + lg * 8];
            oacc[n] = __builtin_amdgcn_mfma_f32_16x16x32_bf16(ap, bv, oacc[n], 0, 0, 0);
        }
    }
#pragma unroll
    for (int n = 0; n < 2; ++n)
#pragma unroll
        for (int q = 0; q < 4; ++q) {
            int qi = q0 + 16 * wave + lg * 4 + q;
            out[((size_t)(b * T_ + qi)) * D_ + h * 32 + 16 * n + lr] = f2bf(oacc[n][q]);
        }
}

// ---------------- LN2d apply + ReLU (float4); stats reduced from part2 in-kernel
__global__ __launch_bounds__(256) void ln2d_apply(
    const float* __restrict__ x, const float* __restrict__ w,
    const float* __restrict__ bb, const float* __restrict__ part2,
    float* __restrict__ y, int CT, int npart) {
    int b = blockIdx.y;
    int tid = threadIdx.x;
    __shared__ float sstat[2];
    if (tid < 64) {
        float s = 0.f, ss = 0.f;
        const float2* p2 = (const float2*)part2 + (size_t)b * npart;
        for (int i = tid; i < npart; i += 64) { float2 v = p2[i]; s += v.x; ss += v.y; }
#pragma unroll
        for (int off = 32; off; off >>= 1) {
            s += __shfl_xor(s, off);
            ss += __shfl_xor(ss, off);
        }
        if (tid == 0) {
            float mu = s / (float)CT;
            sstat[0] = mu;
            sstat[1] = rsqrtf(ss / (float)CT - mu * mu + 1e-5f);
        }
    }
    __syncthreads();
    float mu = sstat[0], rstd = sstat[1];
    int idx = blockIdx.x * 256 + tid;
    const float4* x4 = (const float4*)(x + (size_t)b * CT);
    const float4* w4 = (const float4*)w;
    const float4* b4 = (const float4*)bb;
    float4* y4 = (float4*)(y + (size_t)b * CT);
    float4 v = x4[idx], wv = w4[idx], bv = b4[idx];
    float4 r;
    r.x = fmaxf((v.x - mu) * rstd * wv.x + bv.x, 0.f);
    r.y = fmaxf((v.y - mu) * rstd * wv.y + bv.y, 0.f);
    r.z = fmaxf((v.z - mu) * rstd * wv.z + bv.z, 0.f);
    r.w = fmaxf((v.w - mu) * rstd * wv.w + bv.w, 0.f);
    y4[idx] = r;
}

// ---------------- LN2d apply + ReLU + transpose + pos add: [B,D,T] -> [B,T,D]
__global__ __launch_bounds__(256) void ln2d_apply_t(
    const float* __restrict__ x, const float* __restrict__ w,
    const float* __restrict__ bb, const float* __restrict__ part2,
    const float* __restrict__ pos, float* __restrict__ h, int npart) {
    int t0 = blockIdx.x * 32;
    int d0 = blockIdx.y * 32;
    int b = blockIdx.z;
    int tid = threadIdx.x;
    __shared__ float sstat[2];
    if (tid < 64) {
        float s = 0.f, ss = 0.f;
        const float2* p2 = (const float2*)part2 + (size_t)b * npart;
        for (int i = tid; i < npart; i += 64) { float2 v = p2[i]; s += v.x; ss += v.y; }
#pragma unroll
        for (int off = 32; off; off >>= 1) {
            s += __shfl_xor(s, off);
            ss += __shfl_xor(ss, off);
        }
        if (tid == 0) {
            float mu = s / (float)(D_ * T_);
            sstat[0] = mu;
            sstat[1] = rsqrtf(ss / (float)(D_ * T_) - mu * mu + 1e-5f);
        }
    }
    __syncthreads();
    float mu = sstat[0], rstd = sstat[1];
    __shared__ float xs[32][33];
    int tt = tid & 31, dd = tid >> 5;
#pragma unroll
    for (int p = 0; p < 4; ++p) {
        int d = d0 + dd + p * 8;
        size_t off = ((size_t)b * D_ + d) * T_ + t0 + tt;
        size_t woff = (size_t)d * T_ + t0 + tt;
        float v = (x[off] - mu) * rstd * w[woff] + bb[woff];
        xs[dd + p * 8][tt] = fmaxf(v, 0.f);
    }
    __syncthreads();
    int dd2 = tid & 31, tt2 = tid >> 5;
#pragma unroll
    for (int p = 0; p < 4; ++p) {
        int t = t0 + tt2 + p * 8;
        h[((size_t)(b * T_ + t)) * D_ + d0 + dd2] =
            xs[dd2][tt2 + p * 8] + pos[(size_t)t * D_ + d0 + dd2];
    }
}

extern "C" void kernel_launch(void* const* d_in, const int* in_sizes, int n_in,
                              void* d_out, int out_size, void* d_ws, size_t ws_size,
                              hipStream_t stream) {
    const float* x        = (const float*)d_in[0];
    const float* pre_w0   = (const float*)d_in[1];
    const float* pre_b0   = (const float*)d_in[2];
    const float* pre_lnw0 = (const float*)d_in[3];
    const float* pre_lnb0 = (const float*)d_in[4];
    const float* pre_w1   = (const float*)d_in[5];
    const float* pre_b1   = (const float*)d_in[6];
    const float* pre_lnw1 = (const float*)d_in[7];
    const float* pre_lnb1 = (const float*)d_in[8];
    const float* pos_emb  = (const float*)d_in[9];
    const float* Wqkv     = (const float*)d_in[10];
    const float* bqkv     = (const float*)d_in[11];
    const float* Wo       = (const float*)d_in[12];
    const float* bo       = (const float*)d_in[13];
    const float* ln1w     = (const float*)d_in[14];
    const float* ln1b     = (const float*)d_in[15];
    const float* W1       = (const float*)d_in[16];
    const float* b1       = (const float*)d_in[17];
    const float* W2       = (const float*)d_in[18];
    const float* b2       = (const float*)d_in[19];
    const float* ln2w     = (const float*)d_in[20];
    const float* ln2b     = (const float*)d_in[21];
    const float* post_w0  = (const float*)d_in[22];
    const float* post_b0  = (const float*)d_in[23];
    const float* post_lnw0= (const float*)d_in[24];
    const float* post_lnb0= (const float*)d_in[25];
    const float* post_w1  = (const float*)d_in[26];
    const float* post_b1  = (const float*)d_in[27];
    const float* post_lnw1= (const float*)d_in[28];
    const float* post_lnb1= (const float*)d_in[29];

    float* ws = (float*)d_ws;
    const size_t M1 = 1u << 20;              // 1M floats
    float* H     = ws;                       // [B,T,D] fp32
    float* A0    = ws + 1 * M1;              // [B,D,T] fp32 (pre/post only)
    float* A1    = ws + 2 * M1;              // [B,D,T] fp32 (pre/post only)
    short* QKVb  = (short*)(ws + 1 * M1);    // [B,T,768] bf16 (aliases A0/A1)
    short* ATTb  = (short*)(ws + 5 * M1);    // [B,T,256] bf16
    short* wbf   = (short*)(ws + 6 * M1);    // transformer weights bf16
    short* wqkv_bf = wbf;
    short* wo_bf   = wbf + 786432;
    short* w1_bf   = wbf + 1048576;
    short* w2_bf   = wbf + 1572864;
    short* cwbf  = wbf + 2097152;            // conv weights reordered
    short* cw_pre0  = cwbf;                  // [256][3*128]
    short* cw_pre1  = cwbf + 98304;          // [256][3*256]
    short* cw_post0 = cwbf + 294912;         // [256][3*256]
    short* cw_post1 = cwbf + 491520;         // [128][3*256]
    float* part2 = ws + 8 * M1;              // up to 4*256*2 floats

    const int M = B_ * T_;  // 4096

    // ---- one-time weight prep
    prep_w<<<2048, 256, 0, stream>>>(Wqkv, Wo, W1, W2,
                                     pre_w0, pre_w1, post_w0, post_w1, wbf);

    // ---- pre stage
    gemm_conv16<128, 0><<<dim3(D_ / 64, M / 16), 256, 0, stream>>>(
        x, cw_pre0, pre_b0, A0, D_, part2);
    ln2d_apply<<<dim3(D_ * T_ / 1024, B_), 256, 0, stream>>>(
        A0, pre_lnw0, pre_lnb0, part2, A1, D_ * T_, 256);
    gemm_conv16<256, 0><<<dim3(D_ / 64, M / 16), 256, 0, stream>>>(
        A1, cw_pre1, pre_b1, A0, D_, part2);
    ln2d_apply_t<<<dim3(T_ / 32, D_ / 32, B_), 256, 0, stream>>>(
        A0, pre_lnw1, pre_lnb1, part2, pos_emb, H, 256);

    // ---- transformer layers (3 dispatches each)
    for (int l = 0; l < L_; ++l) {
        gemm64w<0, 1><<<dim3(768 / 64, M / 64), 256, 0, stream>>>(
            H, wqkv_bf + (size_t)l * 196608, bqkv + (size_t)l * 768, QKVb, M, 768, D_);
        attn_mfma<<<dim3(T_ / 64, H_, B_), 256, 0, stream>>>(QKVb, ATTb);
        layer_tail<<<M / 16, 512, 0, stream>>>(
            ATTb, wo_bf + (size_t)l * 65536, bo + (size_t)l * D_,
            w1_bf + (size_t)l * 131072, b1 + (size_t)l * DFF_,
            w2_bf + (size_t)l * 131072, b2 + (size_t)l * D_, H,
            ln1w + (size_t)l * D_, ln1b + (size_t)l * D_,
            ln2w + (size_t)l * D_, ln2b + (size_t)l * D_);
    }

    // ---- post stage
    gemm_conv16<256, 1><<<dim3(D_ / 64, M / 16), 256, 0, stream>>>(
        H, cw_post0, post_b0, A1, D_, part2);
    ln2d_apply<<<dim3(D_ * T_ / 1024, B_), 256, 0, stream>>>(
        A1, post_lnw0, post_lnb0, part2, A0, D_ * T_, 256);
    gemm_conv16<256, 0><<<dim3(CIN_ / 64, M / 16), 256, 0, stream>>>(
        A0, cw_post1, post_b1, A1, CIN_, part2);
    ln2d_apply<<<dim3(CIN_ * T_ / 1024, B_), 256, 0, stream>>>(
        A1, post_lnw1, post_lnb1, part2, (float*)d_out, CIN_ * T_, 128);
}